// Round 9
// baseline (429.104 us; speedup 1.0000x reference)
//
#include <hip/hip_runtime.h>
#include <hip/hip_bf16.h>

#define NB 4
#define SEQ 512
#define CIN 21
#define TDIM 4
#define DM 256
#define NH 8
#define PLEN 16
#define PSTR 8
#define EL 63
#define DFF 1024
#define PRED 96
#define NT 260
#define EPSV 1e-5f

// transposed-weight workspace offsets (floats)
#define T_nlWQ 0
#define T_nlWK 131072
#define T_nlWV 262144
#define T_nlWO 393216
#define T_elWq 524288
#define T_elWk 655360
#define T_elWv 786432
#define T_elWo 917504
#define T_elW1 1048576
#define T_elW2 1572864
#define T_inv  2097152
#define T_proj 2113280
#define T_tok  2137856
#define T_pat  2153984

// ---------------- helpers --------------------------------------------------
__device__ __forceinline__ float2 meanvar256(float v, float* sb) {
  __syncthreads();
  float s1 = v, s2 = v * v;
  #pragma unroll
  for (int off = 32; off > 0; off >>= 1) {
    s1 += __shfl_down(s1, off, 64);
    s2 += __shfl_down(s2, off, 64);
  }
  int wid = threadIdx.x >> 6, lane = threadIdx.x & 63;
  if (lane == 0) { sb[wid * 2] = s1; sb[wid * 2 + 1] = s2; }
  __syncthreads();
  float m = (sb[0] + sb[2] + sb[4] + sb[6]) * (1.0f / 256.0f);
  float q = (sb[1] + sb[3] + sb[5] + sb[7]) * (1.0f / 256.0f);
  return make_float2(m, q - m * m);
}

__device__ __forceinline__ void load16f(const float* p, float* o) {
  const float4* q = reinterpret_cast<const float4*>(p);
  float4 a = q[0], b = q[1], c = q[2], d = q[3];
  o[0]=a.x; o[1]=a.y; o[2]=a.z; o[3]=a.w;
  o[4]=b.x; o[5]=b.y; o[6]=b.z; o[7]=b.w;
  o[8]=c.x; o[9]=c.y; o[10]=c.z; o[11]=c.w;
  o[12]=d.x; o[13]=d.y; o[14]=d.z; o[15]=d.w;
}

__device__ __forceinline__ float dot32(const float4* a, const float4* b) {
  float s = 0.f;
  #pragma unroll
  for (int i = 0; i < 8; ++i) {
    float4 x = a[i], y = b[i];
    s += x.x*y.x + x.y*y.y + x.z*y.z + x.w*y.w;
  }
  return s;
}

// ---- K0: weight transpose (3128) + RevIN stats/tws (88) + g_rel (2016) ---
__global__ void __launch_bounds__(256) k_prep(
    const float* __restrict__ nlWQ, const float* __restrict__ nlWK,
    const float* __restrict__ nlWV, const float* __restrict__ nlWO,
    const float* __restrict__ eWq, const float* __restrict__ eWk,
    const float* __restrict__ eWv, const float* __restrict__ eWo,
    const float* __restrict__ eW1, const float* __restrict__ eW2,
    const float* __restrict__ invW, const float* __restrict__ projW,
    const float* __restrict__ tokW, const float* __restrict__ patW,
    float* __restrict__ wt,
    const float* __restrict__ x, const float* __restrict__ xm,
    float* __restrict__ means, float* __restrict__ stdev,
    float* __restrict__ tout,
    const float* __restrict__ mu_r, const float* __restrict__ sg_r,
    const float* __restrict__ w_r,
    const float* __restrict__ mu_a, const float* __restrict__ sg_a,
    const float* __restrict__ w_a,
    float* __restrict__ grel, float* __restrict__ gib) {
  __shared__ float smem[32 * 33];
  int blk = blockIdx.x;
  int t = threadIdx.x;

  if (blk < 3128) {
    // ----- weight transpose (32x32 LDS tiles) -----
    const float* src; float* dst; int R, C, tr, tc;
    if (blk < 1024) {                 // 16 square [256][256] mats
      int m = blk >> 6, tile = blk & 63;
      tr = tile >> 3; tc = tile & 7; R = 256; C = 256;
      int p = m >> 1, l = m & 1;
      const float* bases[8] = {nlWQ, nlWK, nlWV, nlWO, eWq, eWk, eWv, eWo};
      const int offs[8] = {T_nlWQ, T_nlWK, T_nlWV, T_nlWO, T_elWq, T_elWk, T_elWv, T_elWo};
      src = bases[p] + l * 65536;
      dst = wt + offs[p] + l * 65536;
    } else if (blk < 1536) {          // W1 [1024][256] x2
      int q = blk - 1024; int l = q >> 8, s = q & 255;
      tr = s >> 3; tc = s & 7; R = 1024; C = 256;
      src = eW1 + l * 262144; dst = wt + T_elW1 + l * 262144;
    } else if (blk < 2048) {          // W2 [256][1024] x2
      int q = blk - 1536; int l = q >> 8, s = q & 255;
      tr = s >> 5; tc = s & 31; R = 256; C = 1024;
      src = eW2 + l * 262144; dst = wt + T_elW2 + l * 262144;
    } else if (blk < 3072) {          // patch_W [256][4096]
      int q = blk - 2048; tr = q >> 7; tc = q & 127; R = 256; C = 4096;
      src = patW; dst = wt + T_pat;
    } else if (blk < 3088) {          // inv_W [256][63]
      int q = blk - 3072; tr = q >> 1; tc = q & 1; R = 256; C = 63;
      src = invW; dst = wt + T_inv;
    } else if (blk < 3112) {          // proj_W [96][256]
      int q = blk - 3088; tr = q >> 3; tc = q & 7; R = 96; C = 256;
      src = projW; dst = wt + T_proj;
    } else {                          // tok_W [256][63]
      int q = blk - 3112; tr = q >> 1; tc = q & 1; R = 256; C = 63;
      src = tokW; dst = wt + T_tok;
    }
    float (*ts)[33] = (float(*)[33])smem;
    int tx = t & 31, ty = t >> 5;
    #pragma unroll
    for (int i = 0; i < 4; ++i) {
      int r = tr * 32 + ty + i * 8, c = tc * 32 + tx;
      ts[ty + i * 8][tx] = (c < C) ? src[(size_t)r * C + c] : 0.f;
    }
    __syncthreads();
    #pragma unroll
    for (int i = 0; i < 4; ++i) {
      int c = tc * 32 + ty + i * 8, r = tr * 32 + tx;
      if (c < C) dst[(size_t)c * R + r] = ts[tx][ty + i * 8];
    }
  } else if (blk < 3216) {
    // ----- RevIN stats (84) + patch-time means (4) -----
    int sblk = blk - 3128;
    if (sblk < NB * CIN) {
      int b = sblk / CIN, c = sblk % CIN;
      const float* p = x + (size_t)b * SEQ * CIN + c;
      float v0 = p[t * CIN];
      float v1 = p[(t + 256) * CIN];
      float s1 = v0 + v1, s2 = v0 * v0 + v1 * v1;
      float* sb = smem;
      #pragma unroll
      for (int off = 32; off > 0; off >>= 1) {
        s1 += __shfl_down(s1, off, 64);
        s2 += __shfl_down(s2, off, 64);
      }
      int wid = t >> 6, lane = t & 63;
      if (lane == 0) { sb[wid * 2] = s1; sb[wid * 2 + 1] = s2; }
      __syncthreads();
      if (t == 0) {
        float a = sb[0] + sb[2] + sb[4] + sb[6];
        float q = sb[1] + sb[3] + sb[5] + sb[7];
        float m = a * (1.0f / 512.0f);
        float var = q * (1.0f / 512.0f) - m * m;
        means[sblk] = m;
        stdev[sblk] = sqrtf(var + EPSV);
      }
    } else {
      int idx = (sblk - NB * CIN) * 256 + t;
      if (idx >= NB * EL * TDIM) return;
      int b = idx / (EL * TDIM), r = idx % (EL * TDIM);
      int l = r >> 2, ti = r & 3;
      const float* p = xm + (size_t)b * SEQ * TDIM + (size_t)l * PSTR * TDIM + ti;
      float s = 0.f;
      #pragma unroll
      for (int k = 0; k < PLEN; ++k) s += p[k * TDIM];
      tout[idx] = s * (1.f / 16.f);
    }
  } else {
    // ----- g_rel + g_abs, both layers; s_t computed inline from xm -----
    int gblk = blk - 3216;                   // L*(NB*252) + b*252 + chunk
    int L = gblk / (NB * 252);
    int rem0 = gblk % (NB * 252);
    int b = rem0 / 252, chunk = rem0 % 252;
    int po = L * 4096;
    float* grelL = grel + (size_t)L * (NB * NH * EL * EL);
    float* gibL  = gib + (size_t)L * (NB * NH * EL);
    int h = t >> 5, dh = t & 31;
    float* s_t = smem;
    if (t < EL * TDIM) {
      int l = t >> 2, ti = t & 3;
      const float* p = xm + (size_t)b * SEQ * TDIM + (size_t)l * PSTR * TDIM + ti;
      float s = 0.f;
      #pragma unroll
      for (int k = 0; k < PLEN; ++k) s += p[k * TDIM];
      s_t[t] = s * (1.f / 16.f);
    }
    float pm[16], pc[16], pw[16];
    load16f(mu_r + po + (size_t)t * 16, pm);
    load16f(sg_r + po + (size_t)t * 16, pc);
    load16f(w_r  + po + (size_t)t * 16, pw);
    #pragma unroll
    for (int p = 0; p < 16; ++p) pc[p] = -0.5f / (pc[p] * pc[p]);
    __syncthreads();
    #pragma unroll 1
    for (int q = 0; q < 8; ++q) {
      int p = chunk * 8 + q;                 // 2016 (i<=j) pairs
      int i = (int)((127.0f - sqrtf(16129.0f - 8.0f * (float)p)) * 0.5f);
      while (i * (127 - i) / 2 > p) --i;
      while ((i + 1) * (126 - i) / 2 <= p) ++i;
      int j = i + (p - i * (127 - i) / 2);
      float dvv[4];
      dvv[0] = fabsf(s_t[i*4+0] - s_t[j*4+0]);
      dvv[1] = fabsf(s_t[i*4+1] - s_t[j*4+1]);
      dvv[2] = fabsf(s_t[i*4+2] - s_t[j*4+2]);
      dvv[3] = fabsf(s_t[i*4+3] - s_t[j*4+3]);
      float srel = 0.f;
      #pragma unroll
      for (int tt = 0; tt < 4; ++tt)
        #pragma unroll
        for (int k = 0; k < 4; ++k) {
          int pp = tt * 4 + k;
          float df = dvv[tt] - pm[pp];
          srel += pw[pp] * __expf(pc[pp] * df * df);
        }
      #pragma unroll
      for (int m = 1; m < 32; m <<= 1) srel += __shfl_xor(srel, m, 64);
      if (dh == 0) {
        float v = srel * (1.f / 32.f);
        grelL[(((size_t)b * NH + h) * EL + i) * EL + j] = v;
        grelL[(((size_t)b * NH + h) * EL + j) * EL + i] = v;
      }
    }
    if (chunk < EL) {
      load16f(mu_a + po + (size_t)t * 16, pm);
      load16f(sg_a + po + (size_t)t * 16, pc);
      load16f(w_a  + po + (size_t)t * 16, pw);
      #pragma unroll
      for (int p = 0; p < 16; ++p) pc[p] = -0.5f / (pc[p] * pc[p]);
      int i = chunk;
      float tiv[4] = {s_t[i*4+0], s_t[i*4+1], s_t[i*4+2], s_t[i*4+3]};
      float sabs = 0.f;
      #pragma unroll
      for (int tt = 0; tt < 4; ++tt)
        #pragma unroll
        for (int k = 0; k < 4; ++k) {
          int pp = tt * 4 + k;
          float df = tiv[tt] - pm[pp];
          sabs += pw[pp] * __expf(pc[pp] * df * df);
        }
      #pragma unroll
      for (int m = 1; m < 32; m <<= 1) sabs += __shfl_xor(sabs, m, 64);
      if (dh == 0) gibL[((size_t)b * NH + h) * EL + i] = sabs * (1.f / 32.f);
    }
  }
}

// ---- K3a: token conv + PE (tokWT [63][256] coalesced) --------------------
__global__ void __launch_bounds__(256) k_tokconv(
    const float* __restrict__ x, const float* __restrict__ tokWT,
    const float* __restrict__ means, const float* __restrict__ stdev,
    float* __restrict__ enc1) {
  int bi = blockIdx.x;                       // b*64 + sg
  int b = bi >> 6, sg = bi & 63;
  int s0 = sg * 8;
  __shared__ float sxr[10 * CIN];
  int t = threadIdx.x;
  if (t < 10 * CIN) {
    int li = t / CIN, c = t % CIN;
    int row = (s0 - 1 + li + SEQ) & 511;
    sxr[t] = (x[(size_t)b * SEQ * CIN + row * CIN + c] - means[b * CIN + c])
             / stdev[b * CIN + c];
  }
  __syncthreads();
  int d = t;
  float wreg[63];
  #pragma unroll
  for (int q = 0; q < 63; ++q) wreg[q] = tokWT[q * DM + d];
  int de = d & ~1;
  float dv = expf((float)de * (-9.210340371976184f / 256.0f));
  bool isodd = (d & 1);
  #pragma unroll 1
  for (int k = 0; k < 8; ++k) {
    float acc = 0.f;
    const float* sr = sxr + k * CIN;
    #pragma unroll
    for (int c = 0; c < CIN; ++c) {
      acc += sr[c]           * wreg[c * 3 + 0];
      acc += sr[CIN + c]     * wreg[c * 3 + 1];
      acc += sr[2 * CIN + c] * wreg[c * 3 + 2];
    }
    float ang = (float)(s0 + k) * dv;
    float pe = isodd ? cosf(ang) : sinf(ang);
    enc1[((size_t)b * SEQ + s0 + k) * DM + d] = acc + pe;
  }
}

// ---- K3b: patch conv partials (patWT [4096][256], batched loads) ---------
__global__ void __launch_bounds__(256) k_patch_part(
    const float* __restrict__ enc1, const float* __restrict__ pWT,
    float* __restrict__ pbuf) {
  int bi = blockIdx.x;
  int pg = bi >> 3, kc = bi & 7;
  int p0 = pg * 6;
  __shared__ __align__(16) float sA[6 * 32 * 20];
  int t = threadIdx.x;
  for (int idx = t; idx < 6 * 32 * PLEN; idx += 256) {
    int pp = idx >> 9;
    int rem = idx & 511;
    int c = rem >> 4, k = rem & 15;
    int p = p0 + pp;
    int b = p / EL, l = p % EL;
    sA[pp * 640 + c * 20 + k] =
        enc1[((size_t)b * SEQ + l * PSTR + k) * DM + kc * 32 + c];
  }
  __syncthreads();
  int d = t;
  const float* wb = pWT + (size_t)(kc * 32 * PLEN) * DM + d;
  float acc[6] = {0.f, 0.f, 0.f, 0.f, 0.f, 0.f};
  #pragma unroll 1
  for (int kk0 = 0; kk0 < 512; kk0 += 8) {
    float w[8];
    #pragma unroll
    for (int q = 0; q < 8; ++q) w[q] = wb[(size_t)(kk0 + q) * DM];
    #pragma unroll
    for (int q = 0; q < 8; ++q) {
      int kk = kk0 + q;
      const float* sa = sA + (kk >> 4) * 20 + (kk & 15);
      acc[0] += sa[0 * 640] * w[q];
      acc[1] += sa[1 * 640] * w[q];
      acc[2] += sa[2 * 640] * w[q];
      acc[3] += sa[3 * 640] * w[q];
      acc[4] += sa[4 * 640] * w[q];
      acc[5] += sa[5 * 640] * w[q];
    }
  }
  const int S = NB * EL * DM;
  #pragma unroll
  for (int pp = 0; pp < 6; ++pp)
    pbuf[(size_t)kc * S + (size_t)(p0 + pp) * DM + d] = acc[pp];
}

// ---- K3c: reduce partials + bias -----------------------------------------
__global__ void k_patch_red(const float* __restrict__ pbuf, const float* __restrict__ pb,
                            float* __restrict__ encP) {
  int p = blockIdx.x, t = threadIdx.x;
  const int S = NB * EL * DM;
  float v = 0.f;
  #pragma unroll
  for (int s = 0; s < 8; ++s) v += pbuf[(size_t)s * S + (size_t)p * DM + t];
  encP[(size_t)p * DM + t] = v + pb[t];
}

// ---- QKV: WT [256][256], reg-tile 4 cols x R rows, K-split 4, batch 4 ----
template<int R>
__global__ void __launch_bounds__(256) k_qkv2(
    const float* __restrict__ WqT, const float* __restrict__ WkT,
    const float* __restrict__ WvT,
    const float* __restrict__ bq, const float* __restrict__ bk,
    const float* __restrict__ bv,
    const float* __restrict__ xin,
    float* __restrict__ qo, float* __restrict__ ko, float* __restrict__ vo) {
  int bi = blockIdx.x;
  int rg = bi / 3, mat = bi % 3;
  int row0 = rg * R;
  __shared__ __align__(16) float sx[R * DM];
  __shared__ __align__(16) float sp[3 * R * DM];
  int t = threadIdx.x;
  int colg = t & 63, kq = t >> 6;
  #pragma unroll
  for (int i = 0; i < R / 4; ++i)
    reinterpret_cast<float4*>(sx)[t + i * 256] =
        reinterpret_cast<const float4*>(xin + (size_t)row0 * DM)[t + i * 256];
  __syncthreads();
  const float* WT = (mat == 0) ? WqT : (mat == 1) ? WkT : WvT;
  const float* bias = (mat == 0) ? bq : (mat == 1) ? bk : bv;
  float* out = (mat == 0) ? qo : (mat == 1) ? ko : vo;
  float acc[R][4];
  #pragma unroll
  for (int r = 0; r < R; ++r) { acc[r][0]=0.f; acc[r][1]=0.f; acc[r][2]=0.f; acc[r][3]=0.f; }
  const float* xb = sx + kq * 64;
  const float4* wp = reinterpret_cast<const float4*>(WT + (size_t)(kq * 64) * DM) + colg;
  #pragma unroll 1
  for (int k0 = 0; k0 < 64; k0 += 4) {
    float4 w[4];
    #pragma unroll
    for (int q = 0; q < 4; ++q) w[q] = wp[(size_t)(k0 + q) * 64];
    #pragma unroll
    for (int q = 0; q < 4; ++q)
      #pragma unroll
      for (int r = 0; r < R; ++r) {
        float xv = xb[r * DM + k0 + q];
        acc[r][0] += xv * w[q].x; acc[r][1] += xv * w[q].y;
        acc[r][2] += xv * w[q].z; acc[r][3] += xv * w[q].w;
      }
  }
  if (kq) {
    #pragma unroll
    for (int r = 0; r < R; ++r)
      reinterpret_cast<float4*>(sp)[((kq - 1) * R + r) * 64 + colg] =
          make_float4(acc[r][0], acc[r][1], acc[r][2], acc[r][3]);
  }
  __syncthreads();
  if (kq == 0) {
    float4 b4 = bias ? reinterpret_cast<const float4*>(bias)[colg]
                     : make_float4(0.f, 0.f, 0.f, 0.f);
    const float4* sp4 = reinterpret_cast<const float4*>(sp);
    #pragma unroll
    for (int r = 0; r < R; ++r) {
      float4 p0 = sp4[(0 * R + r) * 64 + colg];
      float4 p1 = sp4[(1 * R + r) * 64 + colg];
      float4 p2 = sp4[(2 * R + r) * 64 + colg];
      float4 o;
      o.x = acc[r][0] + p0.x + p1.x + p2.x + b4.x;
      o.y = acc[r][1] + p0.y + p1.y + p2.y + b4.y;
      o.z = acc[r][2] + p0.z + p1.z + p2.z + b4.z;
      o.w = acc[r][3] + p0.w + p1.w + p2.w + b4.w;
      reinterpret_cast<float4*>(out + (size_t)(row0 + r) * DM)[colg] = o;
    }
  }
}

// ---- QKV layer-1: K,V full (1040 rows) + Q only first 24 rows per b ------
__global__ void __launch_bounds__(256) k_qkv_l1(
    const float* __restrict__ WqT, const float* __restrict__ WkT,
    const float* __restrict__ WvT,
    const float* __restrict__ bq, const float* __restrict__ bk,
    const float* __restrict__ bv,
    const float* __restrict__ xin,
    float* __restrict__ qo, float* __restrict__ ko, float* __restrict__ vo) {
  int bi = blockIdx.x;
  const float* WT; const float* bias; float* out; int row0;
  if (bi < 130)      { WT = WkT; bias = bk; out = ko; row0 = bi * 8; }
  else if (bi < 260) { WT = WvT; bias = bv; out = vo; row0 = (bi - 130) * 8; }
  else {             // 12 blocks: Q for rows b*NT + [0,24)
    int gq = bi - 260;
    WT = WqT; bias = bq; out = qo;
    row0 = (gq / 3) * NT + (gq % 3) * 8;
  }
  __shared__ __align__(16) float sx[8 * DM];
  __shared__ __align__(16) float sp[3 * 8 * DM];
  int t = threadIdx.x;
  int colg = t & 63, kq = t >> 6;
  #pragma unroll
  for (int i = 0; i < 2; ++i)
    reinterpret_cast<float4*>(sx)[t + i * 256] =
        reinterpret_cast<const float4*>(xin + (size_t)row0 * DM)[t + i * 256];
  __syncthreads();
  float acc[8][4];
  #pragma unroll
  for (int r = 0; r < 8; ++r) { acc[r][0]=0.f; acc[r][1]=0.f; acc[r][2]=0.f; acc[r][3]=0.f; }
  const float* xb = sx + kq * 64;
  const float4* wp = reinterpret_cast<const float4*>(WT + (size_t)(kq * 64) * DM) + colg;
  #pragma unroll 1
  for (int k0 = 0; k0 < 64; k0 += 4) {
    float4 w[4];
    #pragma unroll
    for (int q = 0; q < 4; ++q) w[q] = wp[(size_t)(k0 + q) * 64];
    #pragma unroll
    for (int q = 0; q < 4; ++q)
      #pragma unroll
      for (int r = 0; r < 8; ++r) {
        float xv = xb[r * DM + k0 + q];
        acc[r][0] += xv * w[q].x; acc[r][1] += xv * w[q].y;
        acc[r][2] += xv * w[q].z; acc[r][3] += xv * w[q].w;
      }
  }
  if (kq) {
    #pragma unroll
    for (int r = 0; r < 8; ++r)
      reinterpret_cast<float4*>(sp)[((kq - 1) * 8 + r) * 64 + colg] =
          make_float4(acc[r][0], acc[r][1], acc[r][2], acc[r][3]);
  }
  __syncthreads();
  if (kq == 0) {
    float4 b4 = reinterpret_cast<const float4*>(bias)[colg];
    const float4* sp4 = reinterpret_cast<const float4*>(sp);
    #pragma unroll
    for (int r = 0; r < 8; ++r) {
      float4 p0 = sp4[(0 * 8 + r) * 64 + colg];
      float4 p1 = sp4[(1 * 8 + r) * 64 + colg];
      float4 p2 = sp4[(2 * 8 + r) * 64 + colg];
      float4 o;
      o.x = acc[r][0] + p0.x + p1.x + p2.x + b4.x;
      o.y = acc[r][1] + p0.y + p1.y + p2.y + b4.y;
      o.z = acc[r][2] + p0.z + p1.z + p2.z + b4.z;
      o.w = acc[r][3] + p0.w + p1.w + p2.w + b4.w;
      reinterpret_cast<float4*>(out + (size_t)(row0 + r) * DM)[colg] = o;
    }
  }
}

// ---- TKA attention + fused Wo^T, 512 threads, split PV / split-K Wo ------
__global__ void __launch_bounds__(512) k_tka_attn_f(
    const float* __restrict__ xin, const float* __restrict__ qw,
    const float* __restrict__ kw, const float* __restrict__ vw,
    const float* __restrict__ grel, const float* __restrict__ gib,
    const float* __restrict__ alpha, const float* __restrict__ beta,
    const float* __restrict__ gamma,
    const float* __restrict__ WOT, const float* __restrict__ bO,
    float* __restrict__ xout) {
  int bi = blockIdx.x;                       // b*63+i
  int b = bi / EL, i = bi % EL;
  int t = threadIdx.x;
  __shared__ __align__(16) float sQX[2 * DM];
  __shared__ float sP[NH * 64];
  __shared__ __align__(16) float sO[DM];
  __shared__ float sPV[DM];
  if (t < 2 * DM)
    sQX[t] = (t < DM) ? qw[(size_t)bi * DM + t] : xin[(size_t)bi * DM + (t - DM)];
  __syncthreads();
  {
    int tile = t >> 8, h = (t >> 5) & 7, jj = t & 31;
    int j = tile * 32 + jj;
    bool valid = (j < EL);
    int jc = valid ? j : (EL - 1);
    float gi = gib[((size_t)b * NH + h) * EL + i];
    float al = alpha[h], be = beta[h], ga = gamma[h];
    const float* grow = grel + (((size_t)b * NH + h) * EL + i) * EL;
    const float4* kp = reinterpret_cast<const float4*>(
        kw + (size_t)(b * EL + jc) * DM + h * 32);
    const float4* xp = reinterpret_cast<const float4*>(
        xin + (size_t)(b * EL + jc) * DM + h * 32);
    float4 kf[8], xf[8];
    #pragma unroll
    for (int q = 0; q < 8; ++q) { kf[q] = kp[q]; xf[q] = xp[q]; }
    float qk  = dot32(reinterpret_cast<const float4*>(sQX + h * 32), kf);
    float pij = dot32(reinterpret_cast<const float4*>(sQX + DM + h * 32), xf);
    float A = al * pij * (2.f * gi) + be * pij * grow[jc] + ga;
    const float scale = 0.17677669529663687f;
    sP[h * 64 + tile * 32 + jj] = valid ? (qk * scale * A) : -1e30f;
  }
  __syncthreads();
  {
    int h = t >> 6, dh = t & 63;               // one wave per head
    float v = sP[h * 64 + dh];
    float m = v;
    #pragma unroll
    for (int s = 1; s < 64; s <<= 1) m = fmaxf(m, __shfl_xor(m, s, 64));
    float e = __expf(v - m);
    float ssum = e;
    #pragma unroll
    for (int s = 1; s < 64; s <<= 1) ssum += __shfl_xor(ssum, s, 64);
    sP[h * 64 + dh] = e / ssum;                // dh=63 -> 0
  }
  __syncthreads();
  {
    int ch = t & 255, jh = t >> 8, hh = ch >> 5;
    float acc = 0.f;
    const float* pp = sP + hh * 64 + jh * 32;
    int jbase = jh * 32;
    #pragma unroll 1
    for (int j0 = 0; j0 < 32; j0 += 8) {
      float v[8];
      #pragma unroll
      for (int q = 0; q < 8; ++q) {
        int jx = jbase + j0 + q;
        if (jx > 62) jx = 62;                  // j=63 weight is 0; avoid stale row
        v[q] = vw[(size_t)(b * EL + jx) * DM + ch];
      }
      #pragma unroll
      for (int q = 0; q < 8; ++q) acc += pp[j0 + q] * v[q];
    }
    if (jh) sPV[ch] = acc;
    __syncthreads();
    if (!jh) sO[ch] = acc + sPV[ch];
  }
  __syncthreads();
  {
    int col = t & 255, kh = t >> 8;
    float acc = 0.f;
    const float* wc = WOT + (size_t)(kh * 128) * DM + col;
    const float* sx = sO + kh * 128;
    #pragma unroll 1
    for (int k0 = 0; k0 < 128; k0 += 8) {
      float w[8];
      #pragma unroll
      for (int q = 0; q < 8; ++q) w[q] = wc[(size_t)(k0 + q) * DM];
      #pragma unroll
      for (int q = 0; q < 8; ++q) acc += sx[k0 + q] * w[q];
    }
    if (kh) sPV[col] = acc;
    __syncthreads();
    if (!kh) xout[(size_t)bi * DM + col] = acc + sPV[col] + bO[col];
  }
}

// ---- inverted embedding (invWT [63][256], batched) -----------------------
__global__ void k_invemb(const float* __restrict__ invWT, const float* __restrict__ invb,
                         const float* __restrict__ encP, const float* __restrict__ tws,
                         float* __restrict__ enc2) {
  int bi = blockIdx.x;                       // b*260+n
  int b = bi / NT, n = bi % NT;
  __shared__ float sx[EL];
  int t = threadIdx.x;
  if (t < EL) {
    sx[t] = (n < DM) ? encP[(size_t)(b * EL + t) * DM + n]
                     : tws[b * EL * TDIM + t * TDIM + (n - DM)];
  }
  __syncthreads();
  float acc = 0.f;
  #pragma unroll 1
  for (int l0 = 0; l0 < 63; l0 += 9) {
    float w[9];
    #pragma unroll
    for (int q = 0; q < 9; ++q) w[q] = invWT[(size_t)(l0 + q) * DM + t];
    #pragma unroll
    for (int q = 0; q < 9; ++q) acc += sx[l0 + q] * w[q];
  }
  enc2[(size_t)bi * DM + t] = acc + invb[t];
}

// ---- encoder attention, 512 thr, 2 rows/block: scores/PV/Wo + fused LN ---
// tpb: i-tiles (of 2 rows) per batch (130 dense, 12 pruned layer 1).
__global__ void __launch_bounds__(512) k_enc_attn_f(
    const float* __restrict__ qw, const float* __restrict__ kw,
    const float* __restrict__ vw,
    const float* __restrict__ WoT, const float* __restrict__ bo,
    const float* __restrict__ g, const float* __restrict__ bb,
    const float* __restrict__ resin, float* __restrict__ out, int tpb) {
  int blk = blockIdx.x;                      // b*tpb + tile
  int b = blk / tpb, it = blk % tpb;
  int i0 = it * 2;
  int t = threadIdx.x;

  __shared__ __align__(16) float sQ[2 * DM]; // Q rows; later normalized PV out
  __shared__ float sS[2 * NH * NT];          // 16.6 KB
  __shared__ float sL[2 * NH];
  __shared__ __align__(16) float sPV[2 * DM];
  __shared__ float sb[8];

  for (int idx = t; idx < 2 * DM; idx += 512)
    sQ[idx] = qw[((size_t)(b * NT + i0)) * DM + idx];
  __syncthreads();

  const float scale = 0.17677669529663687f;
  {
    int half = t >> 8, h = (t >> 5) & 7, jj = t & 31;
    for (int tile = half; tile < 9; tile += 2) {
      int j = tile * 32 + jj;
      if (j >= NT) break;
      const float4* kp = reinterpret_cast<const float4*>(
          kw + ((size_t)(b * NT + j)) * DM + h * 32);
      float4 kf[8];
      #pragma unroll
      for (int q = 0; q < 8; ++q) kf[q] = kp[q];
      #pragma unroll
      for (int i = 0; i < 2; ++i) {
        float s = dot32(reinterpret_cast<const float4*>(sQ + i * DM + h * 32), kf);
        sS[(i * NH + h) * NT + j] = s * scale;
      }
    }
  }
  __syncthreads();
  {
    int combo = t >> 5, lane32 = t & 31;     // 16 combos x 32 lanes
    float* row = sS + (size_t)combo * NT;
    float m = -1e30f;
    for (int jx = lane32; jx < NT; jx += 32) m = fmaxf(m, row[jx]);
    #pragma unroll
    for (int s = 1; s < 32; s <<= 1) m = fmaxf(m, __shfl_xor(m, s, 32));
    float ssum = 0.f;
    for (int jx = lane32; jx < NT; jx += 32) {
      float e = __expf(row[jx] - m);
      row[jx] = e;
      ssum += e;
    }
    #pragma unroll
    for (int s = 1; s < 32; s <<= 1) ssum += __shfl_xor(ssum, s, 32);
    if (lane32 == 0) sL[combo] = ssum;
  }
  __syncthreads();
  {
    int ch = t & 255, jh = t >> 8, hh = ch >> 5;
    float o0 = 0.f, o1 = 0.f;
    const float* vbase = vw + ((size_t)(b * NT + jh * 130)) * DM + ch;
    const float* p0 = sS + (0 * NH + hh) * NT + jh * 130;
    const float* p1 = sS + (1 * NH + hh) * NT + jh * 130;
    #pragma unroll 1
    for (int j0 = 0; j0 < 130; j0 += 10) {
      float v[10];
      #pragma unroll
      for (int q = 0; q < 10; ++q) v[q] = vbase[(size_t)(j0 + q) * DM];
      #pragma unroll
      for (int q = 0; q < 10; ++q) {
        o0 += p0[j0 + q] * v[q]; o1 += p1[j0 + q] * v[q];
      }
    }
    if (jh) {
      sPV[0 * DM + ch] = o0; sPV[1 * DM + ch] = o1;
    }
    __syncthreads();
    if (!jh) {
      sQ[0 * DM + ch] = (o0 + sPV[0 * DM + ch]) / sL[0 * NH + hh];
      sQ[1 * DM + ch] = (o1 + sPV[1 * DM + ch]) / sL[1 * NH + hh];
    }
  }
  __syncthreads();
  {
    int col = t & 255, kh = t >> 8;
    float acc[2] = {0.f, 0.f};
    const float* wcol = WoT + (size_t)(kh * 128) * DM + col;
    const float* s0 = sQ + kh * 128;
    #pragma unroll 1
    for (int k0 = 0; k0 < 128; k0 += 8) {
      float w[8];
      #pragma unroll
      for (int q = 0; q < 8; ++q) w[q] = wcol[(size_t)(k0 + q) * DM];
      #pragma unroll
      for (int q = 0; q < 8; ++q) {
        acc[0] += s0[0 * DM + k0 + q] * w[q];
        acc[1] += s0[1 * DM + k0 + q] * w[q];
      }
    }
    if (kh) {
      sPV[0 * DM + col] = acc[0]; sPV[1 * DM + col] = acc[1];
    }
    __syncthreads();
    float ov[2] = {0.f, 0.f};
    float gg = g[col], bb2 = bb[col];
    if (!kh) {
      float bias = bo[col];
      #pragma unroll
      for (int r = 0; r < 2; ++r)
        ov[r] = acc[r] + sPV[r * DM + col] + bias
              + resin[((size_t)(b * NT + i0 + r)) * DM + col];
    }
    int wid = t >> 6, lane = t & 63;
    #pragma unroll 1
    for (int r = 0; r < 2; ++r) {
      float o = (!kh) ? ov[r] : 0.f;
      __syncthreads();
      float s1 = o, s2 = o * o;
      #pragma unroll
      for (int off = 32; off > 0; off >>= 1) {
        s1 += __shfl_down(s1, off, 64);
        s2 += __shfl_down(s2, off, 64);
      }
      if (lane == 0 && wid < 4) { sb[wid * 2] = s1; sb[wid * 2 + 1] = s2; }
      __syncthreads();
      float m = (sb[0] + sb[2] + sb[4] + sb[6]) * (1.f / 256.f);
      float q2 = (sb[1] + sb[3] + sb[5] + sb[7]) * (1.f / 256.f);
      float var = q2 - m * m;
      if (!kh)
        out[((size_t)(b * NT + i0 + r)) * DM + col] =
            (ov[r] - m) * rsqrtf(var + EPSV) * gg + bb2;
    }
  }
}

// ---- FFN1: gelu(x@W1.T+b1) via W1T, reg-tile, K-split 4, batch 4 ---------
// gpb: row-groups per batch (0 = dense 130 groups; 3 = pruned 24 rows/b)
__global__ void __launch_bounds__(256) k_ffn1(
    const float* __restrict__ W1T, const float* __restrict__ b1,
    const float* __restrict__ xn, float* __restrict__ y1, int gpb) {
  int bi = blockIdx.x;                       // rg*4 + fg
  int rg = bi >> 2, fg = bi & 3;
  int row0 = gpb ? ((rg / gpb) * NT + (rg % gpb) * 8) : rg * 8;
  __shared__ __align__(16) float sx[8 * DM];
  __shared__ __align__(16) float sp[3 * 8 * DM];
  int t = threadIdx.x;
  int colg = t & 63, kq = t >> 6;
  #pragma unroll
  for (int i = 0; i < 2; ++i)
    reinterpret_cast<float4*>(sx)[t + i * 256] =
        reinterpret_cast<const float4*>(xn + (size_t)row0 * DM)[t + i * 256];
  __syncthreads();
  int f = fg * 256 + colg * 4;
  float acc[8][4];
  #pragma unroll
  for (int r = 0; r < 8; ++r) { acc[r][0]=0.f; acc[r][1]=0.f; acc[r][2]=0.f; acc[r][3]=0.f; }
  const float* xb = sx + kq * 64;
  const float4* wp = reinterpret_cast<const float4*>(W1T + (size_t)(kq * 64) * DFF + f);
  #pragma unroll 1
  for (int k0 = 0; k0 < 64; k0 += 4) {
    float4 w[4];
    #pragma unroll
    for (int q = 0; q < 4; ++q) w[q] = wp[(size_t)(k0 + q) * 256];
    #pragma unroll
    for (int q = 0; q < 4; ++q)
      #pragma unroll
      for (int r = 0; r < 8; ++r) {
        float xv = xb[r * DM + k0 + q];
        acc[r][0] += xv * w[q].x; acc[r][1] += xv * w[q].y;
        acc[r][2] += xv * w[q].z; acc[r][3] += xv * w[q].w;
      }
  }
  if (kq) {
    #pragma unroll
    for (int r = 0; r < 8; ++r)
      reinterpret_cast<float4*>(sp)[((kq - 1) * 8 + r) * 64 + colg] =
          make_float4(acc[r][0], acc[r][1], acc[r][2], acc[r][3]);
  }
  __syncthreads();
  if (kq == 0) {
    float4 b4 = *reinterpret_cast<const float4*>(b1 + f);
    const float4* sp4 = reinterpret_cast<const float4*>(sp);
    #pragma unroll 1
    for (int r = 0; r < 8; ++r) {
      float4 p0 = sp4[(0 * 8 + r) * 64 + colg];
      float4 p1 = sp4[(1 * 8 + r) * 64 + colg];
      float4 p2 = sp4[(2 * 8 + r) * 64 + colg];
      float a0 = acc[r][0] + p0.x + p1.x + p2.x + b4.x;
      float a1 = acc[r][1] + p0.y + p1.y + p2.y + b4.y;
      float a2 = acc[r][2] + p0.z + p1.z + p2.z + b4.z;
      float a3 = acc[r][3] + p0.w + p1.w + p2.w + b4.w;
      float4 o;
      o.x = 0.5f * a0 * (1.f + erff(a0 * 0.70710678118654752f));
      o.y = 0.5f * a1 * (1.f + erff(a1 * 0.70710678118654752f));
      o.z = 0.5f * a2 * (1.f + erff(a2 * 0.70710678118654752f));
      o.w = 0.5f * a3 * (1.f + erff(a3 * 0.70710678118654752f));
      *reinterpret_cast<float4*>(y1 + (size_t)(row0 + r) * DFF + f) = o;
    }
  }
}

// ---- FFN2 fused: W2T, 4 rows/block, 512 thr, K-split 8, batch 8, +LN -----
// gpb: groups-of-4 per batch (0 = dense 260 blocks; 6 = pruned 24 rows/b)
__global__ void __launch_bounds__(512) k_ffn2f(
    const float* __restrict__ W2T, const float* __restrict__ b2,
    const float* __restrict__ g, const float* __restrict__ bb,
    const float* __restrict__ y1, const float* __restrict__ xn,
    float* __restrict__ out, int gpb) {
  int blk = blockIdx.x;
  int row0 = gpb ? ((blk / gpb) * NT + (blk % gpb) * 4) : blk * 4;
  __shared__ __align__(16) float sy[4 * DFF];    // 16 KB
  __shared__ __align__(16) float sp[7 * 4 * DM]; // 28 KB
  int t = threadIdx.x;
  int colg = t & 63, kq = t >> 6;                // kq 0..7
  #pragma unroll
  for (int i = 0; i < 2; ++i)
    reinterpret_cast<float4*>(sy)[t + i * 512] =
        reinterpret_cast<const float4*>(y1 + (size_t)row0 * DFF)[t + i * 512];
  __syncthreads();
  float acc[4][4];
  #pragma unroll
  for (int r = 0; r < 4; ++r) { acc[r][0]=0.f; acc[r][1]=0.f; acc[r][2]=0.f; acc[r][3]=0.f; }
  const float* yb = sy + kq * 128;
  const float4* wp = reinterpret_cast<const float4*>(W2T + (size_t)(kq * 128) * DM) + colg;
  #pragma unroll 1
  for (int k0 = 0; k0 < 128; k0 += 8) {
    float4 w[8];
    #pragma unroll
    for (int q = 0; q < 8; ++q) w[q] = wp[(size_t)(k0 + q) * 64];
    #pragma unroll
    for (int q = 0; q < 8; ++q)
      #pragma unroll
      for (int r = 0; r < 4; ++r) {
        float yv = yb[r * DFF + k0 + q];
        acc[r][0] += yv * w[q].x; acc[r][1] += yv * w[q].y;
        acc[r][2] += yv * w[q].z; acc[r][3] += yv * w[q].w;
      }
  }
  if (kq) {
    #pragma unroll
    for (int r = 0; r < 4; ++r)
      reinterpret_cast<float4*>(sp)[((kq - 1) * 4 + r) * 64 + colg] =
          make_float4(acc[r][0], acc[r][1], acc[r][2], acc[r][3]);
  }
  __syncthreads();
  if (kq == 0) {
    float4 b4 = reinterpret_cast<const float4*>(b2)[colg];
    float4 g4 = reinterpret_cast<const float4*>(g)[colg];
    float4 bb4 = reinterpret_cast<const float4*>(bb)[colg];
    const float4* sp4 = reinterpret_cast<const float4*>(sp);
    #pragma unroll 1
    for (int r = 0; r < 4; ++r) {
      float o0 = acc[r][0], o1 = acc[r][1], o2 = acc[r][2], o3 = acc[r][3];
      #pragma unroll
      for (int s = 0; s < 7; ++s) {
        float4 ps = sp4[(s * 4 + r) * 64 + colg];
        o0 += ps.x; o1 += ps.y; o2 += ps.z; o3 += ps.w;
      }
      float4 xr = reinterpret_cast<const float4*>(xn + (size_t)(row0 + r) * DM)[colg];
      o0 += b4.x + xr.x; o1 += b4.y + xr.y; o2 += b4.z + xr.z; o3 += b4.w + xr.w;
      float s1 = o0 + o1 + o2 + o3;
      float s2 = o0*o0 + o1*o1 + o2*o2 + o3*o3;
      #pragma unroll
      for (int m = 1; m < 64; m <<= 1) {
        s1 += __shfl_xor(s1, m, 64);
        s2 += __shfl_xor(s2, m, 64);
      }
      float mean = s1 * (1.f / 256.f);
      float var = s2 * (1.f / 256.f) - mean * mean;
      float rs = rsqrtf(var + EPSV);
      float4 o;
      o.x = (o0 - mean) * rs * g4.x + bb4.x;
      o.y = (o1 - mean) * rs * g4.y + bb4.y;
      o.z = (o2 - mean) * rs * g4.z + bb4.z;
      o.w = (o3 - mean) * rs * g4.w + bb4.w;
      reinterpret_cast<float4*>(out + (size_t)(row0 + r) * DM)[colg] = o;
    }
  }
}

// ---- final LN + projection (pWT [256][96], batched) + denorm -------------
__global__ void k_final(const float* __restrict__ g, const float* __restrict__ bb,
                        const float* __restrict__ pWT, const float* __restrict__ pb,
                        const float* __restrict__ enc2,
                        const float* __restrict__ stdev, const float* __restrict__ means,
                        float* __restrict__ out) {
  int bi = blockIdx.x;                       // b*21+c
  int b = bi / CIN, c = bi % CIN;
  __shared__ __align__(16) float sx[DM];
  __shared__ float sb[8];
  int t = threadIdx.x;
  float v = enc2[(size_t)(b * NT + c) * DM + t];
  float2 mv = meanvar256(v, sb);
  sx[t] = (v - mv.x) * rsqrtf(mv.y + EPSV) * g[t] + bb[t];
  __syncthreads();
  if (t < PRED) {
    float acc = 0.f;
    #pragma unroll 1
    for (int k0 = 0; k0 < DM; k0 += 8) {
      float w[8];
      #pragma unroll
      for (int q = 0; q < 8; ++q) w[q] = pWT[(size_t)(k0 + q) * PRED + t];
      #pragma unroll
      for (int q = 0; q < 8; ++q) acc += sx[k0 + q] * w[q];
    }
    float y = (acc + pb[t]) * stdev[bi] + means[bi];
    out[(size_t)b * PRED * CIN + t * CIN + c] = y;
  }
}

extern "C" void kernel_launch(void* const* d_in, const int* in_sizes, int n_in,
                              void* d_out, int out_size, void* d_ws, size_t ws_size,
                              hipStream_t stream) {
  const float* x_enc   = (const float*)d_in[0];
  const float* x_mark  = (const float*)d_in[1];
  const float* tok_W   = (const float*)d_in[4];
  const float* patch_W = (const float*)d_in[5];
  const float* patch_b = (const float*)d_in[6];
  const float* nl_WQ   = (const float*)d_in[7];
  const float* nl_WK   = (const float*)d_in[8];
  const float* nl_WV   = (const float*)d_in[9];
  const float* nl_WO   = (const float*)d_in[10];
  const float* nl_bO   = (const float*)d_in[11];
  const float* nl_mu_a = (const float*)d_in[12];
  const float* nl_sg_a = (const float*)d_in[13];
  const float* nl_w_a  = (const float*)d_in[14];
  const float* nl_mu_r = (const float*)d_in[15];
  const float* nl_sg_r = (const float*)d_in[16];
  const float* nl_w_r  = (const float*)d_in[17];
  const float* nl_al   = (const float*)d_in[18];
  const float* nl_be   = (const float*)d_in[19];
  const float* nl_ga   = (const float*)d_in[20];
  const float* inv_W   = (const float*)d_in[21];
  const float* inv_b   = (const float*)d_in[22];
  const float* el_Wq   = (const float*)d_in[23];
  const float* el_bq   = (const float*)d_in[24];
  const float* el_Wk   = (const float*)d_in[25];
  const float* el_bk   = (const float*)d_in[26];
  const float* el_Wv   = (const float*)d_in[27];
  const float* el_bv   = (const float*)d_in[28];
  const float* el_Wo   = (const float*)d_in[29];
  const float* el_bo   = (const float*)d_in[30];
  const float* el_W1   = (const float*)d_in[31];
  const float* el_b1   = (const float*)d_in[32];
  const float* el_W2   = (const float*)d_in[33];
  const float* el_b2   = (const float*)d_in[34];
  const float* n1g     = (const float*)d_in[35];
  const float* n1b     = (const float*)d_in[36];
  const float* n2g     = (const float*)d_in[37];
  const float* n2b     = (const float*)d_in[38];
  const float* norm_g  = (const float*)d_in[39];
  const float* norm_b  = (const float*)d_in[40];
  const float* proj_W  = (const float*)d_in[41];
  const float* proj_b  = (const float*)d_in[42];

  // workspace layout (floats)
  float* ws = (float*)d_ws;
  float* means = ws + 0;          //     96
  float* stdev = ws + 96;         //     96
  float* tws   = ws + 192;        //   1024
  float* enc1  = ws + 1216;       // 524288  (B,512,256)
  float* encP  = ws + 525504;     //  64512  (252,256)
  float* pbuf  = ws + 590016;     // 516096  (8,252,256)
  float* enc2  = ws + 1106112;    // 266240  (1040,256)
  float* qb    = ws + 1638592;    // 266240  (xn aliases qb)
  float* kb    = ws + 1904832;    // 266240
  float* vb    = ws + 2171072;    // 266240
  float* y1    = ws + 2437312;    // 1064960 (1040,1024)
  float* encPb = ws + 3502272;    //  64512  (TKA ping-pong)
  float* grel  = ws + 4567232;    // 254016  (2,B,8,63,63)
  float* gib   = ws + 4821248;    //   4032  (2,B,8,63)
  float* wsT   = ws + 4825344;    // 3202560 (transposed weights)
  float* xn    = qb;              // alias: qb rows only self-read before overwrite

  // prep: weight transpose (3128) + stats/tws (88) + grel/gib (2016)
  k_prep<<<5232, 256, 0, stream>>>(nl_WQ, nl_WK, nl_WV, nl_WO,
                                   el_Wq, el_Wk, el_Wv, el_Wo,
                                   el_W1, el_W2, inv_W, proj_W,
                                   tok_W, patch_W, wsT,
                                   x_enc, x_mark, means, stdev, tws,
                                   nl_mu_r, nl_sg_r, nl_w_r,
                                   nl_mu_a, nl_sg_a, nl_w_a, grel, gib);
  k_tokconv<<<NB * 64, 256, 0, stream>>>(x_enc, wsT + T_tok, means, stdev, enc1);
  k_patch_part<<<42 * 8, 256, 0, stream>>>(enc1, wsT + T_pat, pbuf);
  k_patch_red<<<NB * EL, 256, 0, stream>>>(pbuf, patch_b, encP);

  for (int L = 0; L < 2; ++L) {
    size_t wo = (size_t)L * DM * DM;
    const float* xi = L ? encPb : encP;
    float* xo       = L ? encP : encPb;
    k_qkv2<4><<<63 * 3, 256, 0, stream>>>(wsT + T_nlWQ + wo, wsT + T_nlWK + wo,
                                          wsT + T_nlWV + wo,
                                          nullptr, nullptr, nullptr,
                                          xi, qb, kb, vb);
    k_tka_attn_f<<<NB * EL, 512, 0, stream>>>(xi, qb, kb, vb,
        grel + (size_t)L * (NB * NH * EL * EL), gib + (size_t)L * (NB * NH * EL),
        nl_al + L * 8, nl_be + L * 8, nl_ga + L * 8,
        wsT + T_nlWO + wo, nl_bO + L * DM, xo);
  }

  k_invemb<<<NB * NT, 256, 0, stream>>>(wsT + T_inv, inv_b, encP, tws, enc2);

  // ---- encoder layer 0: dense (all 1040 rows feed layer-1 K/V) ----
  k_qkv2<8><<<130 * 3, 256, 0, stream>>>(wsT + T_elWq, wsT + T_elWk, wsT + T_elWv,
                                         el_bq, el_bk, el_bv,
                                         enc2, qb, kb, vb);
  k_enc_attn_f<<<NB * 130, 512, 0, stream>>>(qb, kb, vb, wsT + T_elWo, el_bo,
                                             n1g, n1b, enc2, xn, 130);
  k_ffn1<<<130 * 4, 256, 0, stream>>>(wsT + T_elW1, el_b1, xn, y1, 0);
  k_ffn2f<<<260, 512, 0, stream>>>(wsT + T_elW2, el_b2, n2g, n2b, y1, xn, enc2, 0);

  // ---- encoder layer 1: pruned — only rows [b*NT, b*NT+24) reach k_final --
  {
    size_t wo = (size_t)DM * DM;
    size_t bo = (size_t)DM;
    size_t fo = (size_t)DFF * DM;
    k_qkv_l1<<<272, 256, 0, stream>>>(wsT + T_elWq + wo, wsT + T_elWk + wo,
                                      wsT + T_elWv + wo,
                                      el_bq + bo, el_bk + bo, el_bv + bo,
                                      enc2, qb, kb, vb);
    k_enc_attn_f<<<NB * 12, 512, 0, stream>>>(qb, kb, vb, wsT + T_elWo + wo,
                                              el_bo + bo, n1g + bo, n1b + bo,
                                              enc2, xn, 12);
    k_ffn1<<<12 * 4, 256, 0, stream>>>(wsT + T_elW1 + fo, el_b1 + DFF, xn, y1, 3);
    k_ffn2f<<<NB * 6, 512, 0, stream>>>(wsT + T_elW2 + fo, el_b2 + bo,
                                        n2g + bo, n2b + bo, y1, xn, enc2, 6);
  }

  k_final<<<NB * CIN, 256, 0, stream>>>(norm_g, norm_b, wsT + T_proj, proj_b,
                                        enc2, stdev, means, (float*)d_out);
}

// Round 10
// 412.965 us; speedup vs baseline: 1.0391x; 1.0391x over previous
//
#include <hip/hip_runtime.h>
#include <hip/hip_bf16.h>

#define NB 4
#define SEQ 512
#define CIN 21
#define TDIM 4
#define DM 256
#define NH 8
#define PLEN 16
#define PSTR 8
#define EL 63
#define DFF 1024
#define PRED 96
#define NT 260
#define EPSV 1e-5f

// transposed-weight workspace offsets (floats)
#define T_nlWQ 0
#define T_nlWK 131072
#define T_nlWV 262144
#define T_nlWO 393216
#define T_elWq 524288
#define T_elWk 655360
#define T_elWv 786432
#define T_elWo 917504
#define T_elW1 1048576
#define T_elW2 1572864
#define T_inv  2097152
#define T_proj 2113280
#define T_tok  2137856
#define T_pat  2153984

// ---------------- helpers --------------------------------------------------
__device__ __forceinline__ float2 meanvar256(float v, float* sb) {
  __syncthreads();
  float s1 = v, s2 = v * v;
  #pragma unroll
  for (int off = 32; off > 0; off >>= 1) {
    s1 += __shfl_down(s1, off, 64);
    s2 += __shfl_down(s2, off, 64);
  }
  int wid = threadIdx.x >> 6, lane = threadIdx.x & 63;
  if (lane == 0) { sb[wid * 2] = s1; sb[wid * 2 + 1] = s2; }
  __syncthreads();
  float m = (sb[0] + sb[2] + sb[4] + sb[6]) * (1.0f / 256.0f);
  float q = (sb[1] + sb[3] + sb[5] + sb[7]) * (1.0f / 256.0f);
  return make_float2(m, q - m * m);
}

__device__ __forceinline__ void load16f(const float* p, float* o) {
  const float4* q = reinterpret_cast<const float4*>(p);
  float4 a = q[0], b = q[1], c = q[2], d = q[3];
  o[0]=a.x; o[1]=a.y; o[2]=a.z; o[3]=a.w;
  o[4]=b.x; o[5]=b.y; o[6]=b.z; o[7]=b.w;
  o[8]=c.x; o[9]=c.y; o[10]=c.z; o[11]=c.w;
  o[12]=d.x; o[13]=d.y; o[14]=d.z; o[15]=d.w;
}

__device__ __forceinline__ float dot32(const float4* a, const float4* b) {
  float s = 0.f;
  #pragma unroll
  for (int i = 0; i < 8; ++i) {
    float4 x = a[i], y = b[i];
    s += x.x*y.x + x.y*y.y + x.z*y.z + x.w*y.w;
  }
  return s;
}

// ---- K0: weight transpose (3128) + RevIN stats/tws (88) + g_rel (2016) ---
__global__ void __launch_bounds__(256) k_prep(
    const float* __restrict__ nlWQ, const float* __restrict__ nlWK,
    const float* __restrict__ nlWV, const float* __restrict__ nlWO,
    const float* __restrict__ eWq, const float* __restrict__ eWk,
    const float* __restrict__ eWv, const float* __restrict__ eWo,
    const float* __restrict__ eW1, const float* __restrict__ eW2,
    const float* __restrict__ invW, const float* __restrict__ projW,
    const float* __restrict__ tokW, const float* __restrict__ patW,
    float* __restrict__ wt,
    const float* __restrict__ x, const float* __restrict__ xm,
    float* __restrict__ means, float* __restrict__ stdev,
    float* __restrict__ tout,
    const float* __restrict__ mu_r, const float* __restrict__ sg_r,
    const float* __restrict__ w_r,
    const float* __restrict__ mu_a, const float* __restrict__ sg_a,
    const float* __restrict__ w_a,
    float* __restrict__ grel, float* __restrict__ gib) {
  __shared__ float smem[32 * 33];
  int blk = blockIdx.x;
  int t = threadIdx.x;

  if (blk < 3128) {
    // ----- weight transpose (32x32 LDS tiles) -----
    const float* src; float* dst; int R, C, tr, tc;
    if (blk < 1024) {                 // 16 square [256][256] mats
      int m = blk >> 6, tile = blk & 63;
      tr = tile >> 3; tc = tile & 7; R = 256; C = 256;
      int p = m >> 1, l = m & 1;
      const float* bases[8] = {nlWQ, nlWK, nlWV, nlWO, eWq, eWk, eWv, eWo};
      const int offs[8] = {T_nlWQ, T_nlWK, T_nlWV, T_nlWO, T_elWq, T_elWk, T_elWv, T_elWo};
      src = bases[p] + l * 65536;
      dst = wt + offs[p] + l * 65536;
    } else if (blk < 1536) {          // W1 [1024][256] x2
      int q = blk - 1024; int l = q >> 8, s = q & 255;
      tr = s >> 3; tc = s & 7; R = 1024; C = 256;
      src = eW1 + l * 262144; dst = wt + T_elW1 + l * 262144;
    } else if (blk < 2048) {          // W2 [256][1024] x2
      int q = blk - 1536; int l = q >> 8, s = q & 255;
      tr = s >> 5; tc = s & 31; R = 256; C = 1024;
      src = eW2 + l * 262144; dst = wt + T_elW2 + l * 262144;
    } else if (blk < 3072) {          // patch_W [256][4096]
      int q = blk - 2048; tr = q >> 7; tc = q & 127; R = 256; C = 4096;
      src = patW; dst = wt + T_pat;
    } else if (blk < 3088) {          // inv_W [256][63]
      int q = blk - 3072; tr = q >> 1; tc = q & 1; R = 256; C = 63;
      src = invW; dst = wt + T_inv;
    } else if (blk < 3112) {          // proj_W [96][256]
      int q = blk - 3088; tr = q >> 3; tc = q & 7; R = 96; C = 256;
      src = projW; dst = wt + T_proj;
    } else {                          // tok_W [256][63]
      int q = blk - 3112; tr = q >> 1; tc = q & 1; R = 256; C = 63;
      src = tokW; dst = wt + T_tok;
    }
    float (*ts)[33] = (float(*)[33])smem;
    int tx = t & 31, ty = t >> 5;
    #pragma unroll
    for (int i = 0; i < 4; ++i) {
      int r = tr * 32 + ty + i * 8, c = tc * 32 + tx;
      ts[ty + i * 8][tx] = (c < C) ? src[(size_t)r * C + c] : 0.f;
    }
    __syncthreads();
    #pragma unroll
    for (int i = 0; i < 4; ++i) {
      int c = tc * 32 + ty + i * 8, r = tr * 32 + tx;
      if (c < C) dst[(size_t)c * R + r] = ts[tx][ty + i * 8];
    }
  } else if (blk < 3216) {
    // ----- RevIN stats (84) + patch-time means (4) -----
    int sblk = blk - 3128;
    if (sblk < NB * CIN) {
      int b = sblk / CIN, c = sblk % CIN;
      const float* p = x + (size_t)b * SEQ * CIN + c;
      float v0 = p[t * CIN];
      float v1 = p[(t + 256) * CIN];
      float s1 = v0 + v1, s2 = v0 * v0 + v1 * v1;
      float* sb = smem;
      #pragma unroll
      for (int off = 32; off > 0; off >>= 1) {
        s1 += __shfl_down(s1, off, 64);
        s2 += __shfl_down(s2, off, 64);
      }
      int wid = t >> 6, lane = t & 63;
      if (lane == 0) { sb[wid * 2] = s1; sb[wid * 2 + 1] = s2; }
      __syncthreads();
      if (t == 0) {
        float a = sb[0] + sb[2] + sb[4] + sb[6];
        float q = sb[1] + sb[3] + sb[5] + sb[7];
        float m = a * (1.0f / 512.0f);
        float var = q * (1.0f / 512.0f) - m * m;
        means[sblk] = m;
        stdev[sblk] = sqrtf(var + EPSV);
      }
    } else {
      int idx = (sblk - NB * CIN) * 256 + t;
      if (idx >= NB * EL * TDIM) return;
      int b = idx / (EL * TDIM), r = idx % (EL * TDIM);
      int l = r >> 2, ti = r & 3;
      const float* p = xm + (size_t)b * SEQ * TDIM + (size_t)l * PSTR * TDIM + ti;
      float s = 0.f;
      #pragma unroll
      for (int k = 0; k < PLEN; ++k) s += p[k * TDIM];
      tout[idx] = s * (1.f / 16.f);
    }
  } else {
    // ----- g_rel + g_abs, both layers; s_t computed inline from xm -----
    int gblk = blk - 3216;                   // L*(NB*252) + b*252 + chunk
    int L = gblk / (NB * 252);
    int rem0 = gblk % (NB * 252);
    int b = rem0 / 252, chunk = rem0 % 252;
    int po = L * 4096;
    float* grelL = grel + (size_t)L * (NB * NH * EL * EL);
    float* gibL  = gib + (size_t)L * (NB * NH * EL);
    int h = t >> 5, dh = t & 31;
    float* s_t = smem;
    if (t < EL * TDIM) {
      int l = t >> 2, ti = t & 3;
      const float* p = xm + (size_t)b * SEQ * TDIM + (size_t)l * PSTR * TDIM + ti;
      float s = 0.f;
      #pragma unroll
      for (int k = 0; k < PLEN; ++k) s += p[k * TDIM];
      s_t[t] = s * (1.f / 16.f);
    }
    float pm[16], pc[16], pw[16];
    load16f(mu_r + po + (size_t)t * 16, pm);
    load16f(sg_r + po + (size_t)t * 16, pc);
    load16f(w_r  + po + (size_t)t * 16, pw);
    #pragma unroll
    for (int p = 0; p < 16; ++p) pc[p] = -0.5f / (pc[p] * pc[p]);
    __syncthreads();
    #pragma unroll 1
    for (int q = 0; q < 8; ++q) {
      int p = chunk * 8 + q;                 // 2016 (i<=j) pairs
      int i = (int)((127.0f - sqrtf(16129.0f - 8.0f * (float)p)) * 0.5f);
      while (i * (127 - i) / 2 > p) --i;
      while ((i + 1) * (126 - i) / 2 <= p) ++i;
      int j = i + (p - i * (127 - i) / 2);
      float dvv[4];
      dvv[0] = fabsf(s_t[i*4+0] - s_t[j*4+0]);
      dvv[1] = fabsf(s_t[i*4+1] - s_t[j*4+1]);
      dvv[2] = fabsf(s_t[i*4+2] - s_t[j*4+2]);
      dvv[3] = fabsf(s_t[i*4+3] - s_t[j*4+3]);
      float srel = 0.f;
      #pragma unroll
      for (int tt = 0; tt < 4; ++tt)
        #pragma unroll
        for (int k = 0; k < 4; ++k) {
          int pp = tt * 4 + k;
          float df = dvv[tt] - pm[pp];
          srel += pw[pp] * __expf(pc[pp] * df * df);
        }
      #pragma unroll
      for (int m = 1; m < 32; m <<= 1) srel += __shfl_xor(srel, m, 64);
      if (dh == 0) {
        float v = srel * (1.f / 32.f);
        grelL[(((size_t)b * NH + h) * EL + i) * EL + j] = v;
        grelL[(((size_t)b * NH + h) * EL + j) * EL + i] = v;
      }
    }
    if (chunk < EL) {
      load16f(mu_a + po + (size_t)t * 16, pm);
      load16f(sg_a + po + (size_t)t * 16, pc);
      load16f(w_a  + po + (size_t)t * 16, pw);
      #pragma unroll
      for (int p = 0; p < 16; ++p) pc[p] = -0.5f / (pc[p] * pc[p]);
      int i = chunk;
      float tiv[4] = {s_t[i*4+0], s_t[i*4+1], s_t[i*4+2], s_t[i*4+3]};
      float sabs = 0.f;
      #pragma unroll
      for (int tt = 0; tt < 4; ++tt)
        #pragma unroll
        for (int k = 0; k < 4; ++k) {
          int pp = tt * 4 + k;
          float df = tiv[tt] - pm[pp];
          sabs += pw[pp] * __expf(pc[pp] * df * df);
        }
      #pragma unroll
      for (int m = 1; m < 32; m <<= 1) sabs += __shfl_xor(sabs, m, 64);
      if (dh == 0) gibL[((size_t)b * NH + h) * EL + i] = sabs * (1.f / 32.f);
    }
  }
}

// ---- K3a: token conv + PE (tokWT [63][256] coalesced) --------------------
__global__ void __launch_bounds__(256) k_tokconv(
    const float* __restrict__ x, const float* __restrict__ tokWT,
    const float* __restrict__ means, const float* __restrict__ stdev,
    float* __restrict__ enc1) {
  int bi = blockIdx.x;                       // b*64 + sg
  int b = bi >> 6, sg = bi & 63;
  int s0 = sg * 8;
  __shared__ float sxr[10 * CIN];
  int t = threadIdx.x;
  if (t < 10 * CIN) {
    int li = t / CIN, c = t % CIN;
    int row = (s0 - 1 + li + SEQ) & 511;
    sxr[t] = (x[(size_t)b * SEQ * CIN + row * CIN + c] - means[b * CIN + c])
             / stdev[b * CIN + c];
  }
  __syncthreads();
  int d = t;
  float wreg[63];
  #pragma unroll
  for (int q = 0; q < 63; ++q) wreg[q] = tokWT[q * DM + d];
  int de = d & ~1;
  float dv = expf((float)de * (-9.210340371976184f / 256.0f));
  bool isodd = (d & 1);
  #pragma unroll 1
  for (int k = 0; k < 8; ++k) {
    float acc = 0.f;
    const float* sr = sxr + k * CIN;
    #pragma unroll
    for (int c = 0; c < CIN; ++c) {
      acc += sr[c]           * wreg[c * 3 + 0];
      acc += sr[CIN + c]     * wreg[c * 3 + 1];
      acc += sr[2 * CIN + c] * wreg[c * 3 + 2];
    }
    float ang = (float)(s0 + k) * dv;
    float pe = isodd ? cosf(ang) : sinf(ang);
    enc1[((size_t)b * SEQ + s0 + k) * DM + d] = acc + pe;
  }
}

// ---- K3b: patch conv partials (patWT [4096][256], batched loads) ---------
__global__ void __launch_bounds__(256) k_patch_part(
    const float* __restrict__ enc1, const float* __restrict__ pWT,
    float* __restrict__ pbuf) {
  int bi = blockIdx.x;
  int pg = bi >> 3, kc = bi & 7;
  int p0 = pg * 6;
  __shared__ __align__(16) float sA[6 * 32 * 20];
  int t = threadIdx.x;
  for (int idx = t; idx < 6 * 32 * PLEN; idx += 256) {
    int pp = idx >> 9;
    int rem = idx & 511;
    int c = rem >> 4, k = rem & 15;
    int p = p0 + pp;
    int b = p / EL, l = p % EL;
    sA[pp * 640 + c * 20 + k] =
        enc1[((size_t)b * SEQ + l * PSTR + k) * DM + kc * 32 + c];
  }
  __syncthreads();
  int d = t;
  const float* wb = pWT + (size_t)(kc * 32 * PLEN) * DM + d;
  float acc[6] = {0.f, 0.f, 0.f, 0.f, 0.f, 0.f};
  #pragma unroll 1
  for (int kk0 = 0; kk0 < 512; kk0 += 8) {
    float w[8];
    #pragma unroll
    for (int q = 0; q < 8; ++q) w[q] = wb[(size_t)(kk0 + q) * DM];
    #pragma unroll
    for (int q = 0; q < 8; ++q) {
      int kk = kk0 + q;
      const float* sa = sA + (kk >> 4) * 20 + (kk & 15);
      acc[0] += sa[0 * 640] * w[q];
      acc[1] += sa[1 * 640] * w[q];
      acc[2] += sa[2 * 640] * w[q];
      acc[3] += sa[3 * 640] * w[q];
      acc[4] += sa[4 * 640] * w[q];
      acc[5] += sa[5 * 640] * w[q];
    }
  }
  const int S = NB * EL * DM;
  #pragma unroll
  for (int pp = 0; pp < 6; ++pp)
    pbuf[(size_t)kc * S + (size_t)(p0 + pp) * DM + d] = acc[pp];
}

// ---- K3c: reduce partials + bias -----------------------------------------
__global__ void k_patch_red(const float* __restrict__ pbuf, const float* __restrict__ pb,
                            float* __restrict__ encP) {
  int p = blockIdx.x, t = threadIdx.x;
  const int S = NB * EL * DM;
  float v = 0.f;
  #pragma unroll
  for (int s = 0; s < 8; ++s) v += pbuf[(size_t)s * S + (size_t)p * DM + t];
  encP[(size_t)p * DM + t] = v + pb[t];
}

// ---- QKV: WT [256][256], reg-tile 4 cols x R rows, K-split 4, batch 4 ----
// ktm: if nonzero, K output is written transposed [b][256][NT] (encoder path).
template<int R>
__global__ void __launch_bounds__(256) k_qkv2(
    const float* __restrict__ WqT, const float* __restrict__ WkT,
    const float* __restrict__ WvT,
    const float* __restrict__ bq, const float* __restrict__ bk,
    const float* __restrict__ bv,
    const float* __restrict__ xin,
    float* __restrict__ qo, float* __restrict__ ko, float* __restrict__ vo,
    int ktm) {
  int bi = blockIdx.x;
  int rg = bi / 3, mat = bi % 3;
  int row0 = rg * R;
  __shared__ __align__(16) float sx[R * DM];
  __shared__ __align__(16) float sp[3 * R * DM];
  int t = threadIdx.x;
  int colg = t & 63, kq = t >> 6;
  #pragma unroll
  for (int i = 0; i < R / 4; ++i)
    reinterpret_cast<float4*>(sx)[t + i * 256] =
        reinterpret_cast<const float4*>(xin + (size_t)row0 * DM)[t + i * 256];
  __syncthreads();
  const float* WT = (mat == 0) ? WqT : (mat == 1) ? WkT : WvT;
  const float* bias = (mat == 0) ? bq : (mat == 1) ? bk : bv;
  float* out = (mat == 0) ? qo : (mat == 1) ? ko : vo;
  float acc[R][4];
  #pragma unroll
  for (int r = 0; r < R; ++r) { acc[r][0]=0.f; acc[r][1]=0.f; acc[r][2]=0.f; acc[r][3]=0.f; }
  const float* xb = sx + kq * 64;
  const float4* wp = reinterpret_cast<const float4*>(WT + (size_t)(kq * 64) * DM) + colg;
  #pragma unroll 1
  for (int k0 = 0; k0 < 64; k0 += 4) {
    float4 w[4];
    #pragma unroll
    for (int q = 0; q < 4; ++q) w[q] = wp[(size_t)(k0 + q) * 64];
    #pragma unroll
    for (int q = 0; q < 4; ++q)
      #pragma unroll
      for (int r = 0; r < R; ++r) {
        float xv = xb[r * DM + k0 + q];
        acc[r][0] += xv * w[q].x; acc[r][1] += xv * w[q].y;
        acc[r][2] += xv * w[q].z; acc[r][3] += xv * w[q].w;
      }
  }
  if (kq) {
    #pragma unroll
    for (int r = 0; r < R; ++r)
      reinterpret_cast<float4*>(sp)[((kq - 1) * R + r) * 64 + colg] =
          make_float4(acc[r][0], acc[r][1], acc[r][2], acc[r][3]);
  }
  __syncthreads();
  if (kq == 0) {
    float4 b4 = bias ? reinterpret_cast<const float4*>(bias)[colg]
                     : make_float4(0.f, 0.f, 0.f, 0.f);
    const float4* sp4 = reinterpret_cast<const float4*>(sp);
    #pragma unroll
    for (int r = 0; r < R; ++r) {
      float4 p0 = sp4[(0 * R + r) * 64 + colg];
      float4 p1 = sp4[(1 * R + r) * 64 + colg];
      float4 p2 = sp4[(2 * R + r) * 64 + colg];
      float4 o;
      o.x = acc[r][0] + p0.x + p1.x + p2.x + b4.x;
      o.y = acc[r][1] + p0.y + p1.y + p2.y + b4.y;
      o.z = acc[r][2] + p0.z + p1.z + p2.z + b4.z;
      o.w = acc[r][3] + p0.w + p1.w + p2.w + b4.w;
      if (ktm && mat == 1) {
        int gr = row0 + r, bb2 = gr / NT, jj2 = gr % NT;
        float* kd = out + (size_t)bb2 * (DM * NT) + jj2;
        kd[(size_t)(colg * 4 + 0) * NT] = o.x;
        kd[(size_t)(colg * 4 + 1) * NT] = o.y;
        kd[(size_t)(colg * 4 + 2) * NT] = o.z;
        kd[(size_t)(colg * 4 + 3) * NT] = o.w;
      } else {
        reinterpret_cast<float4*>(out + (size_t)(row0 + r) * DM)[colg] = o;
      }
    }
  }
}

// ---- QKV layer-1: K^T full (1040 rows) + V full + Q first 24 rows per b --
__global__ void __launch_bounds__(256) k_qkv_l1(
    const float* __restrict__ WqT, const float* __restrict__ WkT,
    const float* __restrict__ WvT,
    const float* __restrict__ bq, const float* __restrict__ bk,
    const float* __restrict__ bv,
    const float* __restrict__ xin,
    float* __restrict__ qo, float* __restrict__ ko, float* __restrict__ vo) {
  int bi = blockIdx.x;
  const float* WT; const float* bias; float* out; int row0; int ktm = 0;
  if (bi < 130)      { WT = WkT; bias = bk; out = ko; row0 = bi * 8; ktm = 1; }
  else if (bi < 260) { WT = WvT; bias = bv; out = vo; row0 = (bi - 130) * 8; }
  else {             // 12 blocks: Q for rows b*NT + [0,24)
    int gq = bi - 260;
    WT = WqT; bias = bq; out = qo;
    row0 = (gq / 3) * NT + (gq % 3) * 8;
  }
  __shared__ __align__(16) float sx[8 * DM];
  __shared__ __align__(16) float sp[3 * 8 * DM];
  int t = threadIdx.x;
  int colg = t & 63, kq = t >> 6;
  #pragma unroll
  for (int i = 0; i < 2; ++i)
    reinterpret_cast<float4*>(sx)[t + i * 256] =
        reinterpret_cast<const float4*>(xin + (size_t)row0 * DM)[t + i * 256];
  __syncthreads();
  float acc[8][4];
  #pragma unroll
  for (int r = 0; r < 8; ++r) { acc[r][0]=0.f; acc[r][1]=0.f; acc[r][2]=0.f; acc[r][3]=0.f; }
  const float* xb = sx + kq * 64;
  const float4* wp = reinterpret_cast<const float4*>(WT + (size_t)(kq * 64) * DM) + colg;
  #pragma unroll 1
  for (int k0 = 0; k0 < 64; k0 += 4) {
    float4 w[4];
    #pragma unroll
    for (int q = 0; q < 4; ++q) w[q] = wp[(size_t)(k0 + q) * 64];
    #pragma unroll
    for (int q = 0; q < 4; ++q)
      #pragma unroll
      for (int r = 0; r < 8; ++r) {
        float xv = xb[r * DM + k0 + q];
        acc[r][0] += xv * w[q].x; acc[r][1] += xv * w[q].y;
        acc[r][2] += xv * w[q].z; acc[r][3] += xv * w[q].w;
      }
  }
  if (kq) {
    #pragma unroll
    for (int r = 0; r < 8; ++r)
      reinterpret_cast<float4*>(sp)[((kq - 1) * 8 + r) * 64 + colg] =
          make_float4(acc[r][0], acc[r][1], acc[r][2], acc[r][3]);
  }
  __syncthreads();
  if (kq == 0) {
    float4 b4 = reinterpret_cast<const float4*>(bias)[colg];
    const float4* sp4 = reinterpret_cast<const float4*>(sp);
    #pragma unroll
    for (int r = 0; r < 8; ++r) {
      float4 p0 = sp4[(0 * 8 + r) * 64 + colg];
      float4 p1 = sp4[(1 * 8 + r) * 64 + colg];
      float4 p2 = sp4[(2 * 8 + r) * 64 + colg];
      float4 o;
      o.x = acc[r][0] + p0.x + p1.x + p2.x + b4.x;
      o.y = acc[r][1] + p0.y + p1.y + p2.y + b4.y;
      o.z = acc[r][2] + p0.z + p1.z + p2.z + b4.z;
      o.w = acc[r][3] + p0.w + p1.w + p2.w + b4.w;
      if (ktm) {
        int gr = row0 + r, bb2 = gr / NT, jj2 = gr % NT;
        float* kd = out + (size_t)bb2 * (DM * NT) + jj2;
        kd[(size_t)(colg * 4 + 0) * NT] = o.x;
        kd[(size_t)(colg * 4 + 1) * NT] = o.y;
        kd[(size_t)(colg * 4 + 2) * NT] = o.z;
        kd[(size_t)(colg * 4 + 3) * NT] = o.w;
      } else {
        reinterpret_cast<float4*>(out + (size_t)(row0 + r) * DM)[colg] = o;
      }
    }
  }
}

// ---- TKA attention + fused Wo^T, 512 threads, split PV / split-K Wo ------
__global__ void __launch_bounds__(512) k_tka_attn_f(
    const float* __restrict__ xin, const float* __restrict__ qw,
    const float* __restrict__ kw, const float* __restrict__ vw,
    const float* __restrict__ grel, const float* __restrict__ gib,
    const float* __restrict__ alpha, const float* __restrict__ beta,
    const float* __restrict__ gamma,
    const float* __restrict__ WOT, const float* __restrict__ bO,
    float* __restrict__ xout) {
  int bi = blockIdx.x;                       // b*63+i
  int b = bi / EL, i = bi % EL;
  int t = threadIdx.x;
  __shared__ __align__(16) float sQX[2 * DM];
  __shared__ float sP[NH * 64];
  __shared__ __align__(16) float sO[DM];
  __shared__ float sPV[DM];
  if (t < 2 * DM)
    sQX[t] = (t < DM) ? qw[(size_t)bi * DM + t] : xin[(size_t)bi * DM + (t - DM)];
  __syncthreads();
  {
    int tile = t >> 8, h = (t >> 5) & 7, jj = t & 31;
    int j = tile * 32 + jj;
    bool valid = (j < EL);
    int jc = valid ? j : (EL - 1);
    float gi = gib[((size_t)b * NH + h) * EL + i];
    float al = alpha[h], be = beta[h], ga = gamma[h];
    const float* grow = grel + (((size_t)b * NH + h) * EL + i) * EL;
    const float4* kp = reinterpret_cast<const float4*>(
        kw + (size_t)(b * EL + jc) * DM + h * 32);
    const float4* xp = reinterpret_cast<const float4*>(
        xin + (size_t)(b * EL + jc) * DM + h * 32);
    float4 kf[8], xf[8];
    #pragma unroll
    for (int q = 0; q < 8; ++q) { kf[q] = kp[q]; xf[q] = xp[q]; }
    float qk  = dot32(reinterpret_cast<const float4*>(sQX + h * 32), kf);
    float pij = dot32(reinterpret_cast<const float4*>(sQX + DM + h * 32), xf);
    float A = al * pij * (2.f * gi) + be * pij * grow[jc] + ga;
    const float scale = 0.17677669529663687f;
    sP[h * 64 + tile * 32 + jj] = valid ? (qk * scale * A) : -1e30f;
  }
  __syncthreads();
  {
    int h = t >> 6, dh = t & 63;               // one wave per head
    float v = sP[h * 64 + dh];
    float m = v;
    #pragma unroll
    for (int s = 1; s < 64; s <<= 1) m = fmaxf(m, __shfl_xor(m, s, 64));
    float e = __expf(v - m);
    float ssum = e;
    #pragma unroll
    for (int s = 1; s < 64; s <<= 1) ssum += __shfl_xor(ssum, s, 64);
    sP[h * 64 + dh] = e / ssum;                // dh=63 -> 0
  }
  __syncthreads();
  {
    int ch = t & 255, jh = t >> 8, hh = ch >> 5;
    float acc = 0.f;
    const float* pp = sP + hh * 64 + jh * 32;
    int jbase = jh * 32;
    #pragma unroll 1
    for (int j0 = 0; j0 < 32; j0 += 8) {
      float v[8];
      #pragma unroll
      for (int q = 0; q < 8; ++q) {
        int jx = jbase + j0 + q;
        if (jx > 62) jx = 62;                  // j=63 weight is 0; avoid stale row
        v[q] = vw[(size_t)(b * EL + jx) * DM + ch];
      }
      #pragma unroll
      for (int q = 0; q < 8; ++q) acc += pp[j0 + q] * v[q];
    }
    if (jh) sPV[ch] = acc;
    __syncthreads();
    if (!jh) sO[ch] = acc + sPV[ch];
  }
  __syncthreads();
  {
    int col = t & 255, kh = t >> 8;
    float acc = 0.f;
    const float* wc = WOT + (size_t)(kh * 128) * DM + col;
    const float* sx = sO + kh * 128;
    #pragma unroll 1
    for (int k0 = 0; k0 < 128; k0 += 8) {
      float w[8];
      #pragma unroll
      for (int q = 0; q < 8; ++q) w[q] = wc[(size_t)(k0 + q) * DM];
      #pragma unroll
      for (int q = 0; q < 8; ++q) acc += sx[k0 + q] * w[q];
    }
    if (kh) sPV[col] = acc;
    __syncthreads();
    if (!kh) xout[(size_t)bi * DM + col] = acc + sPV[col] + bO[col];
  }
}

// ---- inverted embedding (invWT [63][256], batched) -----------------------
__global__ void k_invemb(const float* __restrict__ invWT, const float* __restrict__ invb,
                         const float* __restrict__ encP, const float* __restrict__ tws,
                         float* __restrict__ enc2) {
  int bi = blockIdx.x;                       // b*260+n
  int b = bi / NT, n = bi % NT;
  __shared__ float sx[EL];
  int t = threadIdx.x;
  if (t < EL) {
    sx[t] = (n < DM) ? encP[(size_t)(b * EL + t) * DM + n]
                     : tws[b * EL * TDIM + t * TDIM + (n - DM)];
  }
  __syncthreads();
  float acc = 0.f;
  #pragma unroll 1
  for (int l0 = 0; l0 < 63; l0 += 9) {
    float w[9];
    #pragma unroll
    for (int q = 0; q < 9; ++q) w[q] = invWT[(size_t)(l0 + q) * DM + t];
    #pragma unroll
    for (int q = 0; q < 9; ++q) acc += sx[l0 + q] * w[q];
  }
  enc2[(size_t)bi * DM + t] = acc + invb[t];
}

// ---- encoder attention, 512 thr, 2 rows/block, K^T coalesced scores ------
// kw is K^T [b][256][260]. tpb: i-tiles (2 rows) per batch (130 / 12).
__global__ void __launch_bounds__(512) k_enc_attn_f(
    const float* __restrict__ qw, const float* __restrict__ kw,
    const float* __restrict__ vw,
    const float* __restrict__ WoT, const float* __restrict__ bo,
    const float* __restrict__ g, const float* __restrict__ bb,
    const float* __restrict__ resin, float* __restrict__ out, int tpb) {
  int blk = blockIdx.x;                      // b*tpb + tile
  int b = blk / tpb, it = blk % tpb;
  int i0 = it * 2;
  int t = threadIdx.x;

  __shared__ __align__(16) float sQ[2 * DM]; // Q rows; later normalized PV out
  __shared__ float sS[2 * NH * NT];          // 16.6 KB
  __shared__ float sL[2 * NH];
  __shared__ __align__(16) float sPV[2 * DM];
  __shared__ float sb[8];

  for (int idx = t; idx < 2 * DM; idx += 512)
    sQ[idx] = qw[((size_t)(b * NT + i0)) * DM + idx];
  __syncthreads();

  const float scale = 0.17677669529663687f;
  {
    // scores: thread t owns column j=t (<260); coalesced K^T reads
    if (t < NT) {
      const float* kT = kw + (size_t)b * (DM * NT) + t;
      #pragma unroll
      for (int h = 0; h < NH; ++h) {
        float a0 = 0.f, a1 = 0.f;
        float kv[8];
        #pragma unroll
        for (int d0 = 0; d0 < 32; d0 += 8) {
          #pragma unroll
          for (int q = 0; q < 8; ++q)
            kv[q] = kT[(size_t)(h * 32 + d0 + q) * NT];
          #pragma unroll
          for (int q = 0; q < 8; ++q) {
            a0 += sQ[0 * DM + h * 32 + d0 + q] * kv[q];
            a1 += sQ[1 * DM + h * 32 + d0 + q] * kv[q];
          }
        }
        sS[(0 * NH + h) * NT + t] = a0 * scale;
        sS[(1 * NH + h) * NT + t] = a1 * scale;
      }
    }
  }
  __syncthreads();
  {
    int combo = t >> 5, lane32 = t & 31;     // 16 combos x 32 lanes
    float* row = sS + (size_t)combo * NT;
    float m = -1e30f;
    for (int jx = lane32; jx < NT; jx += 32) m = fmaxf(m, row[jx]);
    #pragma unroll
    for (int s = 1; s < 32; s <<= 1) m = fmaxf(m, __shfl_xor(m, s, 32));
    float ssum = 0.f;
    for (int jx = lane32; jx < NT; jx += 32) {
      float e = __expf(row[jx] - m);
      row[jx] = e;
      ssum += e;
    }
    #pragma unroll
    for (int s = 1; s < 32; s <<= 1) ssum += __shfl_xor(ssum, s, 32);
    if (lane32 == 0) sL[combo] = ssum;
  }
  __syncthreads();
  {
    int ch = t & 255, jh = t >> 8, hh = ch >> 5;
    float o0 = 0.f, o1 = 0.f;
    const float* vbase = vw + ((size_t)(b * NT + jh * 130)) * DM + ch;
    const float* p0 = sS + (0 * NH + hh) * NT + jh * 130;
    const float* p1 = sS + (1 * NH + hh) * NT + jh * 130;
    #pragma unroll 1
    for (int j0 = 0; j0 < 130; j0 += 10) {
      float v[10];
      #pragma unroll
      for (int q = 0; q < 10; ++q) v[q] = vbase[(size_t)(j0 + q) * DM];
      #pragma unroll
      for (int q = 0; q < 10; ++q) {
        o0 += p0[j0 + q] * v[q]; o1 += p1[j0 + q] * v[q];
      }
    }
    if (jh) {
      sPV[0 * DM + ch] = o0; sPV[1 * DM + ch] = o1;
    }
    __syncthreads();
    if (!jh) {
      sQ[0 * DM + ch] = (o0 + sPV[0 * DM + ch]) / sL[0 * NH + hh];
      sQ[1 * DM + ch] = (o1 + sPV[1 * DM + ch]) / sL[1 * NH + hh];
    }
  }
  __syncthreads();
  {
    int col = t & 255, kh = t >> 8;
    float acc[2] = {0.f, 0.f};
    const float* wcol = WoT + (size_t)(kh * 128) * DM + col;
    const float* s0 = sQ + kh * 128;
    #pragma unroll 1
    for (int k0 = 0; k0 < 128; k0 += 8) {
      float w[8];
      #pragma unroll
      for (int q = 0; q < 8; ++q) w[q] = wcol[(size_t)(k0 + q) * DM];
      #pragma unroll
      for (int q = 0; q < 8; ++q) {
        acc[0] += s0[0 * DM + k0 + q] * w[q];
        acc[1] += s0[1 * DM + k0 + q] * w[q];
      }
    }
    if (kh) {
      sPV[0 * DM + col] = acc[0]; sPV[1 * DM + col] = acc[1];
    }
    __syncthreads();
    float ov[2] = {0.f, 0.f};
    float gg = g[col], bb2 = bb[col];
    if (!kh) {
      float bias = bo[col];
      #pragma unroll
      for (int r = 0; r < 2; ++r)
        ov[r] = acc[r] + sPV[r * DM + col] + bias
              + resin[((size_t)(b * NT + i0 + r)) * DM + col];
    }
    int wid = t >> 6, lane = t & 63;
    #pragma unroll 1
    for (int r = 0; r < 2; ++r) {
      float o = (!kh) ? ov[r] : 0.f;
      __syncthreads();
      float s1 = o, s2 = o * o;
      #pragma unroll
      for (int off = 32; off > 0; off >>= 1) {
        s1 += __shfl_down(s1, off, 64);
        s2 += __shfl_down(s2, off, 64);
      }
      if (lane == 0 && wid < 4) { sb[wid * 2] = s1; sb[wid * 2 + 1] = s2; }
      __syncthreads();
      float m = (sb[0] + sb[2] + sb[4] + sb[6]) * (1.f / 256.f);
      float q2 = (sb[1] + sb[3] + sb[5] + sb[7]) * (1.f / 256.f);
      float var = q2 - m * m;
      if (!kh)
        out[((size_t)(b * NT + i0 + r)) * DM + col] =
            (ov[r] - m) * rsqrtf(var + EPSV) * gg + bb2;
    }
  }
}

// ---- FFN1: gelu(x@W1.T+b1) via W1T, reg-tile, K-split 4, batch 4 ---------
// gpb: row-groups per batch (0 = dense 130 groups; 3 = pruned 24 rows/b)
__global__ void __launch_bounds__(256) k_ffn1(
    const float* __restrict__ W1T, const float* __restrict__ b1,
    const float* __restrict__ xn, float* __restrict__ y1, int gpb) {
  int bi = blockIdx.x;                       // rg*4 + fg
  int rg = bi >> 2, fg = bi & 3;
  int row0 = gpb ? ((rg / gpb) * NT + (rg % gpb) * 8) : rg * 8;
  __shared__ __align__(16) float sx[8 * DM];
  __shared__ __align__(16) float sp[3 * 8 * DM];
  int t = threadIdx.x;
  int colg = t & 63, kq = t >> 6;
  #pragma unroll
  for (int i = 0; i < 2; ++i)
    reinterpret_cast<float4*>(sx)[t + i * 256] =
        reinterpret_cast<const float4*>(xn + (size_t)row0 * DM)[t + i * 256];
  __syncthreads();
  int f = fg * 256 + colg * 4;
  float acc[8][4];
  #pragma unroll
  for (int r = 0; r < 8; ++r) { acc[r][0]=0.f; acc[r][1]=0.f; acc[r][2]=0.f; acc[r][3]=0.f; }
  const float* xb = sx + kq * 64;
  const float4* wp = reinterpret_cast<const float4*>(W1T + (size_t)(kq * 64) * DFF + f);
  #pragma unroll 1
  for (int k0 = 0; k0 < 64; k0 += 4) {
    float4 w[4];
    #pragma unroll
    for (int q = 0; q < 4; ++q) w[q] = wp[(size_t)(k0 + q) * 256];
    #pragma unroll
    for (int q = 0; q < 4; ++q)
      #pragma unroll
      for (int r = 0; r < 8; ++r) {
        float xv = xb[r * DM + k0 + q];
        acc[r][0] += xv * w[q].x; acc[r][1] += xv * w[q].y;
        acc[r][2] += xv * w[q].z; acc[r][3] += xv * w[q].w;
      }
  }
  if (kq) {
    #pragma unroll
    for (int r = 0; r < 8; ++r)
      reinterpret_cast<float4*>(sp)[((kq - 1) * 8 + r) * 64 + colg] =
          make_float4(acc[r][0], acc[r][1], acc[r][2], acc[r][3]);
  }
  __syncthreads();
  if (kq == 0) {
    float4 b4 = *reinterpret_cast<const float4*>(b1 + f);
    const float4* sp4 = reinterpret_cast<const float4*>(sp);
    #pragma unroll 1
    for (int r = 0; r < 8; ++r) {
      float4 p0 = sp4[(0 * 8 + r) * 64 + colg];
      float4 p1 = sp4[(1 * 8 + r) * 64 + colg];
      float4 p2 = sp4[(2 * 8 + r) * 64 + colg];
      float a0 = acc[r][0] + p0.x + p1.x + p2.x + b4.x;
      float a1 = acc[r][1] + p0.y + p1.y + p2.y + b4.y;
      float a2 = acc[r][2] + p0.z + p1.z + p2.z + b4.z;
      float a3 = acc[r][3] + p0.w + p1.w + p2.w + b4.w;
      float4 o;
      o.x = 0.5f * a0 * (1.f + erff(a0 * 0.70710678118654752f));
      o.y = 0.5f * a1 * (1.f + erff(a1 * 0.70710678118654752f));
      o.z = 0.5f * a2 * (1.f + erff(a2 * 0.70710678118654752f));
      o.w = 0.5f * a3 * (1.f + erff(a3 * 0.70710678118654752f));
      *reinterpret_cast<float4*>(y1 + (size_t)(row0 + r) * DFF + f) = o;
    }
  }
}

// ---- FFN2 fused: W2T, 4 rows/block, 512 thr, K-split 8, batch 8, +LN -----
// gpb: groups-of-4 per batch (0 = dense 260 blocks; 6 = pruned 24 rows/b)
__global__ void __launch_bounds__(512) k_ffn2f(
    const float* __restrict__ W2T, const float* __restrict__ b2,
    const float* __restrict__ g, const float* __restrict__ bb,
    const float* __restrict__ y1, const float* __restrict__ xn,
    float* __restrict__ out, int gpb) {
  int blk = blockIdx.x;
  int row0 = gpb ? ((blk / gpb) * NT + (blk % gpb) * 4) : blk * 4;
  __shared__ __align__(16) float sy[4 * DFF];    // 16 KB
  __shared__ __align__(16) float sp[7 * 4 * DM]; // 28 KB
  int t = threadIdx.x;
  int colg = t & 63, kq = t >> 6;                // kq 0..7
  #pragma unroll
  for (int i = 0; i < 2; ++i)
    reinterpret_cast<float4*>(sy)[t + i * 512] =
        reinterpret_cast<const float4*>(y1 + (size_t)row0 * DFF)[t + i * 512];
  __syncthreads();
  float acc[4][4];
  #pragma unroll
  for (int r = 0; r < 4; ++r) { acc[r][0]=0.f; acc[r][1]=0.f; acc[r][2]=0.f; acc[r][3]=0.f; }
  const float* yb = sy + kq * 128;
  const float4* wp = reinterpret_cast<const float4*>(W2T + (size_t)(kq * 128) * DM) + colg;
  #pragma unroll 1
  for (int k0 = 0; k0 < 128; k0 += 8) {
    float4 w[8];
    #pragma unroll
    for (int q = 0; q < 8; ++q) w[q] = wp[(size_t)(k0 + q) * 64];
    #pragma unroll
    for (int q = 0; q < 8; ++q)
      #pragma unroll
      for (int r = 0; r < 4; ++r) {
        float yv = yb[r * DFF + k0 + q];
        acc[r][0] += yv * w[q].x; acc[r][1] += yv * w[q].y;
        acc[r][2] += yv * w[q].z; acc[r][3] += yv * w[q].w;
      }
  }
  if (kq) {
    #pragma unroll
    for (int r = 0; r < 4; ++r)
      reinterpret_cast<float4*>(sp)[((kq - 1) * 4 + r) * 64 + colg] =
          make_float4(acc[r][0], acc[r][1], acc[r][2], acc[r][3]);
  }
  __syncthreads();
  if (kq == 0) {
    float4 b4 = reinterpret_cast<const float4*>(b2)[colg];
    float4 g4 = reinterpret_cast<const float4*>(g)[colg];
    float4 bb4 = reinterpret_cast<const float4*>(bb)[colg];
    const float4* sp4 = reinterpret_cast<const float4*>(sp);
    #pragma unroll 1
    for (int r = 0; r < 4; ++r) {
      float o0 = acc[r][0], o1 = acc[r][1], o2 = acc[r][2], o3 = acc[r][3];
      #pragma unroll
      for (int s = 0; s < 7; ++s) {
        float4 ps = sp4[(s * 4 + r) * 64 + colg];
        o0 += ps.x; o1 += ps.y; o2 += ps.z; o3 += ps.w;
      }
      float4 xr = reinterpret_cast<const float4*>(xn + (size_t)(row0 + r) * DM)[colg];
      o0 += b4.x + xr.x; o1 += b4.y + xr.y; o2 += b4.z + xr.z; o3 += b4.w + xr.w;
      float s1 = o0 + o1 + o2 + o3;
      float s2 = o0*o0 + o1*o1 + o2*o2 + o3*o3;
      #pragma unroll
      for (int m = 1; m < 64; m <<= 1) {
        s1 += __shfl_xor(s1, m, 64);
        s2 += __shfl_xor(s2, m, 64);
      }
      float mean = s1 * (1.f / 256.f);
      float var = s2 * (1.f / 256.f) - mean * mean;
      float rs = rsqrtf(var + EPSV);
      float4 o;
      o.x = (o0 - mean) * rs * g4.x + bb4.x;
      o.y = (o1 - mean) * rs * g4.y + bb4.y;
      o.z = (o2 - mean) * rs * g4.z + bb4.z;
      o.w = (o3 - mean) * rs * g4.w + bb4.w;
      reinterpret_cast<float4*>(out + (size_t)(row0 + r) * DM)[colg] = o;
    }
  }
}

// ---- final LN + projection (pWT [256][96], batched) + denorm -------------
__global__ void k_final(const float* __restrict__ g, const float* __restrict__ bb,
                        const float* __restrict__ pWT, const float* __restrict__ pb,
                        const float* __restrict__ enc2,
                        const float* __restrict__ stdev, const float* __restrict__ means,
                        float* __restrict__ out) {
  int bi = blockIdx.x;                       // b*21+c
  int b = bi / CIN, c = bi % CIN;
  __shared__ __align__(16) float sx[DM];
  __shared__ float sb[8];
  int t = threadIdx.x;
  float v = enc2[(size_t)(b * NT + c) * DM + t];
  float2 mv = meanvar256(v, sb);
  sx[t] = (v - mv.x) * rsqrtf(mv.y + EPSV) * g[t] + bb[t];
  __syncthreads();
  if (t < PRED) {
    float acc = 0.f;
    #pragma unroll 1
    for (int k0 = 0; k0 < DM; k0 += 8) {
      float w[8];
      #pragma unroll
      for (int q = 0; q < 8; ++q) w[q] = pWT[(size_t)(k0 + q) * PRED + t];
      #pragma unroll
      for (int q = 0; q < 8; ++q) acc += sx[k0 + q] * w[q];
    }
    float y = (acc + pb[t]) * stdev[bi] + means[bi];
    out[(size_t)b * PRED * CIN + t * CIN + c] = y;
  }
}

extern "C" void kernel_launch(void* const* d_in, const int* in_sizes, int n_in,
                              void* d_out, int out_size, void* d_ws, size_t ws_size,
                              hipStream_t stream) {
  const float* x_enc   = (const float*)d_in[0];
  const float* x_mark  = (const float*)d_in[1];
  const float* tok_W   = (const float*)d_in[4];
  const float* patch_W = (const float*)d_in[5];
  const float* patch_b = (const float*)d_in[6];
  const float* nl_WQ   = (const float*)d_in[7];
  const float* nl_WK   = (const float*)d_in[8];
  const float* nl_WV   = (const float*)d_in[9];
  const float* nl_WO   = (const float*)d_in[10];
  const float* nl_bO   = (const float*)d_in[11];
  const float* nl_mu_a = (const float*)d_in[12];
  const float* nl_sg_a = (const float*)d_in[13];
  const float* nl_w_a  = (const float*)d_in[14];
  const float* nl_mu_r = (const float*)d_in[15];
  const float* nl_sg_r = (const float*)d_in[16];
  const float* nl_w_r  = (const float*)d_in[17];
  const float* nl_al   = (const float*)d_in[18];
  const float* nl_be   = (const float*)d_in[19];
  const float* nl_ga   = (const float*)d_in[20];
  const float* inv_W   = (const float*)d_in[21];
  const float* inv_b   = (const float*)d_in[22];
  const float* el_Wq   = (const float*)d_in[23];
  const float* el_bq   = (const float*)d_in[24];
  const float* el_Wk   = (const float*)d_in[25];
  const float* el_bk   = (const float*)d_in[26];
  const float* el_Wv   = (const float*)d_in[27];
  const float* el_bv   = (const float*)d_in[28];
  const float* el_Wo   = (const float*)d_in[29];
  const float* el_bo   = (const float*)d_in[30];
  const float* el_W1   = (const float*)d_in[31];
  const float* el_b1   = (const float*)d_in[32];
  const float* el_W2   = (const float*)d_in[33];
  const float* el_b2   = (const float*)d_in[34];
  const float* n1g     = (const float*)d_in[35];
  const float* n1b     = (const float*)d_in[36];
  const float* n2g     = (const float*)d_in[37];
  const float* n2b     = (const float*)d_in[38];
  const float* norm_g  = (const float*)d_in[39];
  const float* norm_b  = (const float*)d_in[40];
  const float* proj_W  = (const float*)d_in[41];
  const float* proj_b  = (const float*)d_in[42];

  // workspace layout (floats)
  float* ws = (float*)d_ws;
  float* means = ws + 0;          //     96
  float* stdev = ws + 96;         //     96
  float* tws   = ws + 192;        //   1024
  float* enc1  = ws + 1216;       // 524288  (B,512,256)
  float* encP  = ws + 525504;     //  64512  (252,256)
  float* pbuf  = ws + 590016;     // 516096  (8,252,256)
  float* enc2  = ws + 1106112;    // 266240  (1040,256)
  float* qb    = ws + 1638592;    // 266240  (xn aliases qb)
  float* kb    = ws + 1904832;    // 266240  (K or K^T)
  float* vb    = ws + 2171072;    // 266240
  float* y1    = ws + 2437312;    // 1064960 (1040,1024)
  float* encPb = ws + 3502272;    //  64512  (TKA ping-pong)
  float* grel  = ws + 4567232;    // 254016  (2,B,8,63,63)
  float* gib   = ws + 4821248;    //   4032  (2,B,8,63)
  float* wsT   = ws + 4825344;    // 3202560 (transposed weights)
  float* xn    = qb;              // alias: qb rows only self-read before overwrite

  // prep: weight transpose (3128) + stats/tws (88) + grel/gib (2016)
  k_prep<<<5232, 256, 0, stream>>>(nl_WQ, nl_WK, nl_WV, nl_WO,
                                   el_Wq, el_Wk, el_Wv, el_Wo,
                                   el_W1, el_W2, inv_W, proj_W,
                                   tok_W, patch_W, wsT,
                                   x_enc, x_mark, means, stdev, tws,
                                   nl_mu_r, nl_sg_r, nl_w_r,
                                   nl_mu_a, nl_sg_a, nl_w_a, grel, gib);
  k_tokconv<<<NB * 64, 256, 0, stream>>>(x_enc, wsT + T_tok, means, stdev, enc1);
  k_patch_part<<<42 * 8, 256, 0, stream>>>(enc1, wsT + T_pat, pbuf);
  k_patch_red<<<NB * EL, 256, 0, stream>>>(pbuf, patch_b, encP);

  for (int L = 0; L < 2; ++L) {
    size_t wo = (size_t)L * DM * DM;
    const float* xi = L ? encPb : encP;
    float* xo       = L ? encP : encPb;
    k_qkv2<4><<<63 * 3, 256, 0, stream>>>(wsT + T_nlWQ + wo, wsT + T_nlWK + wo,
                                          wsT + T_nlWV + wo,
                                          nullptr, nullptr, nullptr,
                                          xi, qb, kb, vb, 0);
    k_tka_attn_f<<<NB * EL, 512, 0, stream>>>(xi, qb, kb, vb,
        grel + (size_t)L * (NB * NH * EL * EL), gib + (size_t)L * (NB * NH * EL),
        nl_al + L * 8, nl_be + L * 8, nl_ga + L * 8,
        wsT + T_nlWO + wo, nl_bO + L * DM, xo);
  }

  k_invemb<<<NB * NT, 256, 0, stream>>>(wsT + T_inv, inv_b, encP, tws, enc2);

  // ---- encoder layer 0: dense (all 1040 rows feed layer-1 K/V) ----
  k_qkv2<8><<<130 * 3, 256, 0, stream>>>(wsT + T_elWq, wsT + T_elWk, wsT + T_elWv,
                                         el_bq, el_bk, el_bv,
                                         enc2, qb, kb, vb, 1);
  k_enc_attn_f<<<NB * 130, 512, 0, stream>>>(qb, kb, vb, wsT + T_elWo, el_bo,
                                             n1g, n1b, enc2, xn, 130);
  k_ffn1<<<130 * 4, 256, 0, stream>>>(wsT + T_elW1, el_b1, xn, y1, 0);
  k_ffn2f<<<260, 512, 0, stream>>>(wsT + T_elW2, el_b2, n2g, n2b, y1, xn, enc2, 0);

  // ---- encoder layer 1: pruned — only rows [b*NT, b*NT+24) reach k_final --
  {
    size_t wo = (size_t)DM * DM;
    size_t bo = (size_t)DM;
    size_t fo = (size_t)DFF * DM;
    k_qkv_l1<<<272, 256, 0, stream>>>(wsT + T_elWq + wo, wsT + T_elWk + wo,
                                      wsT + T_elWv + wo,
                                      el_bq + bo, el_bk + bo, el_bv + bo,
                                      enc2, qb, kb, vb);
    k_enc_attn_f<<<NB * 12, 512, 0, stream>>>(qb, kb, vb, wsT + T_elWo + wo,
                                              el_bo + bo, n1g + bo, n1b + bo,
                                              enc2, xn, 12);
    k_ffn1<<<12 * 4, 256, 0, stream>>>(wsT + T_elW1 + fo, el_b1 + DFF, xn, y1, 3);
    k_ffn2f<<<NB * 6, 512, 0, stream>>>(wsT + T_elW2 + fo, el_b2 + bo,
                                        n2g + bo, n2b + bo, y1, xn, enc2, 6);
  }

  k_final<<<NB * CIN, 256, 0, stream>>>(norm_g, norm_b, wsT + T_proj, proj_b,
                                        enc2, stdev, means, (float*)d_out);
}

// Round 11
// 412.856 us; speedup vs baseline: 1.0394x; 1.0003x over previous
//
#include <hip/hip_runtime.h>
#include <hip/hip_bf16.h>

#define NB 4
#define SEQ 512
#define CIN 21
#define TDIM 4
#define DM 256
#define NH 8
#define PLEN 16
#define PSTR 8
#define EL 63
#define DFF 1024
#define PRED 96
#define NT 260
#define EPSV 1e-5f

// transposed-weight workspace offsets (floats)
#define T_nlWQ 0
#define T_nlWK 131072
#define T_nlWV 262144
#define T_nlWO 393216
#define T_elWq 524288
#define T_elWk 655360
#define T_elWv 786432
#define T_elWo 917504
#define T_elW1 1048576
#define T_elW2 1572864
#define T_inv  2097152
#define T_proj 2113280
#define T_tok  2137856
#define T_pat  2153984

// ---------------- helpers --------------------------------------------------
__device__ __forceinline__ float2 meanvar256(float v, float* sb) {
  __syncthreads();
  float s1 = v, s2 = v * v;
  #pragma unroll
  for (int off = 32; off > 0; off >>= 1) {
    s1 += __shfl_down(s1, off, 64);
    s2 += __shfl_down(s2, off, 64);
  }
  int wid = threadIdx.x >> 6, lane = threadIdx.x & 63;
  if (lane == 0) { sb[wid * 2] = s1; sb[wid * 2 + 1] = s2; }
  __syncthreads();
  float m = (sb[0] + sb[2] + sb[4] + sb[6]) * (1.0f / 256.0f);
  float q = (sb[1] + sb[3] + sb[5] + sb[7]) * (1.0f / 256.0f);
  return make_float2(m, q - m * m);
}

__device__ __forceinline__ void load16f(const float* p, float* o) {
  const float4* q = reinterpret_cast<const float4*>(p);
  float4 a = q[0], b = q[1], c = q[2], d = q[3];
  o[0]=a.x; o[1]=a.y; o[2]=a.z; o[3]=a.w;
  o[4]=b.x; o[5]=b.y; o[6]=b.z; o[7]=b.w;
  o[8]=c.x; o[9]=c.y; o[10]=c.z; o[11]=c.w;
  o[12]=d.x; o[13]=d.y; o[14]=d.z; o[15]=d.w;
}

__device__ __forceinline__ float dot32(const float4* a, const float4* b) {
  float s = 0.f;
  #pragma unroll
  for (int i = 0; i < 8; ++i) {
    float4 x = a[i], y = b[i];
    s += x.x*y.x + x.y*y.y + x.z*y.z + x.w*y.w;
  }
  return s;
}

// ---- K0: weight transpose (3128) + RevIN stats/tws (88) + g_rel (2016) ---
__global__ void __launch_bounds__(256) k_prep(
    const float* __restrict__ nlWQ, const float* __restrict__ nlWK,
    const float* __restrict__ nlWV, const float* __restrict__ nlWO,
    const float* __restrict__ eWq, const float* __restrict__ eWk,
    const float* __restrict__ eWv, const float* __restrict__ eWo,
    const float* __restrict__ eW1, const float* __restrict__ eW2,
    const float* __restrict__ invW, const float* __restrict__ projW,
    const float* __restrict__ tokW, const float* __restrict__ patW,
    float* __restrict__ wt,
    const float* __restrict__ x, const float* __restrict__ xm,
    float* __restrict__ means, float* __restrict__ stdev,
    float* __restrict__ tout,
    const float* __restrict__ mu_r, const float* __restrict__ sg_r,
    const float* __restrict__ w_r,
    const float* __restrict__ mu_a, const float* __restrict__ sg_a,
    const float* __restrict__ w_a,
    float* __restrict__ grel, float* __restrict__ gib) {
  __shared__ float smem[32 * 33];
  int blk = blockIdx.x;
  int t = threadIdx.x;

  if (blk < 3128) {
    // ----- weight transpose (32x32 LDS tiles) -----
    const float* src; float* dst; int R, C, tr, tc;
    if (blk < 1024) {                 // 16 square [256][256] mats
      int m = blk >> 6, tile = blk & 63;
      tr = tile >> 3; tc = tile & 7; R = 256; C = 256;
      int p = m >> 1, l = m & 1;
      const float* bases[8] = {nlWQ, nlWK, nlWV, nlWO, eWq, eWk, eWv, eWo};
      const int offs[8] = {T_nlWQ, T_nlWK, T_nlWV, T_nlWO, T_elWq, T_elWk, T_elWv, T_elWo};
      src = bases[p] + l * 65536;
      dst = wt + offs[p] + l * 65536;
    } else if (blk < 1536) {          // W1 [1024][256] x2
      int q = blk - 1024; int l = q >> 8, s = q & 255;
      tr = s >> 3; tc = s & 7; R = 1024; C = 256;
      src = eW1 + l * 262144; dst = wt + T_elW1 + l * 262144;
    } else if (blk < 2048) {          // W2 [256][1024] x2
      int q = blk - 1536; int l = q >> 8, s = q & 255;
      tr = s >> 5; tc = s & 31; R = 256; C = 1024;
      src = eW2 + l * 262144; dst = wt + T_elW2 + l * 262144;
    } else if (blk < 3072) {          // patch_W [256][4096]
      int q = blk - 2048; tr = q >> 7; tc = q & 127; R = 256; C = 4096;
      src = patW; dst = wt + T_pat;
    } else if (blk < 3088) {          // inv_W [256][63]
      int q = blk - 3072; tr = q >> 1; tc = q & 1; R = 256; C = 63;
      src = invW; dst = wt + T_inv;
    } else if (blk < 3112) {          // proj_W [96][256]
      int q = blk - 3088; tr = q >> 3; tc = q & 7; R = 96; C = 256;
      src = projW; dst = wt + T_proj;
    } else {                          // tok_W [256][63]
      int q = blk - 3112; tr = q >> 1; tc = q & 1; R = 256; C = 63;
      src = tokW; dst = wt + T_tok;
    }
    float (*ts)[33] = (float(*)[33])smem;
    int tx = t & 31, ty = t >> 5;
    #pragma unroll
    for (int i = 0; i < 4; ++i) {
      int r = tr * 32 + ty + i * 8, c = tc * 32 + tx;
      ts[ty + i * 8][tx] = (c < C) ? src[(size_t)r * C + c] : 0.f;
    }
    __syncthreads();
    #pragma unroll
    for (int i = 0; i < 4; ++i) {
      int c = tc * 32 + ty + i * 8, r = tr * 32 + tx;
      if (c < C) dst[(size_t)c * R + r] = ts[tx][ty + i * 8];
    }
  } else if (blk < 3216) {
    // ----- RevIN stats (84) + patch-time means (4) -----
    int sblk = blk - 3128;
    if (sblk < NB * CIN) {
      int b = sblk / CIN, c = sblk % CIN;
      const float* p = x + (size_t)b * SEQ * CIN + c;
      float v0 = p[t * CIN];
      float v1 = p[(t + 256) * CIN];
      float s1 = v0 + v1, s2 = v0 * v0 + v1 * v1;
      float* sb = smem;
      #pragma unroll
      for (int off = 32; off > 0; off >>= 1) {
        s1 += __shfl_down(s1, off, 64);
        s2 += __shfl_down(s2, off, 64);
      }
      int wid = t >> 6, lane = t & 63;
      if (lane == 0) { sb[wid * 2] = s1; sb[wid * 2 + 1] = s2; }
      __syncthreads();
      if (t == 0) {
        float a = sb[0] + sb[2] + sb[4] + sb[6];
        float q = sb[1] + sb[3] + sb[5] + sb[7];
        float m = a * (1.0f / 512.0f);
        float var = q * (1.0f / 512.0f) - m * m;
        means[sblk] = m;
        stdev[sblk] = sqrtf(var + EPSV);
      }
    } else {
      int idx = (sblk - NB * CIN) * 256 + t;
      if (idx >= NB * EL * TDIM) return;
      int b = idx / (EL * TDIM), r = idx % (EL * TDIM);
      int l = r >> 2, ti = r & 3;
      const float* p = xm + (size_t)b * SEQ * TDIM + (size_t)l * PSTR * TDIM + ti;
      float s = 0.f;
      #pragma unroll
      for (int k = 0; k < PLEN; ++k) s += p[k * TDIM];
      tout[idx] = s * (1.f / 16.f);
    }
  } else {
    // ----- g_rel + g_abs, both layers; s_t computed inline from xm -----
    int gblk = blk - 3216;                   // L*(NB*252) + b*252 + chunk
    int L = gblk / (NB * 252);
    int rem0 = gblk % (NB * 252);
    int b = rem0 / 252, chunk = rem0 % 252;
    int po = L * 4096;
    float* grelL = grel + (size_t)L * (NB * NH * EL * EL);
    float* gibL  = gib + (size_t)L * (NB * NH * EL);
    int h = t >> 5, dh = t & 31;
    float* s_t = smem;
    if (t < EL * TDIM) {
      int l = t >> 2, ti = t & 3;
      const float* p = xm + (size_t)b * SEQ * TDIM + (size_t)l * PSTR * TDIM + ti;
      float s = 0.f;
      #pragma unroll
      for (int k = 0; k < PLEN; ++k) s += p[k * TDIM];
      s_t[t] = s * (1.f / 16.f);
    }
    float pm[16], pc[16], pw[16];
    load16f(mu_r + po + (size_t)t * 16, pm);
    load16f(sg_r + po + (size_t)t * 16, pc);
    load16f(w_r  + po + (size_t)t * 16, pw);
    #pragma unroll
    for (int p = 0; p < 16; ++p) pc[p] = -0.5f / (pc[p] * pc[p]);
    __syncthreads();
    #pragma unroll 1
    for (int q = 0; q < 8; ++q) {
      int p = chunk * 8 + q;                 // 2016 (i<=j) pairs
      int i = (int)((127.0f - sqrtf(16129.0f - 8.0f * (float)p)) * 0.5f);
      while (i * (127 - i) / 2 > p) --i;
      while ((i + 1) * (126 - i) / 2 <= p) ++i;
      int j = i + (p - i * (127 - i) / 2);
      float dvv[4];
      dvv[0] = fabsf(s_t[i*4+0] - s_t[j*4+0]);
      dvv[1] = fabsf(s_t[i*4+1] - s_t[j*4+1]);
      dvv[2] = fabsf(s_t[i*4+2] - s_t[j*4+2]);
      dvv[3] = fabsf(s_t[i*4+3] - s_t[j*4+3]);
      float srel = 0.f;
      #pragma unroll
      for (int tt = 0; tt < 4; ++tt)
        #pragma unroll
        for (int k = 0; k < 4; ++k) {
          int pp = tt * 4 + k;
          float df = dvv[tt] - pm[pp];
          srel += pw[pp] * __expf(pc[pp] * df * df);
        }
      #pragma unroll
      for (int m = 1; m < 32; m <<= 1) srel += __shfl_xor(srel, m, 64);
      if (dh == 0) {
        float v = srel * (1.f / 32.f);
        grelL[(((size_t)b * NH + h) * EL + i) * EL + j] = v;
        grelL[(((size_t)b * NH + h) * EL + j) * EL + i] = v;
      }
    }
    if (chunk < EL) {
      load16f(mu_a + po + (size_t)t * 16, pm);
      load16f(sg_a + po + (size_t)t * 16, pc);
      load16f(w_a  + po + (size_t)t * 16, pw);
      #pragma unroll
      for (int p = 0; p < 16; ++p) pc[p] = -0.5f / (pc[p] * pc[p]);
      int i = chunk;
      float tiv[4] = {s_t[i*4+0], s_t[i*4+1], s_t[i*4+2], s_t[i*4+3]};
      float sabs = 0.f;
      #pragma unroll
      for (int tt = 0; tt < 4; ++tt)
        #pragma unroll
        for (int k = 0; k < 4; ++k) {
          int pp = tt * 4 + k;
          float df = tiv[tt] - pm[pp];
          sabs += pw[pp] * __expf(pc[pp] * df * df);
        }
      #pragma unroll
      for (int m = 1; m < 32; m <<= 1) sabs += __shfl_xor(sabs, m, 64);
      if (dh == 0) gibL[((size_t)b * NH + h) * EL + i] = sabs * (1.f / 32.f);
    }
  }
}

// ---- K3a: token conv + PE (tokWT [63][256] coalesced) --------------------
__global__ void __launch_bounds__(256) k_tokconv(
    const float* __restrict__ x, const float* __restrict__ tokWT,
    const float* __restrict__ means, const float* __restrict__ stdev,
    float* __restrict__ enc1) {
  int bi = blockIdx.x;                       // b*64 + sg
  int b = bi >> 6, sg = bi & 63;
  int s0 = sg * 8;
  __shared__ float sxr[10 * CIN];
  int t = threadIdx.x;
  if (t < 10 * CIN) {
    int li = t / CIN, c = t % CIN;
    int row = (s0 - 1 + li + SEQ) & 511;
    sxr[t] = (x[(size_t)b * SEQ * CIN + row * CIN + c] - means[b * CIN + c])
             / stdev[b * CIN + c];
  }
  __syncthreads();
  int d = t;
  float wreg[63];
  #pragma unroll
  for (int q = 0; q < 63; ++q) wreg[q] = tokWT[q * DM + d];
  int de = d & ~1;
  float dv = expf((float)de * (-9.210340371976184f / 256.0f));
  bool isodd = (d & 1);
  #pragma unroll 1
  for (int k = 0; k < 8; ++k) {
    float acc = 0.f;
    const float* sr = sxr + k * CIN;
    #pragma unroll
    for (int c = 0; c < CIN; ++c) {
      acc += sr[c]           * wreg[c * 3 + 0];
      acc += sr[CIN + c]     * wreg[c * 3 + 1];
      acc += sr[2 * CIN + c] * wreg[c * 3 + 2];
    }
    float ang = (float)(s0 + k) * dv;
    float pe = isodd ? cosf(ang) : sinf(ang);
    enc1[((size_t)b * SEQ + s0 + k) * DM + d] = acc + pe;
  }
}

// ---- K3b: patch conv partials (patWT [4096][256], batched loads) ---------
__global__ void __launch_bounds__(256) k_patch_part(
    const float* __restrict__ enc1, const float* __restrict__ pWT,
    float* __restrict__ pbuf) {
  int bi = blockIdx.x;
  int pg = bi >> 3, kc = bi & 7;
  int p0 = pg * 6;
  __shared__ __align__(16) float sA[6 * 32 * 20];
  int t = threadIdx.x;
  for (int idx = t; idx < 6 * 32 * PLEN; idx += 256) {
    int pp = idx >> 9;
    int rem = idx & 511;
    int c = rem >> 4, k = rem & 15;
    int p = p0 + pp;
    int b = p / EL, l = p % EL;
    sA[pp * 640 + c * 20 + k] =
        enc1[((size_t)b * SEQ + l * PSTR + k) * DM + kc * 32 + c];
  }
  __syncthreads();
  int d = t;
  const float* wb = pWT + (size_t)(kc * 32 * PLEN) * DM + d;
  float acc[6] = {0.f, 0.f, 0.f, 0.f, 0.f, 0.f};
  #pragma unroll 1
  for (int kk0 = 0; kk0 < 512; kk0 += 8) {
    float w[8];
    #pragma unroll
    for (int q = 0; q < 8; ++q) w[q] = wb[(size_t)(kk0 + q) * DM];
    #pragma unroll
    for (int q = 0; q < 8; ++q) {
      int kk = kk0 + q;
      const float* sa = sA + (kk >> 4) * 20 + (kk & 15);
      acc[0] += sa[0 * 640] * w[q];
      acc[1] += sa[1 * 640] * w[q];
      acc[2] += sa[2 * 640] * w[q];
      acc[3] += sa[3 * 640] * w[q];
      acc[4] += sa[4 * 640] * w[q];
      acc[5] += sa[5 * 640] * w[q];
    }
  }
  const int S = NB * EL * DM;
  #pragma unroll
  for (int pp = 0; pp < 6; ++pp)
    pbuf[(size_t)kc * S + (size_t)(p0 + pp) * DM + d] = acc[pp];
}

// ---- TKA L0 QKV: fused pbuf-reduce (patch_red) + QKV GEMM ----------------
__global__ void __launch_bounds__(256) k_qkv_tka0(
    const float* __restrict__ WqT, const float* __restrict__ WkT,
    const float* __restrict__ WvT,
    const float* __restrict__ pbuf, const float* __restrict__ pb,
    float* __restrict__ qo, float* __restrict__ ko, float* __restrict__ vo,
    float* __restrict__ encPo) {
  int bi = blockIdx.x;
  int rg = bi / 3, mat = bi % 3;
  int row0 = rg * 4;
  __shared__ __align__(16) float sx[4 * DM];
  __shared__ __align__(16) float sp[3 * 4 * DM];
  int t = threadIdx.x;
  int colg = t & 63, kq = t >> 6;
  const int S = NB * EL * DM;
  #pragma unroll
  for (int i = 0; i < 4; ++i) {
    int idx = t + i * 256;
    const float* pp = pbuf + (size_t)row0 * DM + idx;
    float pv[8];
    #pragma unroll
    for (int s = 0; s < 8; ++s) pv[s] = pp[(size_t)s * S];
    float v = pb[idx & 255];
    #pragma unroll
    for (int s = 0; s < 8; ++s) v += pv[s];
    sx[idx] = v;
    if (mat == 0) encPo[(size_t)row0 * DM + idx] = v;
  }
  __syncthreads();
  const float* WT = (mat == 0) ? WqT : (mat == 1) ? WkT : WvT;
  float* out = (mat == 0) ? qo : (mat == 1) ? ko : vo;
  float acc[4][4];
  #pragma unroll
  for (int r = 0; r < 4; ++r) { acc[r][0]=0.f; acc[r][1]=0.f; acc[r][2]=0.f; acc[r][3]=0.f; }
  const float* xb = sx + kq * 64;
  const float4* wp = reinterpret_cast<const float4*>(WT + (size_t)(kq * 64) * DM) + colg;
  #pragma unroll 1
  for (int k0 = 0; k0 < 64; k0 += 4) {
    float4 w[4];
    #pragma unroll
    for (int q = 0; q < 4; ++q) w[q] = wp[(size_t)(k0 + q) * 64];
    #pragma unroll
    for (int q = 0; q < 4; ++q)
      #pragma unroll
      for (int r = 0; r < 4; ++r) {
        float xv = xb[r * DM + k0 + q];
        acc[r][0] += xv * w[q].x; acc[r][1] += xv * w[q].y;
        acc[r][2] += xv * w[q].z; acc[r][3] += xv * w[q].w;
      }
  }
  if (kq) {
    #pragma unroll
    for (int r = 0; r < 4; ++r)
      reinterpret_cast<float4*>(sp)[((kq - 1) * 4 + r) * 64 + colg] =
          make_float4(acc[r][0], acc[r][1], acc[r][2], acc[r][3]);
  }
  __syncthreads();
  if (kq == 0) {
    const float4* sp4 = reinterpret_cast<const float4*>(sp);
    #pragma unroll
    for (int r = 0; r < 4; ++r) {
      float4 p0 = sp4[(0 * 4 + r) * 64 + colg];
      float4 p1 = sp4[(1 * 4 + r) * 64 + colg];
      float4 p2 = sp4[(2 * 4 + r) * 64 + colg];
      float4 o;
      o.x = acc[r][0] + p0.x + p1.x + p2.x;
      o.y = acc[r][1] + p0.y + p1.y + p2.y;
      o.z = acc[r][2] + p0.z + p1.z + p2.z;
      o.w = acc[r][3] + p0.w + p1.w + p2.w;
      reinterpret_cast<float4*>(out + (size_t)(row0 + r) * DM)[colg] = o;
    }
  }
}

// ---- QKV (TKA layer 1): WT [256][256], reg-tile, K-split 4 ---------------
template<int R>
__global__ void __launch_bounds__(256) k_qkv2(
    const float* __restrict__ WqT, const float* __restrict__ WkT,
    const float* __restrict__ WvT,
    const float* __restrict__ bq, const float* __restrict__ bk,
    const float* __restrict__ bv,
    const float* __restrict__ xin,
    float* __restrict__ qo, float* __restrict__ ko, float* __restrict__ vo,
    int ktm) {
  int bi = blockIdx.x;
  int rg = bi / 3, mat = bi % 3;
  int row0 = rg * R;
  __shared__ __align__(16) float sx[R * DM];
  __shared__ __align__(16) float sp[3 * R * DM];
  int t = threadIdx.x;
  int colg = t & 63, kq = t >> 6;
  #pragma unroll
  for (int i = 0; i < R / 4; ++i)
    reinterpret_cast<float4*>(sx)[t + i * 256] =
        reinterpret_cast<const float4*>(xin + (size_t)row0 * DM)[t + i * 256];
  __syncthreads();
  const float* WT = (mat == 0) ? WqT : (mat == 1) ? WkT : WvT;
  const float* bias = (mat == 0) ? bq : (mat == 1) ? bk : bv;
  float* out = (mat == 0) ? qo : (mat == 1) ? ko : vo;
  float acc[R][4];
  #pragma unroll
  for (int r = 0; r < R; ++r) { acc[r][0]=0.f; acc[r][1]=0.f; acc[r][2]=0.f; acc[r][3]=0.f; }
  const float* xb = sx + kq * 64;
  const float4* wp = reinterpret_cast<const float4*>(WT + (size_t)(kq * 64) * DM) + colg;
  #pragma unroll 1
  for (int k0 = 0; k0 < 64; k0 += 4) {
    float4 w[4];
    #pragma unroll
    for (int q = 0; q < 4; ++q) w[q] = wp[(size_t)(k0 + q) * 64];
    #pragma unroll
    for (int q = 0; q < 4; ++q)
      #pragma unroll
      for (int r = 0; r < R; ++r) {
        float xv = xb[r * DM + k0 + q];
        acc[r][0] += xv * w[q].x; acc[r][1] += xv * w[q].y;
        acc[r][2] += xv * w[q].z; acc[r][3] += xv * w[q].w;
      }
  }
  if (kq) {
    #pragma unroll
    for (int r = 0; r < R; ++r)
      reinterpret_cast<float4*>(sp)[((kq - 1) * R + r) * 64 + colg] =
          make_float4(acc[r][0], acc[r][1], acc[r][2], acc[r][3]);
  }
  __syncthreads();
  if (kq == 0) {
    float4 b4 = bias ? reinterpret_cast<const float4*>(bias)[colg]
                     : make_float4(0.f, 0.f, 0.f, 0.f);
    const float4* sp4 = reinterpret_cast<const float4*>(sp);
    #pragma unroll
    for (int r = 0; r < R; ++r) {
      float4 p0 = sp4[(0 * R + r) * 64 + colg];
      float4 p1 = sp4[(1 * R + r) * 64 + colg];
      float4 p2 = sp4[(2 * R + r) * 64 + colg];
      float4 o;
      o.x = acc[r][0] + p0.x + p1.x + p2.x + b4.x;
      o.y = acc[r][1] + p0.y + p1.y + p2.y + b4.y;
      o.z = acc[r][2] + p0.z + p1.z + p2.z + b4.z;
      o.w = acc[r][3] + p0.w + p1.w + p2.w + b4.w;
      if (ktm && mat == 1) {
        int gr = row0 + r, bb2 = gr / NT, jj2 = gr % NT;
        float* kd = out + (size_t)bb2 * (DM * NT) + jj2;
        kd[(size_t)(colg * 4 + 0) * NT] = o.x;
        kd[(size_t)(colg * 4 + 1) * NT] = o.y;
        kd[(size_t)(colg * 4 + 2) * NT] = o.z;
        kd[(size_t)(colg * 4 + 3) * NT] = o.w;
      } else {
        reinterpret_cast<float4*>(out + (size_t)(row0 + r) * DM)[colg] = o;
      }
    }
  }
}

// ---- encoder-L0 QKV: fused inverted-embedding + QKV (K written ^T) -------
__global__ void __launch_bounds__(256) k_qkv_enc0(
    const float* __restrict__ WqT, const float* __restrict__ WkT,
    const float* __restrict__ WvT,
    const float* __restrict__ bq, const float* __restrict__ bk,
    const float* __restrict__ bv,
    const float* __restrict__ invWT, const float* __restrict__ invb,
    const float* __restrict__ encP, const float* __restrict__ tws,
    float* __restrict__ qo, float* __restrict__ ko, float* __restrict__ vo,
    float* __restrict__ enc2) {
  int bi = blockIdx.x;
  int rg = bi / 3, mat = bi % 3;
  int row0 = rg * 8;
  __shared__ __align__(16) float sx[8 * DM];
  __shared__ float sxe[EL * 8 + 8];            // [l][r]
  __shared__ __align__(16) float sp[3 * 8 * DM];
  int t = threadIdx.x;
  int colg = t & 63, kq = t >> 6;
  // gather encP columns / tws for the block's 8 output rows
  #pragma unroll
  for (int it = 0; it < 2; ++it) {
    int idx = t + it * 256;
    if (idx < EL * 8) {
      int l = idx >> 3, r = idx & 7;
      int gr = row0 + r, bb2 = gr / NT, n = gr % NT;
      float v;
      if (n < DM) v = encP[(size_t)(bb2 * EL + l) * DM + n];
      else        v = tws[bb2 * EL * TDIM + l * TDIM + (n - DM)];
      sxe[l * 8 + r] = v;
    }
  }
  __syncthreads();
  // inverted embedding: thread t = output col, 8 rows
  {
    float bv2 = invb[t];
    float acc2[8];
    #pragma unroll
    for (int r = 0; r < 8; ++r) acc2[r] = bv2;
    #pragma unroll 1
    for (int l0 = 0; l0 < EL; l0 += 9) {
      float w[9];
      #pragma unroll
      for (int q = 0; q < 9; ++q) w[q] = invWT[(size_t)(l0 + q) * DM + t];
      #pragma unroll
      for (int q = 0; q < 9; ++q)
        #pragma unroll
        for (int r = 0; r < 8; ++r)
          acc2[r] += sxe[(l0 + q) * 8 + r] * w[q];
    }
    #pragma unroll
    for (int r = 0; r < 8; ++r) {
      sx[r * DM + t] = acc2[r];
      if (mat == 0) enc2[(size_t)(row0 + r) * DM + t] = acc2[r];
    }
  }
  __syncthreads();
  // QKV GEMM (K transposed out)
  const float* WT = (mat == 0) ? WqT : (mat == 1) ? WkT : WvT;
  const float* bias = (mat == 0) ? bq : (mat == 1) ? bk : bv;
  float* out = (mat == 0) ? qo : (mat == 1) ? ko : vo;
  float acc[8][4];
  #pragma unroll
  for (int r = 0; r < 8; ++r) { acc[r][0]=0.f; acc[r][1]=0.f; acc[r][2]=0.f; acc[r][3]=0.f; }
  const float* xb = sx + kq * 64;
  const float4* wp = reinterpret_cast<const float4*>(WT + (size_t)(kq * 64) * DM) + colg;
  #pragma unroll 1
  for (int k0 = 0; k0 < 64; k0 += 4) {
    float4 w[4];
    #pragma unroll
    for (int q = 0; q < 4; ++q) w[q] = wp[(size_t)(k0 + q) * 64];
    #pragma unroll
    for (int q = 0; q < 4; ++q)
      #pragma unroll
      for (int r = 0; r < 8; ++r) {
        float xv = xb[r * DM + k0 + q];
        acc[r][0] += xv * w[q].x; acc[r][1] += xv * w[q].y;
        acc[r][2] += xv * w[q].z; acc[r][3] += xv * w[q].w;
      }
  }
  if (kq) {
    #pragma unroll
    for (int r = 0; r < 8; ++r)
      reinterpret_cast<float4*>(sp)[((kq - 1) * 8 + r) * 64 + colg] =
          make_float4(acc[r][0], acc[r][1], acc[r][2], acc[r][3]);
  }
  __syncthreads();
  if (kq == 0) {
    float4 b4 = reinterpret_cast<const float4*>(bias)[colg];
    const float4* sp4 = reinterpret_cast<const float4*>(sp);
    #pragma unroll
    for (int r = 0; r < 8; ++r) {
      float4 p0 = sp4[(0 * 8 + r) * 64 + colg];
      float4 p1 = sp4[(1 * 8 + r) * 64 + colg];
      float4 p2 = sp4[(2 * 8 + r) * 64 + colg];
      float4 o;
      o.x = acc[r][0] + p0.x + p1.x + p2.x + b4.x;
      o.y = acc[r][1] + p0.y + p1.y + p2.y + b4.y;
      o.z = acc[r][2] + p0.z + p1.z + p2.z + b4.z;
      o.w = acc[r][3] + p0.w + p1.w + p2.w + b4.w;
      if (mat == 1) {
        int gr = row0 + r, bb2 = gr / NT, jj2 = gr % NT;
        float* kd = out + (size_t)bb2 * (DM * NT) + jj2;
        kd[(size_t)(colg * 4 + 0) * NT] = o.x;
        kd[(size_t)(colg * 4 + 1) * NT] = o.y;
        kd[(size_t)(colg * 4 + 2) * NT] = o.z;
        kd[(size_t)(colg * 4 + 3) * NT] = o.w;
      } else {
        reinterpret_cast<float4*>(out + (size_t)(row0 + r) * DM)[colg] = o;
      }
    }
  }
}

// ---- QKV layer-1: K^T full (1040 rows) + V full + Q first 24 rows per b --
__global__ void __launch_bounds__(256) k_qkv_l1(
    const float* __restrict__ WqT, const float* __restrict__ WkT,
    const float* __restrict__ WvT,
    const float* __restrict__ bq, const float* __restrict__ bk,
    const float* __restrict__ bv,
    const float* __restrict__ xin,
    float* __restrict__ qo, float* __restrict__ ko, float* __restrict__ vo) {
  int bi = blockIdx.x;
  const float* WT; const float* bias; float* out; int row0; int ktm = 0;
  if (bi < 130)      { WT = WkT; bias = bk; out = ko; row0 = bi * 8; ktm = 1; }
  else if (bi < 260) { WT = WvT; bias = bv; out = vo; row0 = (bi - 130) * 8; }
  else {             // 12 blocks: Q for rows b*NT + [0,24)
    int gq = bi - 260;
    WT = WqT; bias = bq; out = qo;
    row0 = (gq / 3) * NT + (gq % 3) * 8;
  }
  __shared__ __align__(16) float sx[8 * DM];
  __shared__ __align__(16) float sp[3 * 8 * DM];
  int t = threadIdx.x;
  int colg = t & 63, kq = t >> 6;
  #pragma unroll
  for (int i = 0; i < 2; ++i)
    reinterpret_cast<float4*>(sx)[t + i * 256] =
        reinterpret_cast<const float4*>(xin + (size_t)row0 * DM)[t + i * 256];
  __syncthreads();
  float acc[8][4];
  #pragma unroll
  for (int r = 0; r < 8; ++r) { acc[r][0]=0.f; acc[r][1]=0.f; acc[r][2]=0.f; acc[r][3]=0.f; }
  const float* xb = sx + kq * 64;
  const float4* wp = reinterpret_cast<const float4*>(WT + (size_t)(kq * 64) * DM) + colg;
  #pragma unroll 1
  for (int k0 = 0; k0 < 64; k0 += 4) {
    float4 w[4];
    #pragma unroll
    for (int q = 0; q < 4; ++q) w[q] = wp[(size_t)(k0 + q) * 64];
    #pragma unroll
    for (int q = 0; q < 4; ++q)
      #pragma unroll
      for (int r = 0; r < 8; ++r) {
        float xv = xb[r * DM + k0 + q];
        acc[r][0] += xv * w[q].x; acc[r][1] += xv * w[q].y;
        acc[r][2] += xv * w[q].z; acc[r][3] += xv * w[q].w;
      }
  }
  if (kq) {
    #pragma unroll
    for (int r = 0; r < 8; ++r)
      reinterpret_cast<float4*>(sp)[((kq - 1) * 8 + r) * 64 + colg] =
          make_float4(acc[r][0], acc[r][1], acc[r][2], acc[r][3]);
  }
  __syncthreads();
  if (kq == 0) {
    float4 b4 = reinterpret_cast<const float4*>(bias)[colg];
    const float4* sp4 = reinterpret_cast<const float4*>(sp);
    #pragma unroll
    for (int r = 0; r < 8; ++r) {
      float4 p0 = sp4[(0 * 8 + r) * 64 + colg];
      float4 p1 = sp4[(1 * 8 + r) * 64 + colg];
      float4 p2 = sp4[(2 * 8 + r) * 64 + colg];
      float4 o;
      o.x = acc[r][0] + p0.x + p1.x + p2.x + b4.x;
      o.y = acc[r][1] + p0.y + p1.y + p2.y + b4.y;
      o.z = acc[r][2] + p0.z + p1.z + p2.z + b4.z;
      o.w = acc[r][3] + p0.w + p1.w + p2.w + b4.w;
      if (ktm) {
        int gr = row0 + r, bb2 = gr / NT, jj2 = gr % NT;
        float* kd = out + (size_t)bb2 * (DM * NT) + jj2;
        kd[(size_t)(colg * 4 + 0) * NT] = o.x;
        kd[(size_t)(colg * 4 + 1) * NT] = o.y;
        kd[(size_t)(colg * 4 + 2) * NT] = o.z;
        kd[(size_t)(colg * 4 + 3) * NT] = o.w;
      } else {
        reinterpret_cast<float4*>(out + (size_t)(row0 + r) * DM)[colg] = o;
      }
    }
  }
}

// ---- TKA attention + fused Wo^T, 512 threads, split PV / split-K Wo ------
__global__ void __launch_bounds__(512) k_tka_attn_f(
    const float* __restrict__ xin, const float* __restrict__ qw,
    const float* __restrict__ kw, const float* __restrict__ vw,
    const float* __restrict__ grel, const float* __restrict__ gib,
    const float* __restrict__ alpha, const float* __restrict__ beta,
    const float* __restrict__ gamma,
    const float* __restrict__ WOT, const float* __restrict__ bO,
    float* __restrict__ xout) {
  int bi = blockIdx.x;                       // b*63+i
  int b = bi / EL, i = bi % EL;
  int t = threadIdx.x;
  __shared__ __align__(16) float sQX[2 * DM];
  __shared__ float sP[NH * 64];
  __shared__ __align__(16) float sO[DM];
  __shared__ float sPV[DM];
  if (t < 2 * DM)
    sQX[t] = (t < DM) ? qw[(size_t)bi * DM + t] : xin[(size_t)bi * DM + (t - DM)];
  __syncthreads();
  {
    int tile = t >> 8, h = (t >> 5) & 7, jj = t & 31;
    int j = tile * 32 + jj;
    bool valid = (j < EL);
    int jc = valid ? j : (EL - 1);
    float gi = gib[((size_t)b * NH + h) * EL + i];
    float al = alpha[h], be = beta[h], ga = gamma[h];
    const float* grow = grel + (((size_t)b * NH + h) * EL + i) * EL;
    const float4* kp = reinterpret_cast<const float4*>(
        kw + (size_t)(b * EL + jc) * DM + h * 32);
    const float4* xp = reinterpret_cast<const float4*>(
        xin + (size_t)(b * EL + jc) * DM + h * 32);
    float4 kf[8], xf[8];
    #pragma unroll
    for (int q = 0; q < 8; ++q) { kf[q] = kp[q]; xf[q] = xp[q]; }
    float qk  = dot32(reinterpret_cast<const float4*>(sQX + h * 32), kf);
    float pij = dot32(reinterpret_cast<const float4*>(sQX + DM + h * 32), xf);
    float A = al * pij * (2.f * gi) + be * pij * grow[jc] + ga;
    const float scale = 0.17677669529663687f;
    sP[h * 64 + tile * 32 + jj] = valid ? (qk * scale * A) : -1e30f;
  }
  __syncthreads();
  {
    int h = t >> 6, dh = t & 63;               // one wave per head
    float v = sP[h * 64 + dh];
    float m = v;
    #pragma unroll
    for (int s = 1; s < 64; s <<= 1) m = fmaxf(m, __shfl_xor(m, s, 64));
    float e = __expf(v - m);
    float ssum = e;
    #pragma unroll
    for (int s = 1; s < 64; s <<= 1) ssum += __shfl_xor(ssum, s, 64);
    sP[h * 64 + dh] = e / ssum;                // dh=63 -> 0
  }
  __syncthreads();
  {
    int ch = t & 255, jh = t >> 8, hh = ch >> 5;
    float acc = 0.f;
    const float* pp = sP + hh * 64 + jh * 32;
    int jbase = jh * 32;
    #pragma unroll 1
    for (int j0 = 0; j0 < 32; j0 += 8) {
      float v[8];
      #pragma unroll
      for (int q = 0; q < 8; ++q) {
        int jx = jbase + j0 + q;
        if (jx > 62) jx = 62;                  // j=63 weight is 0; avoid stale row
        v[q] = vw[(size_t)(b * EL + jx) * DM + ch];
      }
      #pragma unroll
      for (int q = 0; q < 8; ++q) acc += pp[j0 + q] * v[q];
    }
    if (jh) sPV[ch] = acc;
    __syncthreads();
    if (!jh) sO[ch] = acc + sPV[ch];
  }
  __syncthreads();
  {
    int col = t & 255, kh = t >> 8;
    float acc = 0.f;
    const float* wc = WOT + (size_t)(kh * 128) * DM + col;
    const float* sx = sO + kh * 128;
    #pragma unroll 1
    for (int k0 = 0; k0 < 128; k0 += 8) {
      float w[8];
      #pragma unroll
      for (int q = 0; q < 8; ++q) w[q] = wc[(size_t)(k0 + q) * DM];
      #pragma unroll
      for (int q = 0; q < 8; ++q) acc += sx[k0 + q] * w[q];
    }
    if (kh) sPV[col] = acc;
    __syncthreads();
    if (!kh) xout[(size_t)bi * DM + col] = acc + sPV[col] + bO[col];
  }
}

// ---- encoder attention, 512 thr, 2 rows/block, K^T coalesced scores ------
// kw is K^T [b][256][260]. tpb: i-tiles (2 rows) per batch (130 / 12).
__global__ void __launch_bounds__(512) k_enc_attn_f(
    const float* __restrict__ qw, const float* __restrict__ kw,
    const float* __restrict__ vw,
    const float* __restrict__ WoT, const float* __restrict__ bo,
    const float* __restrict__ g, const float* __restrict__ bb,
    const float* __restrict__ resin, float* __restrict__ out, int tpb) {
  int blk = blockIdx.x;                      // b*tpb + tile
  int b = blk / tpb, it = blk % tpb;
  int i0 = it * 2;
  int t = threadIdx.x;

  __shared__ __align__(16) float sQ[2 * DM]; // Q rows; later normalized PV out
  __shared__ float sS[2 * NH * NT];          // 16.6 KB
  __shared__ float sL[2 * NH];
  __shared__ __align__(16) float sPV[2 * DM];
  __shared__ float sb[8];

  for (int idx = t; idx < 2 * DM; idx += 512)
    sQ[idx] = qw[((size_t)(b * NT + i0)) * DM + idx];
  __syncthreads();

  const float scale = 0.17677669529663687f;
  {
    // scores: thread t owns column j=t (<260); coalesced K^T reads
    if (t < NT) {
      const float* kT = kw + (size_t)b * (DM * NT) + t;
      #pragma unroll
      for (int h = 0; h < NH; ++h) {
        float a0 = 0.f, a1 = 0.f;
        float kv[8];
        #pragma unroll
        for (int d0 = 0; d0 < 32; d0 += 8) {
          #pragma unroll
          for (int q = 0; q < 8; ++q)
            kv[q] = kT[(size_t)(h * 32 + d0 + q) * NT];
          #pragma unroll
          for (int q = 0; q < 8; ++q) {
            a0 += sQ[0 * DM + h * 32 + d0 + q] * kv[q];
            a1 += sQ[1 * DM + h * 32 + d0 + q] * kv[q];
          }
        }
        sS[(0 * NH + h) * NT + t] = a0 * scale;
        sS[(1 * NH + h) * NT + t] = a1 * scale;
      }
    }
  }
  __syncthreads();
  {
    int combo = t >> 5, lane32 = t & 31;     // 16 combos x 32 lanes
    float* row = sS + (size_t)combo * NT;
    float m = -1e30f;
    for (int jx = lane32; jx < NT; jx += 32) m = fmaxf(m, row[jx]);
    #pragma unroll
    for (int s = 1; s < 32; s <<= 1) m = fmaxf(m, __shfl_xor(m, s, 32));
    float ssum = 0.f;
    for (int jx = lane32; jx < NT; jx += 32) {
      float e = __expf(row[jx] - m);
      row[jx] = e;
      ssum += e;
    }
    #pragma unroll
    for (int s = 1; s < 32; s <<= 1) ssum += __shfl_xor(ssum, s, 32);
    if (lane32 == 0) sL[combo] = ssum;
  }
  __syncthreads();
  {
    int ch = t & 255, jh = t >> 8, hh = ch >> 5;
    float o0 = 0.f, o1 = 0.f;
    const float* vbase = vw + ((size_t)(b * NT + jh * 130)) * DM + ch;
    const float* p0 = sS + (0 * NH + hh) * NT + jh * 130;
    const float* p1 = sS + (1 * NH + hh) * NT + jh * 130;
    #pragma unroll 1
    for (int j0 = 0; j0 < 130; j0 += 10) {
      float v[10];
      #pragma unroll
      for (int q = 0; q < 10; ++q) v[q] = vbase[(size_t)(j0 + q) * DM];
      #pragma unroll
      for (int q = 0; q < 10; ++q) {
        o0 += p0[j0 + q] * v[q]; o1 += p1[j0 + q] * v[q];
      }
    }
    if (jh) {
      sPV[0 * DM + ch] = o0; sPV[1 * DM + ch] = o1;
    }
    __syncthreads();
    if (!jh) {
      sQ[0 * DM + ch] = (o0 + sPV[0 * DM + ch]) / sL[0 * NH + hh];
      sQ[1 * DM + ch] = (o1 + sPV[1 * DM + ch]) / sL[1 * NH + hh];
    }
  }
  __syncthreads();
  {
    int col = t & 255, kh = t >> 8;
    float acc[2] = {0.f, 0.f};
    const float* wcol = WoT + (size_t)(kh * 128) * DM + col;
    const float* s0 = sQ + kh * 128;
    #pragma unroll 1
    for (int k0 = 0; k0 < 128; k0 += 8) {
      float w[8];
      #pragma unroll
      for (int q = 0; q < 8; ++q) w[q] = wcol[(size_t)(k0 + q) * DM];
      #pragma unroll
      for (int q = 0; q < 8; ++q) {
        acc[0] += s0[0 * DM + k0 + q] * w[q];
        acc[1] += s0[1 * DM + k0 + q] * w[q];
      }
    }
    if (kh) {
      sPV[0 * DM + col] = acc[0]; sPV[1 * DM + col] = acc[1];
    }
    __syncthreads();
    float ov[2] = {0.f, 0.f};
    float gg = g[col], bb2 = bb[col];
    if (!kh) {
      float bias = bo[col];
      #pragma unroll
      for (int r = 0; r < 2; ++r)
        ov[r] = acc[r] + sPV[r * DM + col] + bias
              + resin[((size_t)(b * NT + i0 + r)) * DM + col];
    }
    int wid = t >> 6, lane = t & 63;
    #pragma unroll 1
    for (int r = 0; r < 2; ++r) {
      float o = (!kh) ? ov[r] : 0.f;
      __syncthreads();
      float s1 = o, s2 = o * o;
      #pragma unroll
      for (int off = 32; off > 0; off >>= 1) {
        s1 += __shfl_down(s1, off, 64);
        s2 += __shfl_down(s2, off, 64);
      }
      if (lane == 0 && wid < 4) { sb[wid * 2] = s1; sb[wid * 2 + 1] = s2; }
      __syncthreads();
      float m = (sb[0] + sb[2] + sb[4] + sb[6]) * (1.f / 256.f);
      float q2 = (sb[1] + sb[3] + sb[5] + sb[7]) * (1.f / 256.f);
      float var = q2 - m * m;
      if (!kh)
        out[((size_t)(b * NT + i0 + r)) * DM + col] =
            (ov[r] - m) * rsqrtf(var + EPSV) * gg + bb2;
    }
  }
}

// ---- FFN1: gelu(x@W1.T+b1) via W1T, reg-tile, K-split 4, batch 4 ---------
// gpb: row-groups per batch (0 = dense 130 groups; 3 = pruned 24 rows/b)
__global__ void __launch_bounds__(256) k_ffn1(
    const float* __restrict__ W1T, const float* __restrict__ b1,
    const float* __restrict__ xn, float* __restrict__ y1, int gpb) {
  int bi = blockIdx.x;                       // rg*4 + fg
  int rg = bi >> 2, fg = bi & 3;
  int row0 = gpb ? ((rg / gpb) * NT + (rg % gpb) * 8) : rg * 8;
  __shared__ __align__(16) float sx[8 * DM];
  __shared__ __align__(16) float sp[3 * 8 * DM];
  int t = threadIdx.x;
  int colg = t & 63, kq = t >> 6;
  #pragma unroll
  for (int i = 0; i < 2; ++i)
    reinterpret_cast<float4*>(sx)[t + i * 256] =
        reinterpret_cast<const float4*>(xn + (size_t)row0 * DM)[t + i * 256];
  __syncthreads();
  int f = fg * 256 + colg * 4;
  float acc[8][4];
  #pragma unroll
  for (int r = 0; r < 8; ++r) { acc[r][0]=0.f; acc[r][1]=0.f; acc[r][2]=0.f; acc[r][3]=0.f; }
  const float* xb = sx + kq * 64;
  const float4* wp = reinterpret_cast<const float4*>(W1T + (size_t)(kq * 64) * DFF + f);
  #pragma unroll 1
  for (int k0 = 0; k0 < 64; k0 += 4) {
    float4 w[4];
    #pragma unroll
    for (int q = 0; q < 4; ++q) w[q] = wp[(size_t)(k0 + q) * 256];
    #pragma unroll
    for (int q = 0; q < 4; ++q)
      #pragma unroll
      for (int r = 0; r < 8; ++r) {
        float xv = xb[r * DM + k0 + q];
        acc[r][0] += xv * w[q].x; acc[r][1] += xv * w[q].y;
        acc[r][2] += xv * w[q].z; acc[r][3] += xv * w[q].w;
      }
  }
  if (kq) {
    #pragma unroll
    for (int r = 0; r < 8; ++r)
      reinterpret_cast<float4*>(sp)[((kq - 1) * 8 + r) * 64 + colg] =
          make_float4(acc[r][0], acc[r][1], acc[r][2], acc[r][3]);
  }
  __syncthreads();
  if (kq == 0) {
    float4 b4 = *reinterpret_cast<const float4*>(b1 + f);
    const float4* sp4 = reinterpret_cast<const float4*>(sp);
    #pragma unroll 1
    for (int r = 0; r < 8; ++r) {
      float4 p0 = sp4[(0 * 8 + r) * 64 + colg];
      float4 p1 = sp4[(1 * 8 + r) * 64 + colg];
      float4 p2 = sp4[(2 * 8 + r) * 64 + colg];
      float a0 = acc[r][0] + p0.x + p1.x + p2.x + b4.x;
      float a1 = acc[r][1] + p0.y + p1.y + p2.y + b4.y;
      float a2 = acc[r][2] + p0.z + p1.z + p2.z + b4.z;
      float a3 = acc[r][3] + p0.w + p1.w + p2.w + b4.w;
      float4 o;
      o.x = 0.5f * a0 * (1.f + erff(a0 * 0.70710678118654752f));
      o.y = 0.5f * a1 * (1.f + erff(a1 * 0.70710678118654752f));
      o.z = 0.5f * a2 * (1.f + erff(a2 * 0.70710678118654752f));
      o.w = 0.5f * a3 * (1.f + erff(a3 * 0.70710678118654752f));
      *reinterpret_cast<float4*>(y1 + (size_t)(row0 + r) * DFF + f) = o;
    }
  }
}

// ---- FFN2 fused: W2T, 4 rows/block, 512 thr, K-split 8, batch 8, +LN -----
// gpb: groups-of-4 per batch (0 = dense 260 blocks; 6 = pruned 24 rows/b)
__global__ void __launch_bounds__(512) k_ffn2f(
    const float* __restrict__ W2T, const float* __restrict__ b2,
    const float* __restrict__ g, const float* __restrict__ bb,
    const float* __restrict__ y1, const float* __restrict__ xn,
    float* __restrict__ out, int gpb) {
  int blk = blockIdx.x;
  int row0 = gpb ? ((blk / gpb) * NT + (blk % gpb) * 4) : blk * 4;
  __shared__ __align__(16) float sy[4 * DFF];    // 16 KB
  __shared__ __align__(16) float sp[7 * 4 * DM]; // 28 KB
  int t = threadIdx.x;
  int colg = t & 63, kq = t >> 6;                // kq 0..7
  #pragma unroll
  for (int i = 0; i < 2; ++i)
    reinterpret_cast<float4*>(sy)[t + i * 512] =
        reinterpret_cast<const float4*>(y1 + (size_t)row0 * DFF)[t + i * 512];
  __syncthreads();
  float acc[4][4];
  #pragma unroll
  for (int r = 0; r < 4; ++r) { acc[r][0]=0.f; acc[r][1]=0.f; acc[r][2]=0.f; acc[r][3]=0.f; }
  const float* yb = sy + kq * 128;
  const float4* wp = reinterpret_cast<const float4*>(W2T + (size_t)(kq * 128) * DM) + colg;
  #pragma unroll 1
  for (int k0 = 0; k0 < 128; k0 += 8) {
    float4 w[8];
    #pragma unroll
    for (int q = 0; q < 8; ++q) w[q] = wp[(size_t)(k0 + q) * 64];
    #pragma unroll
    for (int q = 0; q < 8; ++q)
      #pragma unroll
      for (int r = 0; r < 4; ++r) {
        float yv = yb[r * DFF + k0 + q];
        acc[r][0] += yv * w[q].x; acc[r][1] += yv * w[q].y;
        acc[r][2] += yv * w[q].z; acc[r][3] += yv * w[q].w;
      }
  }
  if (kq) {
    #pragma unroll
    for (int r = 0; r < 4; ++r)
      reinterpret_cast<float4*>(sp)[((kq - 1) * 4 + r) * 64 + colg] =
          make_float4(acc[r][0], acc[r][1], acc[r][2], acc[r][3]);
  }
  __syncthreads();
  if (kq == 0) {
    float4 b4 = reinterpret_cast<const float4*>(b2)[colg];
    float4 g4 = reinterpret_cast<const float4*>(g)[colg];
    float4 bb4 = reinterpret_cast<const float4*>(bb)[colg];
    const float4* sp4 = reinterpret_cast<const float4*>(sp);
    #pragma unroll 1
    for (int r = 0; r < 4; ++r) {
      float o0 = acc[r][0], o1 = acc[r][1], o2 = acc[r][2], o3 = acc[r][3];
      #pragma unroll
      for (int s = 0; s < 7; ++s) {
        float4 ps = sp4[(s * 4 + r) * 64 + colg];
        o0 += ps.x; o1 += ps.y; o2 += ps.z; o3 += ps.w;
      }
      float4 xr = reinterpret_cast<const float4*>(xn + (size_t)(row0 + r) * DM)[colg];
      o0 += b4.x + xr.x; o1 += b4.y + xr.y; o2 += b4.z + xr.z; o3 += b4.w + xr.w;
      float s1 = o0 + o1 + o2 + o3;
      float s2 = o0*o0 + o1*o1 + o2*o2 + o3*o3;
      #pragma unroll
      for (int m = 1; m < 64; m <<= 1) {
        s1 += __shfl_xor(s1, m, 64);
        s2 += __shfl_xor(s2, m, 64);
      }
      float mean = s1 * (1.f / 256.f);
      float var = s2 * (1.f / 256.f) - mean * mean;
      float rs = rsqrtf(var + EPSV);
      float4 o;
      o.x = (o0 - mean) * rs * g4.x + bb4.x;
      o.y = (o1 - mean) * rs * g4.y + bb4.y;
      o.z = (o2 - mean) * rs * g4.z + bb4.z;
      o.w = (o3 - mean) * rs * g4.w + bb4.w;
      reinterpret_cast<float4*>(out + (size_t)(row0 + r) * DM)[colg] = o;
    }
  }
}

// ---- final LN + projection (pWT [256][96], batched) + denorm -------------
__global__ void k_final(const float* __restrict__ g, const float* __restrict__ bb,
                        const float* __restrict__ pWT, const float* __restrict__ pb,
                        const float* __restrict__ enc2,
                        const float* __restrict__ stdev, const float* __restrict__ means,
                        float* __restrict__ out) {
  int bi = blockIdx.x;                       // b*21+c
  int b = bi / CIN, c = bi % CIN;
  __shared__ __align__(16) float sx[DM];
  __shared__ float sb[8];
  int t = threadIdx.x;
  float v = enc2[(size_t)(b * NT + c) * DM + t];
  float2 mv = meanvar256(v, sb);
  sx[t] = (v - mv.x) * rsqrtf(mv.y + EPSV) * g[t] + bb[t];
  __syncthreads();
  if (t < PRED) {
    float acc = 0.f;
    #pragma unroll 1
    for (int k0 = 0; k0 < DM; k0 += 8) {
      float w[8];
      #pragma unroll
      for (int q = 0; q < 8; ++q) w[q] = pWT[(size_t)(k0 + q) * PRED + t];
      #pragma unroll
      for (int q = 0; q < 8; ++q) acc += sx[k0 + q] * w[q];
    }
    float y = (acc + pb[t]) * stdev[bi] + means[bi];
    out[(size_t)b * PRED * CIN + t * CIN + c] = y;
  }
}

extern "C" void kernel_launch(void* const* d_in, const int* in_sizes, int n_in,
                              void* d_out, int out_size, void* d_ws, size_t ws_size,
                              hipStream_t stream) {
  const float* x_enc   = (const float*)d_in[0];
  const float* x_mark  = (const float*)d_in[1];
  const float* tok_W   = (const float*)d_in[4];
  const float* patch_W = (const float*)d_in[5];
  const float* patch_b = (const float*)d_in[6];
  const float* nl_WQ   = (const float*)d_in[7];
  const float* nl_WK   = (const float*)d_in[8];
  const float* nl_WV   = (const float*)d_in[9];
  const float* nl_WO   = (const float*)d_in[10];
  const float* nl_bO   = (const float*)d_in[11];
  const float* nl_mu_a = (const float*)d_in[12];
  const float* nl_sg_a = (const float*)d_in[13];
  const float* nl_w_a  = (const float*)d_in[14];
  const float* nl_mu_r = (const float*)d_in[15];
  const float* nl_sg_r = (const float*)d_in[16];
  const float* nl_w_r  = (const float*)d_in[17];
  const float* nl_al   = (const float*)d_in[18];
  const float* nl_be   = (const float*)d_in[19];
  const float* nl_ga   = (const float*)d_in[20];
  const float* inv_W   = (const float*)d_in[21];
  const float* inv_b   = (const float*)d_in[22];
  const float* el_Wq   = (const float*)d_in[23];
  const float* el_bq   = (const float*)d_in[24];
  const float* el_Wk   = (const float*)d_in[25];
  const float* el_bk   = (const float*)d_in[26];
  const float* el_Wv   = (const float*)d_in[27];
  const float* el_bv   = (const float*)d_in[28];
  const float* el_Wo   = (const float*)d_in[29];
  const float* el_bo   = (const float*)d_in[30];
  const float* el_W1   = (const float*)d_in[31];
  const float* el_b1   = (const float*)d_in[32];
  const float* el_W2   = (const float*)d_in[33];
  const float* el_b2   = (const float*)d_in[34];
  const float* n1g     = (const float*)d_in[35];
  const float* n1b     = (const float*)d_in[36];
  const float* n2g     = (const float*)d_in[37];
  const float* n2b     = (const float*)d_in[38];
  const float* norm_g  = (const float*)d_in[39];
  const float* norm_b  = (const float*)d_in[40];
  const float* proj_W  = (const float*)d_in[41];
  const float* proj_b  = (const float*)d_in[42];

  // workspace layout (floats)
  float* ws = (float*)d_ws;
  float* means = ws + 0;          //     96
  float* stdev = ws + 96;         //     96
  float* tws   = ws + 192;        //   1024
  float* enc1  = ws + 1216;       // 524288  (B,512,256)
  float* encP  = ws + 525504;     //  64512  (252,256)
  float* pbuf  = ws + 590016;     // 516096  (8,252,256)
  float* enc2  = ws + 1106112;    // 266240  (1040,256)
  float* qb    = ws + 1638592;    // 266240  (xn aliases qb)
  float* kb    = ws + 1904832;    // 266240  (K or K^T)
  float* vb    = ws + 2171072;    // 266240
  float* y1    = ws + 2437312;    // 1064960 (1040,1024)
  float* encPb = ws + 3502272;    //  64512  (TKA ping-pong)
  float* grel  = ws + 4567232;    // 254016  (2,B,8,63,63)
  float* gib   = ws + 4821248;    //   4032  (2,B,8,63)
  float* wsT   = ws + 4825344;    // 3202560 (transposed weights)
  float* xn    = qb;              // alias: qb rows only self-read before overwrite

  // prep: weight transpose (3128) + stats/tws (88) + grel/gib (2016)
  k_prep<<<5232, 256, 0, stream>>>(nl_WQ, nl_WK, nl_WV, nl_WO,
                                   el_Wq, el_Wk, el_Wv, el_Wo,
                                   el_W1, el_W2, inv_W, proj_W,
                                   tok_W, patch_W, wsT,
                                   x_enc, x_mark, means, stdev, tws,
                                   nl_mu_r, nl_sg_r, nl_w_r,
                                   nl_mu_a, nl_sg_a, nl_w_a, grel, gib);
  k_tokconv<<<NB * 64, 256, 0, stream>>>(x_enc, wsT + T_tok, means, stdev, enc1);
  k_patch_part<<<42 * 8, 256, 0, stream>>>(enc1, wsT + T_pat, pbuf);

  // ---- TKA layer 0: fused patch-reduce + QKV, then attention -------------
  k_qkv_tka0<<<63 * 3, 256, 0, stream>>>(wsT + T_nlWQ, wsT + T_nlWK, wsT + T_nlWV,
                                         pbuf, patch_b, qb, kb, vb, encP);
  k_tka_attn_f<<<NB * EL, 512, 0, stream>>>(encP, qb, kb, vb,
      grel, gib, nl_al, nl_be, nl_ga,
      wsT + T_nlWO, nl_bO, encPb);
  // ---- TKA layer 1 -------------------------------------------------------
  {
    size_t wo = (size_t)DM * DM;
    k_qkv2<4><<<63 * 3, 256, 0, stream>>>(wsT + T_nlWQ + wo, wsT + T_nlWK + wo,
                                          wsT + T_nlWV + wo,
                                          nullptr, nullptr, nullptr,
                                          encPb, qb, kb, vb, 0);
    k_tka_attn_f<<<NB * EL, 512, 0, stream>>>(encPb, qb, kb, vb,
        grel + (size_t)(NB * NH * EL * EL), gib + (size_t)(NB * NH * EL),
        nl_al + 8, nl_be + 8, nl_ga + 8,
        wsT + T_nlWO + wo, nl_bO + DM, encP);
  }

  // ---- encoder layer 0: fused inv-embedding + QKV (K^T) ------------------
  k_qkv_enc0<<<130 * 3, 256, 0, stream>>>(wsT + T_elWq, wsT + T_elWk, wsT + T_elWv,
                                          el_bq, el_bk, el_bv,
                                          wsT + T_inv, inv_b, encP, tws,
                                          qb, kb, vb, enc2);
  k_enc_attn_f<<<NB * 130, 512, 0, stream>>>(qb, kb, vb, wsT + T_elWo, el_bo,
                                             n1g, n1b, enc2, xn, 130);
  k_ffn1<<<130 * 4, 256, 0, stream>>>(wsT + T_elW1, el_b1, xn, y1, 0);
  k_ffn2f<<<260, 512, 0, stream>>>(wsT + T_elW2, el_b2, n2g, n2b, y1, xn, enc2, 0);

  // ---- encoder layer 1: pruned — only rows [b*NT, b*NT+24) reach k_final --
  {
    size_t wo = (size_t)DM * DM;
    size_t bo = (size_t)DM;
    size_t fo = (size_t)DFF * DM;
    k_qkv_l1<<<272, 256, 0, stream>>>(wsT + T_elWq + wo, wsT + T_elWk + wo,
                                      wsT + T_elWv + wo,
                                      el_bq + bo, el_bk + bo, el_bv + bo,
                                      enc2, qb, kb, vb);
    k_enc_attn_f<<<NB * 12, 512, 0, stream>>>(qb, kb, vb, wsT + T_elWo + wo,
                                              el_bo + bo, n1g + bo, n1b + bo,
                                              enc2, xn, 12);
    k_ffn1<<<12 * 4, 256, 0, stream>>>(wsT + T_elW1 + fo, el_b1 + DFF, xn, y1, 3);
    k_ffn2f<<<NB * 6, 512, 0, stream>>>(wsT + T_elW2 + fo, el_b2 + bo,
                                        n2g + bo, n2b + bo, y1, xn, enc2, 6);
  }

  k_final<<<NB * CIN, 256, 0, stream>>>(norm_g, norm_b, wsT + T_proj, proj_b,
                                        enc2, stdev, means, (float*)d_out);
}

// Round 14
// 407.833 us; speedup vs baseline: 1.0522x; 1.0123x over previous
//
#include <hip/hip_runtime.h>
#include <hip/hip_bf16.h>

#define NB 4
#define SEQ 512
#define CIN 21
#define TDIM 4
#define DM 256
#define NH 8
#define PLEN 16
#define PSTR 8
#define EL 63
#define DFF 1024
#define PRED 96
#define NT 260
#define EPSV 1e-5f

// transposed-weight workspace offsets (floats)
#define T_nlWQ 0
#define T_nlWK 131072
#define T_nlWV 262144
#define T_nlWO 393216
#define T_elWq 524288
#define T_elWk 655360
#define T_elWv 786432
#define T_elWo 917504
#define T_elW1 1048576
#define T_elW2 1572864
#define T_inv  2097152
#define T_proj 2113280
#define T_tok  2137856
#define T_pat  2153984

// ---------------- helpers --------------------------------------------------
__device__ __forceinline__ float2 meanvar256(float v, float* sb) {
  __syncthreads();
  float s1 = v, s2 = v * v;
  #pragma unroll
  for (int off = 32; off > 0; off >>= 1) {
    s1 += __shfl_down(s1, off, 64);
    s2 += __shfl_down(s2, off, 64);
  }
  int wid = threadIdx.x >> 6, lane = threadIdx.x & 63;
  if (lane == 0) { sb[wid * 2] = s1; sb[wid * 2 + 1] = s2; }
  __syncthreads();
  float m = (sb[0] + sb[2] + sb[4] + sb[6]) * (1.0f / 256.0f);
  float q = (sb[1] + sb[3] + sb[5] + sb[7]) * (1.0f / 256.0f);
  return make_float2(m, q - m * m);
}

__device__ __forceinline__ void load16f(const float* p, float* o) {
  const float4* q = reinterpret_cast<const float4*>(p);
  float4 a = q[0], b = q[1], c = q[2], d = q[3];
  o[0]=a.x; o[1]=a.y; o[2]=a.z; o[3]=a.w;
  o[4]=b.x; o[5]=b.y; o[6]=b.z; o[7]=b.w;
  o[8]=c.x; o[9]=c.y; o[10]=c.z; o[11]=c.w;
  o[12]=d.x; o[13]=d.y; o[14]=d.z; o[15]=d.w;
}

__device__ __forceinline__ float dot32(const float4* a, const float4* b) {
  float s = 0.f;
  #pragma unroll
  for (int i = 0; i < 8; ++i) {
    float4 x = a[i], y = b[i];
    s += x.x*y.x + x.y*y.y + x.z*y.z + x.w*y.w;
  }
  return s;
}

// ---- K0: weight transpose (3128) + RevIN stats/tws (88) + g_rel (2016) ---
__global__ void __launch_bounds__(256) k_prep(
    const float* __restrict__ nlWQ, const float* __restrict__ nlWK,
    const float* __restrict__ nlWV, const float* __restrict__ nlWO,
    const float* __restrict__ eWq, const float* __restrict__ eWk,
    const float* __restrict__ eWv, const float* __restrict__ eWo,
    const float* __restrict__ eW1, const float* __restrict__ eW2,
    const float* __restrict__ invW, const float* __restrict__ projW,
    const float* __restrict__ tokW, const float* __restrict__ patW,
    float* __restrict__ wt,
    const float* __restrict__ x, const float* __restrict__ xm,
    float* __restrict__ means, float* __restrict__ stdev,
    float* __restrict__ tout,
    const float* __restrict__ mu_r, const float* __restrict__ sg_r,
    const float* __restrict__ w_r,
    const float* __restrict__ mu_a, const float* __restrict__ sg_a,
    const float* __restrict__ w_a,
    float* __restrict__ grel, float* __restrict__ gib) {
  __shared__ float smem[32 * 33];
  int blk = blockIdx.x;
  int t = threadIdx.x;

  if (blk < 3128) {
    // ----- weight transpose (32x32 LDS tiles) -----
    const float* src; float* dst; int R, C, tr, tc;
    if (blk < 1024) {                 // 16 square [256][256] mats
      int m = blk >> 6, tile = blk & 63;
      tr = tile >> 3; tc = tile & 7; R = 256; C = 256;
      int p = m >> 1, l = m & 1;
      const float* bases[8] = {nlWQ, nlWK, nlWV, nlWO, eWq, eWk, eWv, eWo};
      const int offs[8] = {T_nlWQ, T_nlWK, T_nlWV, T_nlWO, T_elWq, T_elWk, T_elWv, T_elWo};
      src = bases[p] + l * 65536;
      dst = wt + offs[p] + l * 65536;
    } else if (blk < 1536) {          // W1 [1024][256] x2
      int q = blk - 1024; int l = q >> 8, s = q & 255;
      tr = s >> 3; tc = s & 7; R = 1024; C = 256;
      src = eW1 + l * 262144; dst = wt + T_elW1 + l * 262144;
    } else if (blk < 2048) {          // W2 [256][1024] x2
      int q = blk - 1536; int l = q >> 8, s = q & 255;
      tr = s >> 5; tc = s & 31; R = 256; C = 1024;
      src = eW2 + l * 262144; dst = wt + T_elW2 + l * 262144;
    } else if (blk < 3072) {          // patch_W [256][4096]
      int q = blk - 2048; tr = q >> 7; tc = q & 127; R = 256; C = 4096;
      src = patW; dst = wt + T_pat;
    } else if (blk < 3088) {          // inv_W [256][63]
      int q = blk - 3072; tr = q >> 1; tc = q & 1; R = 256; C = 63;
      src = invW; dst = wt + T_inv;
    } else if (blk < 3112) {          // proj_W [96][256]
      int q = blk - 3088; tr = q >> 3; tc = q & 7; R = 96; C = 256;
      src = projW; dst = wt + T_proj;
    } else {                          // tok_W [256][63]
      int q = blk - 3112; tr = q >> 1; tc = q & 1; R = 256; C = 63;
      src = tokW; dst = wt + T_tok;
    }
    float (*ts)[33] = (float(*)[33])smem;
    int tx = t & 31, ty = t >> 5;
    #pragma unroll
    for (int i = 0; i < 4; ++i) {
      int r = tr * 32 + ty + i * 8, c = tc * 32 + tx;
      ts[ty + i * 8][tx] = (c < C) ? src[(size_t)r * C + c] : 0.f;
    }
    __syncthreads();
    #pragma unroll
    for (int i = 0; i < 4; ++i) {
      int c = tc * 32 + ty + i * 8, r = tr * 32 + tx;
      if (c < C) dst[(size_t)c * R + r] = ts[tx][ty + i * 8];
    }
  } else if (blk < 3216) {
    // ----- RevIN stats (84) + patch-time means (4) -----
    int sblk = blk - 3128;
    if (sblk < NB * CIN) {
      int b = sblk / CIN, c = sblk % CIN;
      const float* p = x + (size_t)b * SEQ * CIN + c;
      float v0 = p[t * CIN];
      float v1 = p[(t + 256) * CIN];
      float s1 = v0 + v1, s2 = v0 * v0 + v1 * v1;
      float* sb = smem;
      #pragma unroll
      for (int off = 32; off > 0; off >>= 1) {
        s1 += __shfl_down(s1, off, 64);
        s2 += __shfl_down(s2, off, 64);
      }
      int wid = t >> 6, lane = t & 63;
      if (lane == 0) { sb[wid * 2] = s1; sb[wid * 2 + 1] = s2; }
      __syncthreads();
      if (t == 0) {
        float a = sb[0] + sb[2] + sb[4] + sb[6];
        float q = sb[1] + sb[3] + sb[5] + sb[7];
        float m = a * (1.0f / 512.0f);
        float var = q * (1.0f / 512.0f) - m * m;
        means[sblk] = m;
        stdev[sblk] = sqrtf(var + EPSV);
      }
    } else {
      int idx = (sblk - NB * CIN) * 256 + t;
      if (idx >= NB * EL * TDIM) return;
      int b = idx / (EL * TDIM), r = idx % (EL * TDIM);
      int l = r >> 2, ti = r & 3;
      const float* p = xm + (size_t)b * SEQ * TDIM + (size_t)l * PSTR * TDIM + ti;
      float s = 0.f;
      #pragma unroll
      for (int k = 0; k < PLEN; ++k) s += p[k * TDIM];
      tout[idx] = s * (1.f / 16.f);
    }
  } else {
    // ----- g_rel + g_abs, both layers; s_t computed inline from xm -----
    int gblk = blk - 3216;                   // L*(NB*252) + b*252 + chunk
    int L = gblk / (NB * 252);
    int rem0 = gblk % (NB * 252);
    int b = rem0 / 252, chunk = rem0 % 252;
    int po = L * 4096;
    float* grelL = grel + (size_t)L * (NB * NH * EL * EL);
    float* gibL  = gib + (size_t)L * (NB * NH * EL);
    int h = t >> 5, dh = t & 31;
    float* s_t = smem;
    if (t < EL * TDIM) {
      int l = t >> 2, ti = t & 3;
      const float* p = xm + (size_t)b * SEQ * TDIM + (size_t)l * PSTR * TDIM + ti;
      float s = 0.f;
      #pragma unroll
      for (int k = 0; k < PLEN; ++k) s += p[k * TDIM];
      s_t[t] = s * (1.f / 16.f);
    }
    float pm[16], pc[16], pw[16];
    load16f(mu_r + po + (size_t)t * 16, pm);
    load16f(sg_r + po + (size_t)t * 16, pc);
    load16f(w_r  + po + (size_t)t * 16, pw);
    #pragma unroll
    for (int p = 0; p < 16; ++p) pc[p] = -0.5f / (pc[p] * pc[p]);
    __syncthreads();
    #pragma unroll 1
    for (int q = 0; q < 8; ++q) {
      int p = chunk * 8 + q;                 // 2016 (i<=j) pairs
      int i = (int)((127.0f - sqrtf(16129.0f - 8.0f * (float)p)) * 0.5f);
      while (i * (127 - i) / 2 > p) --i;
      while ((i + 1) * (126 - i) / 2 <= p) ++i;
      int j = i + (p - i * (127 - i) / 2);
      float dvv[4];
      dvv[0] = fabsf(s_t[i*4+0] - s_t[j*4+0]);
      dvv[1] = fabsf(s_t[i*4+1] - s_t[j*4+1]);
      dvv[2] = fabsf(s_t[i*4+2] - s_t[j*4+2]);
      dvv[3] = fabsf(s_t[i*4+3] - s_t[j*4+3]);
      float srel = 0.f;
      #pragma unroll
      for (int tt = 0; tt < 4; ++tt)
        #pragma unroll
        for (int k = 0; k < 4; ++k) {
          int pp = tt * 4 + k;
          float df = dvv[tt] - pm[pp];
          srel += pw[pp] * __expf(pc[pp] * df * df);
        }
      #pragma unroll
      for (int m = 1; m < 32; m <<= 1) srel += __shfl_xor(srel, m, 64);
      if (dh == 0) {
        float v = srel * (1.f / 32.f);
        grelL[(((size_t)b * NH + h) * EL + i) * EL + j] = v;
        grelL[(((size_t)b * NH + h) * EL + j) * EL + i] = v;
      }
    }
    if (chunk < EL) {
      load16f(mu_a + po + (size_t)t * 16, pm);
      load16f(sg_a + po + (size_t)t * 16, pc);
      load16f(w_a  + po + (size_t)t * 16, pw);
      #pragma unroll
      for (int p = 0; p < 16; ++p) pc[p] = -0.5f / (pc[p] * pc[p]);
      int i = chunk;
      float tiv[4] = {s_t[i*4+0], s_t[i*4+1], s_t[i*4+2], s_t[i*4+3]};
      float sabs = 0.f;
      #pragma unroll
      for (int tt = 0; tt < 4; ++tt)
        #pragma unroll
        for (int k = 0; k < 4; ++k) {
          int pp = tt * 4 + k;
          float df = tiv[tt] - pm[pp];
          sabs += pw[pp] * __expf(pc[pp] * df * df);
        }
      #pragma unroll
      for (int m = 1; m < 32; m <<= 1) sabs += __shfl_xor(sabs, m, 64);
      if (dh == 0) gibL[((size_t)b * NH + h) * EL + i] = sabs * (1.f / 32.f);
    }
  }
}

// ---- K3a: token conv + PE (tokWT [63][256] coalesced) --------------------
__global__ void __launch_bounds__(256) k_tokconv(
    const float* __restrict__ x, const float* __restrict__ tokWT,
    const float* __restrict__ means, const float* __restrict__ stdev,
    float* __restrict__ enc1) {
  int bi = blockIdx.x;                       // b*64 + sg
  int b = bi >> 6, sg = bi & 63;
  int s0 = sg * 8;
  __shared__ float sxr[10 * CIN];
  int t = threadIdx.x;
  if (t < 10 * CIN) {
    int li = t / CIN, c = t % CIN;
    int row = (s0 - 1 + li + SEQ) & 511;
    sxr[t] = (x[(size_t)b * SEQ * CIN + row * CIN + c] - means[b * CIN + c])
             / stdev[b * CIN + c];
  }
  __syncthreads();
  int d = t;
  float wreg[63];
  #pragma unroll
  for (int q = 0; q < 63; ++q) wreg[q] = tokWT[q * DM + d];
  int de = d & ~1;
  float dv = expf((float)de * (-9.210340371976184f / 256.0f));
  bool isodd = (d & 1);
  #pragma unroll 1
  for (int k = 0; k < 8; ++k) {
    float acc = 0.f;
    const float* sr = sxr + k * CIN;
    #pragma unroll
    for (int c = 0; c < CIN; ++c) {
      acc += sr[c]           * wreg[c * 3 + 0];
      acc += sr[CIN + c]     * wreg[c * 3 + 1];
      acc += sr[2 * CIN + c] * wreg[c * 3 + 2];
    }
    float ang = (float)(s0 + k) * dv;
    float pe = isodd ? cosf(ang) : sinf(ang);
    enc1[((size_t)b * SEQ + s0 + k) * DM + d] = acc + pe;
  }
}

// ---- K3b: patch conv partials (patWT [4096][256], batched loads) ---------
__global__ void __launch_bounds__(256) k_patch_part(
    const float* __restrict__ enc1, const float* __restrict__ pWT,
    float* __restrict__ pbuf) {
  int bi = blockIdx.x;
  int pg = bi >> 3, kc = bi & 7;
  int p0 = pg * 6;
  __shared__ __align__(16) float sA[6 * 32 * 20];
  int t = threadIdx.x;
  for (int idx = t; idx < 6 * 32 * PLEN; idx += 256) {
    int pp = idx >> 9;
    int rem = idx & 511;
    int c = rem >> 4, k = rem & 15;
    int p = p0 + pp;
    int b = p / EL, l = p % EL;
    sA[pp * 640 + c * 20 + k] =
        enc1[((size_t)b * SEQ + l * PSTR + k) * DM + kc * 32 + c];
  }
  __syncthreads();
  int d = t;
  const float* wb = pWT + (size_t)(kc * 32 * PLEN) * DM + d;
  float acc[6] = {0.f, 0.f, 0.f, 0.f, 0.f, 0.f};
  #pragma unroll 1
  for (int kk0 = 0; kk0 < 512; kk0 += 8) {
    float w[8];
    #pragma unroll
    for (int q = 0; q < 8; ++q) w[q] = wb[(size_t)(kk0 + q) * DM];
    #pragma unroll
    for (int q = 0; q < 8; ++q) {
      int kk = kk0 + q;
      const float* sa = sA + (kk >> 4) * 20 + (kk & 15);
      acc[0] += sa[0 * 640] * w[q];
      acc[1] += sa[1 * 640] * w[q];
      acc[2] += sa[2 * 640] * w[q];
      acc[3] += sa[3 * 640] * w[q];
      acc[4] += sa[4 * 640] * w[q];
      acc[5] += sa[5 * 640] * w[q];
    }
  }
  const int S = NB * EL * DM;
  #pragma unroll
  for (int pp = 0; pp < 6; ++pp)
    pbuf[(size_t)kc * S + (size_t)(p0 + pp) * DM + d] = acc[pp];
}

// ---- TKA L0 QKV: fused pbuf-reduce (patch_red) + QKV GEMM ----------------
__global__ void __launch_bounds__(256) k_qkv_tka0(
    const float* __restrict__ WqT, const float* __restrict__ WkT,
    const float* __restrict__ WvT,
    const float* __restrict__ pbuf, const float* __restrict__ pb,
    float* __restrict__ qo, float* __restrict__ ko, float* __restrict__ vo,
    float* __restrict__ encPo) {
  int bi = blockIdx.x;
  int rg = bi / 3, mat = bi % 3;
  int row0 = rg * 4;
  __shared__ __align__(16) float sx[4 * DM];
  __shared__ __align__(16) float sp[3 * 4 * DM];
  int t = threadIdx.x;
  int colg = t & 63, kq = t >> 6;
  const int S = NB * EL * DM;
  #pragma unroll
  for (int i = 0; i < 4; ++i) {
    int idx = t + i * 256;
    const float* pp = pbuf + (size_t)row0 * DM + idx;
    float pv[8];
    #pragma unroll
    for (int s = 0; s < 8; ++s) pv[s] = pp[(size_t)s * S];
    float v = pb[idx & 255];
    #pragma unroll
    for (int s = 0; s < 8; ++s) v += pv[s];
    sx[idx] = v;
    if (mat == 0) encPo[(size_t)row0 * DM + idx] = v;
  }
  __syncthreads();
  const float* WT = (mat == 0) ? WqT : (mat == 1) ? WkT : WvT;
  float* out = (mat == 0) ? qo : (mat == 1) ? ko : vo;
  float acc[4][4];
  #pragma unroll
  for (int r = 0; r < 4; ++r) { acc[r][0]=0.f; acc[r][1]=0.f; acc[r][2]=0.f; acc[r][3]=0.f; }
  const float* xb = sx + kq * 64;
  const float4* wp = reinterpret_cast<const float4*>(WT + (size_t)(kq * 64) * DM) + colg;
  #pragma unroll 1
  for (int k0 = 0; k0 < 64; k0 += 4) {
    float4 w[4];
    #pragma unroll
    for (int q = 0; q < 4; ++q) w[q] = wp[(size_t)(k0 + q) * 64];
    #pragma unroll
    for (int q = 0; q < 4; ++q)
      #pragma unroll
      for (int r = 0; r < 4; ++r) {
        float xv = xb[r * DM + k0 + q];
        acc[r][0] += xv * w[q].x; acc[r][1] += xv * w[q].y;
        acc[r][2] += xv * w[q].z; acc[r][3] += xv * w[q].w;
      }
  }
  if (kq) {
    #pragma unroll
    for (int r = 0; r < 4; ++r)
      reinterpret_cast<float4*>(sp)[((kq - 1) * 4 + r) * 64 + colg] =
          make_float4(acc[r][0], acc[r][1], acc[r][2], acc[r][3]);
  }
  __syncthreads();
  if (kq == 0) {
    const float4* sp4 = reinterpret_cast<const float4*>(sp);
    #pragma unroll
    for (int r = 0; r < 4; ++r) {
      float4 p0 = sp4[(0 * 4 + r) * 64 + colg];
      float4 p1 = sp4[(1 * 4 + r) * 64 + colg];
      float4 p2 = sp4[(2 * 4 + r) * 64 + colg];
      float4 o;
      o.x = acc[r][0] + p0.x + p1.x + p2.x;
      o.y = acc[r][1] + p0.y + p1.y + p2.y;
      o.z = acc[r][2] + p0.z + p1.z + p2.z;
      o.w = acc[r][3] + p0.w + p1.w + p2.w;
      reinterpret_cast<float4*>(out + (size_t)(row0 + r) * DM)[colg] = o;
    }
  }
}

// ---- QKV (TKA layer 1): WT [256][256], reg-tile, K-split 4 ---------------
template<int R>
__global__ void __launch_bounds__(256) k_qkv2(
    const float* __restrict__ WqT, const float* __restrict__ WkT,
    const float* __restrict__ WvT,
    const float* __restrict__ bq, const float* __restrict__ bk,
    const float* __restrict__ bv,
    const float* __restrict__ xin,
    float* __restrict__ qo, float* __restrict__ ko, float* __restrict__ vo,
    int ktm) {
  int bi = blockIdx.x;
  int rg = bi / 3, mat = bi % 3;
  int row0 = rg * R;
  __shared__ __align__(16) float sx[R * DM];
  __shared__ __align__(16) float sp[3 * R * DM];
  int t = threadIdx.x;
  int colg = t & 63, kq = t >> 6;
  #pragma unroll
  for (int i = 0; i < R / 4; ++i)
    reinterpret_cast<float4*>(sx)[t + i * 256] =
        reinterpret_cast<const float4*>(xin + (size_t)row0 * DM)[t + i * 256];
  __syncthreads();
  const float* WT = (mat == 0) ? WqT : (mat == 1) ? WkT : WvT;
  const float* bias = (mat == 0) ? bq : (mat == 1) ? bk : bv;
  float* out = (mat == 0) ? qo : (mat == 1) ? ko : vo;
  float acc[R][4];
  #pragma unroll
  for (int r = 0; r < R; ++r) { acc[r][0]=0.f; acc[r][1]=0.f; acc[r][2]=0.f; acc[r][3]=0.f; }
  const float* xb = sx + kq * 64;
  const float4* wp = reinterpret_cast<const float4*>(WT + (size_t)(kq * 64) * DM) + colg;
  #pragma unroll 1
  for (int k0 = 0; k0 < 64; k0 += 4) {
    float4 w[4];
    #pragma unroll
    for (int q = 0; q < 4; ++q) w[q] = wp[(size_t)(k0 + q) * 64];
    #pragma unroll
    for (int q = 0; q < 4; ++q)
      #pragma unroll
      for (int r = 0; r < R; ++r) {
        float xv = xb[r * DM + k0 + q];
        acc[r][0] += xv * w[q].x; acc[r][1] += xv * w[q].y;
        acc[r][2] += xv * w[q].z; acc[r][3] += xv * w[q].w;
      }
  }
  if (kq) {
    #pragma unroll
    for (int r = 0; r < R; ++r)
      reinterpret_cast<float4*>(sp)[((kq - 1) * R + r) * 64 + colg] =
          make_float4(acc[r][0], acc[r][1], acc[r][2], acc[r][3]);
  }
  __syncthreads();
  if (kq == 0) {
    float4 b4 = bias ? reinterpret_cast<const float4*>(bias)[colg]
                     : make_float4(0.f, 0.f, 0.f, 0.f);
    const float4* sp4 = reinterpret_cast<const float4*>(sp);
    #pragma unroll
    for (int r = 0; r < R; ++r) {
      float4 p0 = sp4[(0 * R + r) * 64 + colg];
      float4 p1 = sp4[(1 * R + r) * 64 + colg];
      float4 p2 = sp4[(2 * R + r) * 64 + colg];
      float4 o;
      o.x = acc[r][0] + p0.x + p1.x + p2.x + b4.x;
      o.y = acc[r][1] + p0.y + p1.y + p2.y + b4.y;
      o.z = acc[r][2] + p0.z + p1.z + p2.z + b4.z;
      o.w = acc[r][3] + p0.w + p1.w + p2.w + b4.w;
      if (ktm && mat == 1) {
        int gr = row0 + r, bb2 = gr / NT, jj2 = gr % NT;
        float* kd = out + (size_t)bb2 * (DM * NT) + jj2;
        kd[(size_t)(colg * 4 + 0) * NT] = o.x;
        kd[(size_t)(colg * 4 + 1) * NT] = o.y;
        kd[(size_t)(colg * 4 + 2) * NT] = o.z;
        kd[(size_t)(colg * 4 + 3) * NT] = o.w;
      } else {
        reinterpret_cast<float4*>(out + (size_t)(row0 + r) * DM)[colg] = o;
      }
    }
  }
}

// ---- encoder-L0 QKV: fused inverted-embedding + QKV (K written ^T) -------
__global__ void __launch_bounds__(256) k_qkv_enc0(
    const float* __restrict__ WqT, const float* __restrict__ WkT,
    const float* __restrict__ WvT,
    const float* __restrict__ bq, const float* __restrict__ bk,
    const float* __restrict__ bv,
    const float* __restrict__ invWT, const float* __restrict__ invb,
    const float* __restrict__ encP, const float* __restrict__ tws,
    float* __restrict__ qo, float* __restrict__ ko, float* __restrict__ vo,
    float* __restrict__ enc2) {
  int bi = blockIdx.x;
  int rg = bi / 3, mat = bi % 3;
  int row0 = rg * 8;
  __shared__ __align__(16) float sx[8 * DM];
  __shared__ float sxe[EL * 8 + 8];            // [l][r]
  __shared__ __align__(16) float sp[3 * 8 * DM];
  int t = threadIdx.x;
  int colg = t & 63, kq = t >> 6;
  // gather encP columns / tws for the block's 8 output rows
  #pragma unroll
  for (int it = 0; it < 2; ++it) {
    int idx = t + it * 256;
    if (idx < EL * 8) {
      int l = idx >> 3, r = idx & 7;
      int gr = row0 + r, bb2 = gr / NT, n = gr % NT;
      float v;
      if (n < DM) v = encP[(size_t)(bb2 * EL + l) * DM + n];
      else        v = tws[bb2 * EL * TDIM + l * TDIM + (n - DM)];
      sxe[l * 8 + r] = v;
    }
  }
  __syncthreads();
  // inverted embedding: thread t = output col, 8 rows
  {
    float bv2 = invb[t];
    float acc2[8];
    #pragma unroll
    for (int r = 0; r < 8; ++r) acc2[r] = bv2;
    #pragma unroll 1
    for (int l0 = 0; l0 < EL; l0 += 9) {
      float w[9];
      #pragma unroll
      for (int q = 0; q < 9; ++q) w[q] = invWT[(size_t)(l0 + q) * DM + t];
      #pragma unroll
      for (int q = 0; q < 9; ++q)
        #pragma unroll
        for (int r = 0; r < 8; ++r)
          acc2[r] += sxe[(l0 + q) * 8 + r] * w[q];
    }
    #pragma unroll
    for (int r = 0; r < 8; ++r) {
      sx[r * DM + t] = acc2[r];
      if (mat == 0) enc2[(size_t)(row0 + r) * DM + t] = acc2[r];
    }
  }
  __syncthreads();
  // QKV GEMM (K transposed out)
  const float* WT = (mat == 0) ? WqT : (mat == 1) ? WkT : WvT;
  const float* bias = (mat == 0) ? bq : (mat == 1) ? bk : bv;
  float* out = (mat == 0) ? qo : (mat == 1) ? ko : vo;
  float acc[8][4];
  #pragma unroll
  for (int r = 0; r < 8; ++r) { acc[r][0]=0.f; acc[r][1]=0.f; acc[r][2]=0.f; acc[r][3]=0.f; }
  const float* xb = sx + kq * 64;
  const float4* wp = reinterpret_cast<const float4*>(WT + (size_t)(kq * 64) * DM) + colg;
  #pragma unroll 1
  for (int k0 = 0; k0 < 64; k0 += 4) {
    float4 w[4];
    #pragma unroll
    for (int q = 0; q < 4; ++q) w[q] = wp[(size_t)(k0 + q) * 64];
    #pragma unroll
    for (int q = 0; q < 4; ++q)
      #pragma unroll
      for (int r = 0; r < 8; ++r) {
        float xv = xb[r * DM + k0 + q];
        acc[r][0] += xv * w[q].x; acc[r][1] += xv * w[q].y;
        acc[r][2] += xv * w[q].z; acc[r][3] += xv * w[q].w;
      }
  }
  if (kq) {
    #pragma unroll
    for (int r = 0; r < 8; ++r)
      reinterpret_cast<float4*>(sp)[((kq - 1) * 8 + r) * 64 + colg] =
          make_float4(acc[r][0], acc[r][1], acc[r][2], acc[r][3]);
  }
  __syncthreads();
  if (kq == 0) {
    float4 b4 = reinterpret_cast<const float4*>(bias)[colg];
    const float4* sp4 = reinterpret_cast<const float4*>(sp);
    #pragma unroll
    for (int r = 0; r < 8; ++r) {
      float4 p0 = sp4[(0 * 8 + r) * 64 + colg];
      float4 p1 = sp4[(1 * 8 + r) * 64 + colg];
      float4 p2 = sp4[(2 * 8 + r) * 64 + colg];
      float4 o;
      o.x = acc[r][0] + p0.x + p1.x + p2.x + b4.x;
      o.y = acc[r][1] + p0.y + p1.y + p2.y + b4.y;
      o.z = acc[r][2] + p0.z + p1.z + p2.z + b4.z;
      o.w = acc[r][3] + p0.w + p1.w + p2.w + b4.w;
      if (mat == 1) {
        int gr = row0 + r, bb2 = gr / NT, jj2 = gr % NT;
        float* kd = out + (size_t)bb2 * (DM * NT) + jj2;
        kd[(size_t)(colg * 4 + 0) * NT] = o.x;
        kd[(size_t)(colg * 4 + 1) * NT] = o.y;
        kd[(size_t)(colg * 4 + 2) * NT] = o.z;
        kd[(size_t)(colg * 4 + 3) * NT] = o.w;
      } else {
        reinterpret_cast<float4*>(out + (size_t)(row0 + r) * DM)[colg] = o;
      }
    }
  }
}

// ---- QKV layer-1: K^T full (1040 rows) + V full + Q first 24 rows per b --
__global__ void __launch_bounds__(256) k_qkv_l1(
    const float* __restrict__ WqT, const float* __restrict__ WkT,
    const float* __restrict__ WvT,
    const float* __restrict__ bq, const float* __restrict__ bk,
    const float* __restrict__ bv,
    const float* __restrict__ xin,
    float* __restrict__ qo, float* __restrict__ ko, float* __restrict__ vo) {
  int bi = blockIdx.x;
  const float* WT; const float* bias; float* out; int row0; int ktm = 0;
  if (bi < 130)      { WT = WkT; bias = bk; out = ko; row0 = bi * 8; ktm = 1; }
  else if (bi < 260) { WT = WvT; bias = bv; out = vo; row0 = (bi - 130) * 8; }
  else {             // 12 blocks: Q for rows b*NT + [0,24)
    int gq = bi - 260;
    WT = WqT; bias = bq; out = qo;
    row0 = (gq / 3) * NT + (gq % 3) * 8;
  }
  __shared__ __align__(16) float sx[8 * DM];
  __shared__ __align__(16) float sp[3 * 8 * DM];
  int t = threadIdx.x;
  int colg = t & 63, kq = t >> 6;
  #pragma unroll
  for (int i = 0; i < 2; ++i)
    reinterpret_cast<float4*>(sx)[t + i * 256] =
        reinterpret_cast<const float4*>(xin + (size_t)row0 * DM)[t + i * 256];
  __syncthreads();
  float acc[8][4];
  #pragma unroll
  for (int r = 0; r < 8; ++r) { acc[r][0]=0.f; acc[r][1]=0.f; acc[r][2]=0.f; acc[r][3]=0.f; }
  const float* xb = sx + kq * 64;
  const float4* wp = reinterpret_cast<const float4*>(WT + (size_t)(kq * 64) * DM) + colg;
  #pragma unroll 1
  for (int k0 = 0; k0 < 64; k0 += 4) {
    float4 w[4];
    #pragma unroll
    for (int q = 0; q < 4; ++q) w[q] = wp[(size_t)(k0 + q) * 64];
    #pragma unroll
    for (int q = 0; q < 4; ++q)
      #pragma unroll
      for (int r = 0; r < 8; ++r) {
        float xv = xb[r * DM + k0 + q];
        acc[r][0] += xv * w[q].x; acc[r][1] += xv * w[q].y;
        acc[r][2] += xv * w[q].z; acc[r][3] += xv * w[q].w;
      }
  }
  if (kq) {
    #pragma unroll
    for (int r = 0; r < 8; ++r)
      reinterpret_cast<float4*>(sp)[((kq - 1) * 8 + r) * 64 + colg] =
          make_float4(acc[r][0], acc[r][1], acc[r][2], acc[r][3]);
  }
  __syncthreads();
  if (kq == 0) {
    float4 b4 = reinterpret_cast<const float4*>(bias)[colg];
    const float4* sp4 = reinterpret_cast<const float4*>(sp);
    #pragma unroll
    for (int r = 0; r < 8; ++r) {
      float4 p0 = sp4[(0 * 8 + r) * 64 + colg];
      float4 p1 = sp4[(1 * 8 + r) * 64 + colg];
      float4 p2 = sp4[(2 * 8 + r) * 64 + colg];
      float4 o;
      o.x = acc[r][0] + p0.x + p1.x + p2.x + b4.x;
      o.y = acc[r][1] + p0.y + p1.y + p2.y + b4.y;
      o.z = acc[r][2] + p0.z + p1.z + p2.z + b4.z;
      o.w = acc[r][3] + p0.w + p1.w + p2.w + b4.w;
      if (ktm) {
        int gr = row0 + r, bb2 = gr / NT, jj2 = gr % NT;
        float* kd = out + (size_t)bb2 * (DM * NT) + jj2;
        kd[(size_t)(colg * 4 + 0) * NT] = o.x;
        kd[(size_t)(colg * 4 + 1) * NT] = o.y;
        kd[(size_t)(colg * 4 + 2) * NT] = o.z;
        kd[(size_t)(colg * 4 + 3) * NT] = o.w;
      } else {
        reinterpret_cast<float4*>(out + (size_t)(row0 + r) * DM)[colg] = o;
      }
    }
  }
}

// ---- TKA attention + fused Wo^T, 512 threads, split PV / split-K Wo ------
__global__ void __launch_bounds__(512) k_tka_attn_f(
    const float* __restrict__ xin, const float* __restrict__ qw,
    const float* __restrict__ kw, const float* __restrict__ vw,
    const float* __restrict__ grel, const float* __restrict__ gib,
    const float* __restrict__ alpha, const float* __restrict__ beta,
    const float* __restrict__ gamma,
    const float* __restrict__ WOT, const float* __restrict__ bO,
    float* __restrict__ xout) {
  int bi = blockIdx.x;                       // b*63+i
  int b = bi / EL, i = bi % EL;
  int t = threadIdx.x;
  __shared__ __align__(16) float sQX[2 * DM];
  __shared__ float sP[NH * 64];
  __shared__ __align__(16) float sO[DM];
  __shared__ float sPV[DM];
  if (t < 2 * DM)
    sQX[t] = (t < DM) ? qw[(size_t)bi * DM + t] : xin[(size_t)bi * DM + (t - DM)];
  __syncthreads();
  {
    int tile = t >> 8, h = (t >> 5) & 7, jj = t & 31;
    int j = tile * 32 + jj;
    bool valid = (j < EL);
    int jc = valid ? j : (EL - 1);
    float gi = gib[((size_t)b * NH + h) * EL + i];
    float al = alpha[h], be = beta[h], ga = gamma[h];
    const float* grow = grel + (((size_t)b * NH + h) * EL + i) * EL;
    const float4* kp = reinterpret_cast<const float4*>(
        kw + (size_t)(b * EL + jc) * DM + h * 32);
    const float4* xp = reinterpret_cast<const float4*>(
        xin + (size_t)(b * EL + jc) * DM + h * 32);
    float4 kf[8], xf[8];
    #pragma unroll
    for (int q = 0; q < 8; ++q) { kf[q] = kp[q]; xf[q] = xp[q]; }
    float qk  = dot32(reinterpret_cast<const float4*>(sQX + h * 32), kf);
    float pij = dot32(reinterpret_cast<const float4*>(sQX + DM + h * 32), xf);
    float A = al * pij * (2.f * gi) + be * pij * grow[jc] + ga;
    const float scale = 0.17677669529663687f;
    sP[h * 64 + tile * 32 + jj] = valid ? (qk * scale * A) : -1e30f;
  }
  __syncthreads();
  {
    int h = t >> 6, dh = t & 63;               // one wave per head
    float v = sP[h * 64 + dh];
    float m = v;
    #pragma unroll
    for (int s = 1; s < 64; s <<= 1) m = fmaxf(m, __shfl_xor(m, s, 64));
    float e = __expf(v - m);
    float ssum = e;
    #pragma unroll
    for (int s = 1; s < 64; s <<= 1) ssum += __shfl_xor(ssum, s, 64);
    sP[h * 64 + dh] = e / ssum;                // dh=63 -> 0
  }
  __syncthreads();
  {
    int ch = t & 255, jh = t >> 8, hh = ch >> 5;
    float acc = 0.f;
    const float* pp = sP + hh * 64 + jh * 32;
    int jbase = jh * 32;
    #pragma unroll 1
    for (int j0 = 0; j0 < 32; j0 += 8) {
      float v[8];
      #pragma unroll
      for (int q = 0; q < 8; ++q) {
        int jx = jbase + j0 + q;
        if (jx > 62) jx = 62;                  // j=63 weight is 0; avoid stale row
        v[q] = vw[(size_t)(b * EL + jx) * DM + ch];
      }
      #pragma unroll
      for (int q = 0; q < 8; ++q) acc += pp[j0 + q] * v[q];
    }
    if (jh) sPV[ch] = acc;
    __syncthreads();
    if (!jh) sO[ch] = acc + sPV[ch];
  }
  __syncthreads();
  {
    int col = t & 255, kh = t >> 8;
    float acc = 0.f;
    const float* wc = WOT + (size_t)(kh * 128) * DM + col;
    const float* sx = sO + kh * 128;
    #pragma unroll 1
    for (int k0 = 0; k0 < 128; k0 += 8) {
      float w[8];
      #pragma unroll
      for (int q = 0; q < 8; ++q) w[q] = wc[(size_t)(k0 + q) * DM];
      #pragma unroll
      for (int q = 0; q < 8; ++q) acc += sx[k0 + q] * w[q];
    }
    if (kh) sPV[col] = acc;
    __syncthreads();
    if (!kh) xout[(size_t)bi * DM + col] = acc + sPV[col] + bO[col];
  }
}

// ---- encoder attention, 512 thr, 2 rows/block, K^T coalesced scores ------
// kw is K^T [b][256][260]. tpb: i-tiles (2 rows) per batch (130 / 12).
__global__ void __launch_bounds__(512) k_enc_attn_f(
    const float* __restrict__ qw, const float* __restrict__ kw,
    const float* __restrict__ vw,
    const float* __restrict__ WoT, const float* __restrict__ bo,
    const float* __restrict__ g, const float* __restrict__ bb,
    const float* __restrict__ resin, float* __restrict__ out, int tpb) {
  int blk = blockIdx.x;                      // b*tpb + tile
  int b = blk / tpb, it = blk % tpb;
  int i0 = it * 2;
  int t = threadIdx.x;

  __shared__ __align__(16) float sQ[2 * DM]; // Q rows; later normalized PV out
  __shared__ float sS[2 * NH * NT];          // 16.6 KB
  __shared__ float sL[2 * NH];
  __shared__ __align__(16) float sPV[2 * DM];
  __shared__ float sb[8];

  for (int idx = t; idx < 2 * DM; idx += 512)
    sQ[idx] = qw[((size_t)(b * NT + i0)) * DM + idx];
  __syncthreads();

  const float scale = 0.17677669529663687f;
  {
    // scores: thread t owns column j=t (<260); coalesced K^T reads
    if (t < NT) {
      const float* kT = kw + (size_t)b * (DM * NT) + t;
      #pragma unroll
      for (int h = 0; h < NH; ++h) {
        float a0 = 0.f, a1 = 0.f;
        float kv[8];
        #pragma unroll
        for (int d0 = 0; d0 < 32; d0 += 8) {
          #pragma unroll
          for (int q = 0; q < 8; ++q)
            kv[q] = kT[(size_t)(h * 32 + d0 + q) * NT];
          #pragma unroll
          for (int q = 0; q < 8; ++q) {
            a0 += sQ[0 * DM + h * 32 + d0 + q] * kv[q];
            a1 += sQ[1 * DM + h * 32 + d0 + q] * kv[q];
          }
        }
        sS[(0 * NH + h) * NT + t] = a0 * scale;
        sS[(1 * NH + h) * NT + t] = a1 * scale;
      }
    }
  }
  __syncthreads();
  {
    int combo = t >> 5, lane32 = t & 31;     // 16 combos x 32 lanes
    float* row = sS + (size_t)combo * NT;
    float m = -1e30f;
    for (int jx = lane32; jx < NT; jx += 32) m = fmaxf(m, row[jx]);
    #pragma unroll
    for (int s = 1; s < 32; s <<= 1) m = fmaxf(m, __shfl_xor(m, s, 32));
    float ssum = 0.f;
    for (int jx = lane32; jx < NT; jx += 32) {
      float e = __expf(row[jx] - m);
      row[jx] = e;
      ssum += e;
    }
    #pragma unroll
    for (int s = 1; s < 32; s <<= 1) ssum += __shfl_xor(ssum, s, 32);
    if (lane32 == 0) sL[combo] = ssum;
  }
  __syncthreads();
  {
    int ch = t & 255, jh = t >> 8, hh = ch >> 5;
    float o0 = 0.f, o1 = 0.f;
    const float* vbase = vw + ((size_t)(b * NT + jh * 130)) * DM + ch;
    const float* p0 = sS + (0 * NH + hh) * NT + jh * 130;
    const float* p1 = sS + (1 * NH + hh) * NT + jh * 130;
    #pragma unroll 1
    for (int j0 = 0; j0 < 130; j0 += 10) {
      float v[10];
      #pragma unroll
      for (int q = 0; q < 10; ++q) v[q] = vbase[(size_t)(j0 + q) * DM];
      #pragma unroll
      for (int q = 0; q < 10; ++q) {
        o0 += p0[j0 + q] * v[q]; o1 += p1[j0 + q] * v[q];
      }
    }
    if (jh) {
      sPV[0 * DM + ch] = o0; sPV[1 * DM + ch] = o1;
    }
    __syncthreads();
    if (!jh) {
      sQ[0 * DM + ch] = (o0 + sPV[0 * DM + ch]) / sL[0 * NH + hh];
      sQ[1 * DM + ch] = (o1 + sPV[1 * DM + ch]) / sL[1 * NH + hh];
    }
  }
  __syncthreads();
  {
    int col = t & 255, kh = t >> 8;
    float acc[2] = {0.f, 0.f};
    const float* wcol = WoT + (size_t)(kh * 128) * DM + col;
    const float* s0 = sQ + kh * 128;
    #pragma unroll 1
    for (int k0 = 0; k0 < 128; k0 += 8) {
      float w[8];
      #pragma unroll
      for (int q = 0; q < 8; ++q) w[q] = wcol[(size_t)(k0 + q) * DM];
      #pragma unroll
      for (int q = 0; q < 8; ++q) {
        acc[0] += s0[0 * DM + k0 + q] * w[q];
        acc[1] += s0[1 * DM + k0 + q] * w[q];
      }
    }
    if (kh) {
      sPV[0 * DM + col] = acc[0]; sPV[1 * DM + col] = acc[1];
    }
    __syncthreads();
    float ov[2] = {0.f, 0.f};
    float gg = g[col], bb2 = bb[col];
    if (!kh) {
      float bias = bo[col];
      #pragma unroll
      for (int r = 0; r < 2; ++r)
        ov[r] = acc[r] + sPV[r * DM + col] + bias
              + resin[((size_t)(b * NT + i0 + r)) * DM + col];
    }
    int wid = t >> 6, lane = t & 63;
    #pragma unroll 1
    for (int r = 0; r < 2; ++r) {
      float o = (!kh) ? ov[r] : 0.f;
      __syncthreads();
      float s1 = o, s2 = o * o;
      #pragma unroll
      for (int off = 32; off > 0; off >>= 1) {
        s1 += __shfl_down(s1, off, 64);
        s2 += __shfl_down(s2, off, 64);
      }
      if (lane == 0 && wid < 4) { sb[wid * 2] = s1; sb[wid * 2 + 1] = s2; }
      __syncthreads();
      float m = (sb[0] + sb[2] + sb[4] + sb[6]) * (1.f / 256.f);
      float q2 = (sb[1] + sb[3] + sb[5] + sb[7]) * (1.f / 256.f);
      float var = q2 - m * m;
      if (!kh)
        out[((size_t)(b * NT + i0 + r)) * DM + col] =
            (ov[r] - m) * rsqrtf(var + EPSV) * gg + bb2;
    }
  }
}

// ---- FFN1: gelu(x@W1.T+b1) via W1T, reg-tile, K-split 4, batch 4 ---------
// gpb: row-groups per batch (0 = dense 130 groups; 3 = pruned 24 rows/b)
__global__ void __launch_bounds__(256) k_ffn1(
    const float* __restrict__ W1T, const float* __restrict__ b1,
    const float* __restrict__ xn, float* __restrict__ y1, int gpb) {
  int bi = blockIdx.x;                       // rg*4 + fg
  int rg = bi >> 2, fg = bi & 3;
  int row0 = gpb ? ((rg / gpb) * NT + (rg % gpb) * 8) : rg * 8;
  __shared__ __align__(16) float sx[8 * DM];
  __shared__ __align__(16) float sp[3 * 8 * DM];
  int t = threadIdx.x;
  int colg = t & 63, kq = t >> 6;
  #pragma unroll
  for (int i = 0; i < 2; ++i)
    reinterpret_cast<float4*>(sx)[t + i * 256] =
        reinterpret_cast<const float4*>(xn + (size_t)row0 * DM)[t + i * 256];
  __syncthreads();
  int f = fg * 256 + colg * 4;
  float acc[8][4];
  #pragma unroll
  for (int r = 0; r < 8; ++r) { acc[r][0]=0.f; acc[r][1]=0.f; acc[r][2]=0.f; acc[r][3]=0.f; }
  const float* xb = sx + kq * 64;
  const float4* wp = reinterpret_cast<const float4*>(W1T + (size_t)(kq * 64) * DFF + f);
  #pragma unroll 1
  for (int k0 = 0; k0 < 64; k0 += 4) {
    float4 w[4];
    #pragma unroll
    for (int q = 0; q < 4; ++q) w[q] = wp[(size_t)(k0 + q) * 256];
    #pragma unroll
    for (int q = 0; q < 4; ++q)
      #pragma unroll
      for (int r = 0; r < 8; ++r) {
        float xv = xb[r * DM + k0 + q];
        acc[r][0] += xv * w[q].x; acc[r][1] += xv * w[q].y;
        acc[r][2] += xv * w[q].z; acc[r][3] += xv * w[q].w;
      }
  }
  if (kq) {
    #pragma unroll
    for (int r = 0; r < 8; ++r)
      reinterpret_cast<float4*>(sp)[((kq - 1) * 8 + r) * 64 + colg] =
          make_float4(acc[r][0], acc[r][1], acc[r][2], acc[r][3]);
  }
  __syncthreads();
  if (kq == 0) {
    float4 b4 = *reinterpret_cast<const float4*>(b1 + f);
    const float4* sp4 = reinterpret_cast<const float4*>(sp);
    #pragma unroll 1
    for (int r = 0; r < 8; ++r) {
      float4 p0 = sp4[(0 * 8 + r) * 64 + colg];
      float4 p1 = sp4[(1 * 8 + r) * 64 + colg];
      float4 p2 = sp4[(2 * 8 + r) * 64 + colg];
      float a0 = acc[r][0] + p0.x + p1.x + p2.x + b4.x;
      float a1 = acc[r][1] + p0.y + p1.y + p2.y + b4.y;
      float a2 = acc[r][2] + p0.z + p1.z + p2.z + b4.z;
      float a3 = acc[r][3] + p0.w + p1.w + p2.w + b4.w;
      float4 o;
      o.x = 0.5f * a0 * (1.f + erff(a0 * 0.70710678118654752f));
      o.y = 0.5f * a1 * (1.f + erff(a1 * 0.70710678118654752f));
      o.z = 0.5f * a2 * (1.f + erff(a2 * 0.70710678118654752f));
      o.w = 0.5f * a3 * (1.f + erff(a3 * 0.70710678118654752f));
      *reinterpret_cast<float4*>(y1 + (size_t)(row0 + r) * DFF + f) = o;
    }
  }
}

// ---- FFN2 fused: W2T, 4 rows/block, 512 thr, K-split 8, batch 8, +LN -----
// gpb: groups-of-4 per batch (0 = dense 260 blocks; 6 = pruned 24 rows/b)
__global__ void __launch_bounds__(512) k_ffn2f(
    const float* __restrict__ W2T, const float* __restrict__ b2,
    const float* __restrict__ g, const float* __restrict__ bb,
    const float* __restrict__ y1, const float* __restrict__ xn,
    float* __restrict__ out, int gpb) {
  int blk = blockIdx.x;
  int row0 = gpb ? ((blk / gpb) * NT + (blk % gpb) * 4) : blk * 4;
  __shared__ __align__(16) float sy[4 * DFF];    // 16 KB
  __shared__ __align__(16) float sp[7 * 4 * DM]; // 28 KB
  int t = threadIdx.x;
  int colg = t & 63, kq = t >> 6;                // kq 0..7
  #pragma unroll
  for (int i = 0; i < 2; ++i)
    reinterpret_cast<float4*>(sy)[t + i * 512] =
        reinterpret_cast<const float4*>(y1 + (size_t)row0 * DFF)[t + i * 512];
  __syncthreads();
  float acc[4][4];
  #pragma unroll
  for (int r = 0; r < 4; ++r) { acc[r][0]=0.f; acc[r][1]=0.f; acc[r][2]=0.f; acc[r][3]=0.f; }
  const float* yb = sy + kq * 128;
  const float4* wp = reinterpret_cast<const float4*>(W2T + (size_t)(kq * 128) * DM) + colg;
  #pragma unroll 1
  for (int k0 = 0; k0 < 128; k0 += 8) {
    float4 w[8];
    #pragma unroll
    for (int q = 0; q < 8; ++q) w[q] = wp[(size_t)(k0 + q) * 64];
    #pragma unroll
    for (int q = 0; q < 8; ++q)
      #pragma unroll
      for (int r = 0; r < 4; ++r) {
        float yv = yb[r * DFF + k0 + q];
        acc[r][0] += yv * w[q].x; acc[r][1] += yv * w[q].y;
        acc[r][2] += yv * w[q].z; acc[r][3] += yv * w[q].w;
      }
  }
  if (kq) {
    #pragma unroll
    for (int r = 0; r < 4; ++r)
      reinterpret_cast<float4*>(sp)[((kq - 1) * 4 + r) * 64 + colg] =
          make_float4(acc[r][0], acc[r][1], acc[r][2], acc[r][3]);
  }
  __syncthreads();
  if (kq == 0) {
    float4 b4 = reinterpret_cast<const float4*>(b2)[colg];
    float4 g4 = reinterpret_cast<const float4*>(g)[colg];
    float4 bb4 = reinterpret_cast<const float4*>(bb)[colg];
    const float4* sp4 = reinterpret_cast<const float4*>(sp);
    #pragma unroll 1
    for (int r = 0; r < 4; ++r) {
      float o0 = acc[r][0], o1 = acc[r][1], o2 = acc[r][2], o3 = acc[r][3];
      #pragma unroll
      for (int s = 0; s < 7; ++s) {
        float4 ps = sp4[(s * 4 + r) * 64 + colg];
        o0 += ps.x; o1 += ps.y; o2 += ps.z; o3 += ps.w;
      }
      float4 xr = reinterpret_cast<const float4*>(xn + (size_t)(row0 + r) * DM)[colg];
      o0 += b4.x + xr.x; o1 += b4.y + xr.y; o2 += b4.z + xr.z; o3 += b4.w + xr.w;
      float s1 = o0 + o1 + o2 + o3;
      float s2 = o0*o0 + o1*o1 + o2*o2 + o3*o3;
      #pragma unroll
      for (int m = 1; m < 64; m <<= 1) {
        s1 += __shfl_xor(s1, m, 64);
        s2 += __shfl_xor(s2, m, 64);
      }
      float mean = s1 * (1.f / 256.f);
      float var = s2 * (1.f / 256.f) - mean * mean;
      float rs = rsqrtf(var + EPSV);
      float4 o;
      o.x = (o0 - mean) * rs * g4.x + bb4.x;
      o.y = (o1 - mean) * rs * g4.y + bb4.y;
      o.z = (o2 - mean) * rs * g4.z + bb4.z;
      o.w = (o3 - mean) * rs * g4.w + bb4.w;
      reinterpret_cast<float4*>(out + (size_t)(row0 + r) * DM)[colg] = o;
    }
  }
}

// ---- final LN + projection (pWT [256][96], batched) + denorm -------------
__global__ void k_final(const float* __restrict__ g, const float* __restrict__ bb,
                        const float* __restrict__ pWT, const float* __restrict__ pb,
                        const float* __restrict__ enc2,
                        const float* __restrict__ stdev, const float* __restrict__ means,
                        float* __restrict__ out) {
  int bi = blockIdx.x;                       // b*21+c
  int b = bi / CIN, c = bi % CIN;
  __shared__ __align__(16) float sx[DM];
  __shared__ float sb[8];
  int t = threadIdx.x;
  float v = enc2[(size_t)(b * NT + c) * DM + t];
  float2 mv = meanvar256(v, sb);
  sx[t] = (v - mv.x) * rsqrtf(mv.y + EPSV) * g[t] + bb[t];
  __syncthreads();
  if (t < PRED) {
    float acc = 0.f;
    #pragma unroll 1
    for (int k0 = 0; k0 < DM; k0 += 8) {
      float w[8];
      #pragma unroll
      for (int q = 0; q < 8; ++q) w[q] = pWT[(size_t)(k0 + q) * PRED + t];
      #pragma unroll
      for (int q = 0; q < 8; ++q) acc += sx[k0 + q] * w[q];
    }
    float y = (acc + pb[t]) * stdev[bi] + means[bi];
    out[(size_t)b * PRED * CIN + t * CIN + c] = y;
  }
}

extern "C" void kernel_launch(void* const* d_in, const int* in_sizes, int n_in,
                              void* d_out, int out_size, void* d_ws, size_t ws_size,
                              hipStream_t stream) {
  const float* x_enc   = (const float*)d_in[0];
  const float* x_mark  = (const float*)d_in[1];
  const float* tok_W   = (const float*)d_in[4];
  const float* patch_W = (const float*)d_in[5];
  const float* patch_b = (const float*)d_in[6];
  const float* nl_WQ   = (const float*)d_in[7];
  const float* nl_WK   = (const float*)d_in[8];
  const float* nl_WV   = (const float*)d_in[9];
  const float* nl_WO   = (const float*)d_in[10];
  const float* nl_bO   = (const float*)d_in[11];
  const float* nl_mu_a = (const float*)d_in[12];
  const float* nl_sg_a = (const float*)d_in[13];
  const float* nl_w_a  = (const float*)d_in[14];
  const float* nl_mu_r = (const float*)d_in[15];
  const float* nl_sg_r = (const float*)d_in[16];
  const float* nl_w_r  = (const float*)d_in[17];
  const float* nl_al   = (const float*)d_in[18];
  const float* nl_be   = (const float*)d_in[19];
  const float* nl_ga   = (const float*)d_in[20];
  const float* inv_W   = (const float*)d_in[21];
  const float* inv_b   = (const float*)d_in[22];
  const float* el_Wq   = (const float*)d_in[23];
  const float* el_bq   = (const float*)d_in[24];
  const float* el_Wk   = (const float*)d_in[25];
  const float* el_bk   = (const float*)d_in[26];
  const float* el_Wv   = (const float*)d_in[27];
  const float* el_bv   = (const float*)d_in[28];
  const float* el_Wo   = (const float*)d_in[29];
  const float* el_bo   = (const float*)d_in[30];
  const float* el_W1   = (const float*)d_in[31];
  const float* el_b1   = (const float*)d_in[32];
  const float* el_W2   = (const float*)d_in[33];
  const float* el_b2   = (const float*)d_in[34];
  const float* n1g     = (const float*)d_in[35];
  const float* n1b     = (const float*)d_in[36];
  const float* n2g     = (const float*)d_in[37];
  const float* n2b     = (const float*)d_in[38];
  const float* norm_g  = (const float*)d_in[39];
  const float* norm_b  = (const float*)d_in[40];
  const float* proj_W  = (const float*)d_in[41];
  const float* proj_b  = (const float*)d_in[42];

  // workspace layout (floats)
  float* ws = (float*)d_ws;
  float* means = ws + 0;          //     96
  float* stdev = ws + 96;         //     96
  float* tws   = ws + 192;        //   1024
  float* enc1  = ws + 1216;       // 524288  (B,512,256)
  float* encP  = ws + 525504;     //  64512  (252,256)
  float* pbuf  = ws + 590016;     // 516096  (8,252,256)
  float* enc2  = ws + 1106112;    // 266240  (1040,256)
  float* qb    = ws + 1638592;    // 266240  (xn aliases qb)
  float* kb    = ws + 1904832;    // 266240  (K or K^T)
  float* vb    = ws + 2171072;    // 266240
  float* y1    = ws + 2437312;    // 1064960 (1040,1024)
  float* encPb = ws + 3502272;    //  64512  (TKA ping-pong)
  float* grel  = ws + 4567232;    // 254016  (2,B,8,63,63)
  float* gib   = ws + 4821248;    //   4032  (2,B,8,63)
  float* wsT   = ws + 4825344;    // 3202560 (transposed weights)
  float* xn    = qb;              // alias: qb rows only self-read before overwrite

  // prep: weight transpose (3128) + stats/tws (88) + grel/gib (2016)
  k_prep<<<5232, 256, 0, stream>>>(nl_WQ, nl_WK, nl_WV, nl_WO,
                                   el_Wq, el_Wk, el_Wv, el_Wo,
                                   el_W1, el_W2, inv_W, proj_W,
                                   tok_W, patch_W, wsT,
                                   x_enc, x_mark, means, stdev, tws,
                                   nl_mu_r, nl_sg_r, nl_w_r,
                                   nl_mu_a, nl_sg_a, nl_w_a, grel, gib);
  k_tokconv<<<NB * 64, 256, 0, stream>>>(x_enc, wsT + T_tok, means, stdev, enc1);
  k_patch_part<<<42 * 8, 256, 0, stream>>>(enc1, wsT + T_pat, pbuf);

  // ---- TKA layer 0: fused patch-reduce + QKV, then attention -------------
  k_qkv_tka0<<<63 * 3, 256, 0, stream>>>(wsT + T_nlWQ, wsT + T_nlWK, wsT + T_nlWV,
                                         pbuf, patch_b, qb, kb, vb, encP);
  k_tka_attn_f<<<NB * EL, 512, 0, stream>>>(encP, qb, kb, vb,
      grel, gib, nl_al, nl_be, nl_ga,
      wsT + T_nlWO, nl_bO, encPb);
  // ---- TKA layer 1 -------------------------------------------------------
  {
    size_t wo = (size_t)DM * DM;
    k_qkv2<4><<<63 * 3, 256, 0, stream>>>(wsT + T_nlWQ + wo, wsT + T_nlWK + wo,
                                          wsT + T_nlWV + wo,
                                          nullptr, nullptr, nullptr,
                                          encPb, qb, kb, vb, 0);
    k_tka_attn_f<<<NB * EL, 512, 0, stream>>>(encPb, qb, kb, vb,
        grel + (size_t)(NB * NH * EL * EL), gib + (size_t)(NB * NH * EL),
        nl_al + 8, nl_be + 8, nl_ga + 8,
        wsT + T_nlWO + wo, nl_bO + DM, encP);
  }

  // ---- encoder layer 0: fused inv-embedding + QKV (K^T) ------------------
  k_qkv_enc0<<<130 * 3, 256, 0, stream>>>(wsT + T_elWq, wsT + T_elWk, wsT + T_elWv,
                                          el_bq, el_bk, el_bv,
                                          wsT + T_inv, inv_b, encP, tws,
                                          qb, kb, vb, enc2);
  k_enc_attn_f<<<NB * 130, 512, 0, stream>>>(qb, kb, vb, wsT + T_elWo, el_bo,
                                             n1g, n1b, enc2, xn, 130);
  k_ffn1<<<130 * 4, 256, 0, stream>>>(wsT + T_elW1, el_b1, xn, y1, 0);
  k_ffn2f<<<260, 512, 0, stream>>>(wsT + T_elW2, el_b2, n2g, n2b, y1, xn, enc2, 0);

  // ---- encoder layer 1: pruned — only rows [b*NT, b*NT+24) reach k_final --
  {
    size_t wo = (size_t)DM * DM;
    size_t bo = (size_t)DM;
    size_t fo = (size_t)DFF * DM;
    k_qkv_l1<<<272, 256, 0, stream>>>(wsT + T_elWq + wo, wsT + T_elWk + wo,
                                      wsT + T_elWv + wo,
                                      el_bq + bo, el_bk + bo, el_bv + bo,
                                      enc2, qb, kb, vb);
    k_enc_attn_f<<<NB * 12, 512, 0, stream>>>(qb, kb, vb, wsT + T_elWo + wo,
                                              el_bo + bo, n1g + bo, n1b + bo,
                                              enc2, xn, 12);
    k_ffn1<<<12 * 4, 256, 0, stream>>>(wsT + T_elW1 + fo, el_b1 + DFF, xn, y1, 3);
    k_ffn2f<<<NB * 6, 512, 0, stream>>>(wsT + T_elW2 + fo, el_b2 + bo,
                                        n2g + bo, n2b + bo, y1, xn, enc2, 6);
  }

  k_final<<<NB * CIN, 256, 0, stream>>>(norm_g, norm_b, wsT + T_proj, proj_b,
                                        enc2, stdev, means, (float*)d_out);
}

// Round 15
// 407.688 us; speedup vs baseline: 1.0525x; 1.0004x over previous
//
#include <hip/hip_runtime.h>
#include <hip/hip_bf16.h>

#define NB 4
#define SEQ 512
#define CIN 21
#define TDIM 4
#define DM 256
#define NH 8
#define PLEN 16
#define PSTR 8
#define EL 63
#define DFF 1024
#define PRED 96
#define NT 260
#define EPSV 1e-5f

// transposed-weight workspace offsets (floats)
#define T_nlWQ 0
#define T_nlWK 131072
#define T_nlWV 262144
#define T_nlWO 393216
#define T_elWq 524288
#define T_elWk 655360
#define T_elWv 786432
#define T_elWo 917504
#define T_elW1 1048576
#define T_elW2 1572864
#define T_inv  2097152
#define T_proj 2113280
#define T_tok  2137856
#define T_pat  2153984

// ---------------- helpers --------------------------------------------------
__device__ __forceinline__ unsigned short f2bf(float f) {
  unsigned int u = __float_as_uint(f);
  unsigned int r = u + 0x7FFFu + ((u >> 16) & 1u);
  return (unsigned short)(r >> 16);
}
__device__ __forceinline__ float bf2f(unsigned short h) {
  return __uint_as_float(((unsigned int)h) << 16);
}

__device__ __forceinline__ float2 meanvar256(float v, float* sb) {
  __syncthreads();
  float s1 = v, s2 = v * v;
  #pragma unroll
  for (int off = 32; off > 0; off >>= 1) {
    s1 += __shfl_down(s1, off, 64);
    s2 += __shfl_down(s2, off, 64);
  }
  int wid = threadIdx.x >> 6, lane = threadIdx.x & 63;
  if (lane == 0) { sb[wid * 2] = s1; sb[wid * 2 + 1] = s2; }
  __syncthreads();
  float m = (sb[0] + sb[2] + sb[4] + sb[6]) * (1.0f / 256.0f);
  float q = (sb[1] + sb[3] + sb[5] + sb[7]) * (1.0f / 256.0f);
  return make_float2(m, q - m * m);
}

__device__ __forceinline__ void load16f(const float* p, float* o) {
  const float4* q = reinterpret_cast<const float4*>(p);
  float4 a = q[0], b = q[1], c = q[2], d = q[3];
  o[0]=a.x; o[1]=a.y; o[2]=a.z; o[3]=a.w;
  o[4]=b.x; o[5]=b.y; o[6]=b.z; o[7]=b.w;
  o[8]=c.x; o[9]=c.y; o[10]=c.z; o[11]=c.w;
  o[12]=d.x; o[13]=d.y; o[14]=d.z; o[15]=d.w;
}

__device__ __forceinline__ float dot32(const float4* a, const float4* b) {
  float s = 0.f;
  #pragma unroll
  for (int i = 0; i < 8; ++i) {
    float4 x = a[i], y = b[i];
    s += x.x*y.x + x.y*y.y + x.z*y.z + x.w*y.w;
  }
  return s;
}

// ---- K0: weight transpose (3128) + RevIN stats/tws (88) + g_rel (2016) ---
// W1/W2 are written transposed AND converted to bf16 (RNE).
__global__ void __launch_bounds__(256) k_prep(
    const float* __restrict__ nlWQ, const float* __restrict__ nlWK,
    const float* __restrict__ nlWV, const float* __restrict__ nlWO,
    const float* __restrict__ eWq, const float* __restrict__ eWk,
    const float* __restrict__ eWv, const float* __restrict__ eWo,
    const float* __restrict__ eW1, const float* __restrict__ eW2,
    const float* __restrict__ invW, const float* __restrict__ projW,
    const float* __restrict__ tokW, const float* __restrict__ patW,
    float* __restrict__ wt,
    const float* __restrict__ x, const float* __restrict__ xm,
    float* __restrict__ means, float* __restrict__ stdev,
    float* __restrict__ tout,
    const float* __restrict__ mu_r, const float* __restrict__ sg_r,
    const float* __restrict__ w_r,
    const float* __restrict__ mu_a, const float* __restrict__ sg_a,
    const float* __restrict__ w_a,
    float* __restrict__ grel, float* __restrict__ gib) {
  __shared__ float smem[32 * 33];
  int blk = blockIdx.x;
  int t = threadIdx.x;

  if (blk < 3128) {
    // ----- weight transpose (32x32 LDS tiles) -----
    const float* src; float* dst = nullptr; unsigned short* dstb = nullptr;
    int R, C, tr, tc;
    if (blk < 1024) {                 // 16 square [256][256] mats
      int m = blk >> 6, tile = blk & 63;
      tr = tile >> 3; tc = tile & 7; R = 256; C = 256;
      int p = m >> 1, l = m & 1;
      const float* bases[8] = {nlWQ, nlWK, nlWV, nlWO, eWq, eWk, eWv, eWo};
      const int offs[8] = {T_nlWQ, T_nlWK, T_nlWV, T_nlWO, T_elWq, T_elWk, T_elWv, T_elWo};
      src = bases[p] + l * 65536;
      dst = wt + offs[p] + l * 65536;
    } else if (blk < 1536) {          // W1 [1024][256] x2 -> bf16 W1T
      int q = blk - 1024; int l = q >> 8, s = q & 255;
      tr = s >> 3; tc = s & 7; R = 1024; C = 256;
      src = eW1 + l * 262144;
      dstb = (unsigned short*)(wt + T_elW1) + (size_t)l * 262144;
    } else if (blk < 2048) {          // W2 [256][1024] x2 -> bf16 W2T
      int q = blk - 1536; int l = q >> 8, s = q & 255;
      tr = s >> 5; tc = s & 31; R = 256; C = 1024;
      src = eW2 + l * 262144;
      dstb = (unsigned short*)(wt + T_elW2) + (size_t)l * 262144;
    } else if (blk < 3072) {          // patch_W [256][4096]
      int q = blk - 2048; tr = q >> 7; tc = q & 127; R = 256; C = 4096;
      src = patW; dst = wt + T_pat;
    } else if (blk < 3088) {          // inv_W [256][63]
      int q = blk - 3072; tr = q >> 1; tc = q & 1; R = 256; C = 63;
      src = invW; dst = wt + T_inv;
    } else if (blk < 3112) {          // proj_W [96][256]
      int q = blk - 3088; tr = q >> 3; tc = q & 7; R = 96; C = 256;
      src = projW; dst = wt + T_proj;
    } else {                          // tok_W [256][63]
      int q = blk - 3112; tr = q >> 1; tc = q & 1; R = 256; C = 63;
      src = tokW; dst = wt + T_tok;
    }
    float (*ts)[33] = (float(*)[33])smem;
    int tx = t & 31, ty = t >> 5;
    #pragma unroll
    for (int i = 0; i < 4; ++i) {
      int r = tr * 32 + ty + i * 8, c = tc * 32 + tx;
      ts[ty + i * 8][tx] = (c < C) ? src[(size_t)r * C + c] : 0.f;
    }
    __syncthreads();
    #pragma unroll
    for (int i = 0; i < 4; ++i) {
      int c = tc * 32 + ty + i * 8, r = tr * 32 + tx;
      if (c < C) {
        float v = ts[tx][ty + i * 8];
        if (dstb) dstb[(size_t)c * R + r] = f2bf(v);
        else      dst[(size_t)c * R + r] = v;
      }
    }
  } else if (blk < 3216) {
    // ----- RevIN stats (84) + patch-time means (4) -----
    int sblk = blk - 3128;
    if (sblk < NB * CIN) {
      int b = sblk / CIN, c = sblk % CIN;
      const float* p = x + (size_t)b * SEQ * CIN + c;
      float v0 = p[t * CIN];
      float v1 = p[(t + 256) * CIN];
      float s1 = v0 + v1, s2 = v0 * v0 + v1 * v1;
      float* sb = smem;
      #pragma unroll
      for (int off = 32; off > 0; off >>= 1) {
        s1 += __shfl_down(s1, off, 64);
        s2 += __shfl_down(s2, off, 64);
      }
      int wid = t >> 6, lane = t & 63;
      if (lane == 0) { sb[wid * 2] = s1; sb[wid * 2 + 1] = s2; }
      __syncthreads();
      if (t == 0) {
        float a = sb[0] + sb[2] + sb[4] + sb[6];
        float q = sb[1] + sb[3] + sb[5] + sb[7];
        float m = a * (1.0f / 512.0f);
        float var = q * (1.0f / 512.0f) - m * m;
        means[sblk] = m;
        stdev[sblk] = sqrtf(var + EPSV);
      }
    } else {
      int idx = (sblk - NB * CIN) * 256 + t;
      if (idx >= NB * EL * TDIM) return;
      int b = idx / (EL * TDIM), r = idx % (EL * TDIM);
      int l = r >> 2, ti = r & 3;
      const float* p = xm + (size_t)b * SEQ * TDIM + (size_t)l * PSTR * TDIM + ti;
      float s = 0.f;
      #pragma unroll
      for (int k = 0; k < PLEN; ++k) s += p[k * TDIM];
      tout[idx] = s * (1.f / 16.f);
    }
  } else {
    // ----- g_rel + g_abs, both layers; s_t computed inline from xm -----
    int gblk = blk - 3216;                   // L*(NB*252) + b*252 + chunk
    int L = gblk / (NB * 252);
    int rem0 = gblk % (NB * 252);
    int b = rem0 / 252, chunk = rem0 % 252;
    int po = L * 4096;
    float* grelL = grel + (size_t)L * (NB * NH * EL * EL);
    float* gibL  = gib + (size_t)L * (NB * NH * EL);
    int h = t >> 5, dh = t & 31;
    float* s_t = smem;
    if (t < EL * TDIM) {
      int l = t >> 2, ti = t & 3;
      const float* p = xm + (size_t)b * SEQ * TDIM + (size_t)l * PSTR * TDIM + ti;
      float s = 0.f;
      #pragma unroll
      for (int k = 0; k < PLEN; ++k) s += p[k * TDIM];
      s_t[t] = s * (1.f / 16.f);
    }
    float pm[16], pc[16], pw[16];
    load16f(mu_r + po + (size_t)t * 16, pm);
    load16f(sg_r + po + (size_t)t * 16, pc);
    load16f(w_r  + po + (size_t)t * 16, pw);
    #pragma unroll
    for (int p = 0; p < 16; ++p) pc[p] = -0.5f / (pc[p] * pc[p]);
    __syncthreads();
    #pragma unroll 1
    for (int q = 0; q < 8; ++q) {
      int p = chunk * 8 + q;                 // 2016 (i<=j) pairs
      int i = (int)((127.0f - sqrtf(16129.0f - 8.0f * (float)p)) * 0.5f);
      while (i * (127 - i) / 2 > p) --i;
      while ((i + 1) * (126 - i) / 2 <= p) ++i;
      int j = i + (p - i * (127 - i) / 2);
      float dvv[4];
      dvv[0] = fabsf(s_t[i*4+0] - s_t[j*4+0]);
      dvv[1] = fabsf(s_t[i*4+1] - s_t[j*4+1]);
      dvv[2] = fabsf(s_t[i*4+2] - s_t[j*4+2]);
      dvv[3] = fabsf(s_t[i*4+3] - s_t[j*4+3]);
      float srel = 0.f;
      #pragma unroll
      for (int tt = 0; tt < 4; ++tt)
        #pragma unroll
        for (int k = 0; k < 4; ++k) {
          int pp = tt * 4 + k;
          float df = dvv[tt] - pm[pp];
          srel += pw[pp] * __expf(pc[pp] * df * df);
        }
      #pragma unroll
      for (int m = 1; m < 32; m <<= 1) srel += __shfl_xor(srel, m, 64);
      if (dh == 0) {
        float v = srel * (1.f / 32.f);
        grelL[(((size_t)b * NH + h) * EL + i) * EL + j] = v;
        grelL[(((size_t)b * NH + h) * EL + j) * EL + i] = v;
      }
    }
    if (chunk < EL) {
      load16f(mu_a + po + (size_t)t * 16, pm);
      load16f(sg_a + po + (size_t)t * 16, pc);
      load16f(w_a  + po + (size_t)t * 16, pw);
      #pragma unroll
      for (int p = 0; p < 16; ++p) pc[p] = -0.5f / (pc[p] * pc[p]);
      int i = chunk;
      float tiv[4] = {s_t[i*4+0], s_t[i*4+1], s_t[i*4+2], s_t[i*4+3]};
      float sabs = 0.f;
      #pragma unroll
      for (int tt = 0; tt < 4; ++tt)
        #pragma unroll
        for (int k = 0; k < 4; ++k) {
          int pp = tt * 4 + k;
          float df = tiv[tt] - pm[pp];
          sabs += pw[pp] * __expf(pc[pp] * df * df);
        }
      #pragma unroll
      for (int m = 1; m < 32; m <<= 1) sabs += __shfl_xor(sabs, m, 64);
      if (dh == 0) gibL[((size_t)b * NH + h) * EL + i] = sabs * (1.f / 32.f);
    }
  }
}

// ---- K3a: token conv + PE (tokWT [63][256] coalesced) --------------------
__global__ void __launch_bounds__(256) k_tokconv(
    const float* __restrict__ x, const float* __restrict__ tokWT,
    const float* __restrict__ means, const float* __restrict__ stdev,
    float* __restrict__ enc1) {
  int bi = blockIdx.x;                       // b*64 + sg
  int b = bi >> 6, sg = bi & 63;
  int s0 = sg * 8;
  __shared__ float sxr[10 * CIN];
  int t = threadIdx.x;
  if (t < 10 * CIN) {
    int li = t / CIN, c = t % CIN;
    int row = (s0 - 1 + li + SEQ) & 511;
    sxr[t] = (x[(size_t)b * SEQ * CIN + row * CIN + c] - means[b * CIN + c])
             / stdev[b * CIN + c];
  }
  __syncthreads();
  int d = t;
  float wreg[63];
  #pragma unroll
  for (int q = 0; q < 63; ++q) wreg[q] = tokWT[q * DM + d];
  int de = d & ~1;
  float dv = expf((float)de * (-9.210340371976184f / 256.0f));
  bool isodd = (d & 1);
  #pragma unroll 1
  for (int k = 0; k < 8; ++k) {
    float acc = 0.f;
    const float* sr = sxr + k * CIN;
    #pragma unroll
    for (int c = 0; c < CIN; ++c) {
      acc += sr[c]           * wreg[c * 3 + 0];
      acc += sr[CIN + c]     * wreg[c * 3 + 1];
      acc += sr[2 * CIN + c] * wreg[c * 3 + 2];
    }
    float ang = (float)(s0 + k) * dv;
    float pe = isodd ? cosf(ang) : sinf(ang);
    enc1[((size_t)b * SEQ + s0 + k) * DM + d] = acc + pe;
  }
}

// ---- K3b: patch conv partials (patWT [4096][256], batched loads) ---------
__global__ void __launch_bounds__(256) k_patch_part(
    const float* __restrict__ enc1, const float* __restrict__ pWT,
    float* __restrict__ pbuf) {
  int bi = blockIdx.x;
  int pg = bi >> 3, kc = bi & 7;
  int p0 = pg * 6;
  __shared__ __align__(16) float sA[6 * 32 * 20];
  int t = threadIdx.x;
  for (int idx = t; idx < 6 * 32 * PLEN; idx += 256) {
    int pp = idx >> 9;
    int rem = idx & 511;
    int c = rem >> 4, k = rem & 15;
    int p = p0 + pp;
    int b = p / EL, l = p % EL;
    sA[pp * 640 + c * 20 + k] =
        enc1[((size_t)b * SEQ + l * PSTR + k) * DM + kc * 32 + c];
  }
  __syncthreads();
  int d = t;
  const float* wb = pWT + (size_t)(kc * 32 * PLEN) * DM + d;
  float acc[6] = {0.f, 0.f, 0.f, 0.f, 0.f, 0.f};
  #pragma unroll 1
  for (int kk0 = 0; kk0 < 512; kk0 += 8) {
    float w[8];
    #pragma unroll
    for (int q = 0; q < 8; ++q) w[q] = wb[(size_t)(kk0 + q) * DM];
    #pragma unroll
    for (int q = 0; q < 8; ++q) {
      int kk = kk0 + q;
      const float* sa = sA + (kk >> 4) * 20 + (kk & 15);
      acc[0] += sa[0 * 640] * w[q];
      acc[1] += sa[1 * 640] * w[q];
      acc[2] += sa[2 * 640] * w[q];
      acc[3] += sa[3 * 640] * w[q];
      acc[4] += sa[4 * 640] * w[q];
      acc[5] += sa[5 * 640] * w[q];
    }
  }
  const int S = NB * EL * DM;
  #pragma unroll
  for (int pp = 0; pp < 6; ++pp)
    pbuf[(size_t)kc * S + (size_t)(p0 + pp) * DM + d] = acc[pp];
}

// ---- TKA L0 QKV: fused pbuf-reduce (patch_red) + QKV GEMM ----------------
__global__ void __launch_bounds__(256) k_qkv_tka0(
    const float* __restrict__ WqT, const float* __restrict__ WkT,
    const float* __restrict__ WvT,
    const float* __restrict__ pbuf, const float* __restrict__ pb,
    float* __restrict__ qo, float* __restrict__ ko, float* __restrict__ vo,
    float* __restrict__ encPo) {
  int bi = blockIdx.x;
  int rg = bi / 3, mat = bi % 3;
  int row0 = rg * 4;
  __shared__ __align__(16) float sx[4 * DM];
  __shared__ __align__(16) float sp[3 * 4 * DM];
  int t = threadIdx.x;
  int colg = t & 63, kq = t >> 6;
  const int S = NB * EL * DM;
  #pragma unroll
  for (int i = 0; i < 4; ++i) {
    int idx = t + i * 256;
    const float* pp = pbuf + (size_t)row0 * DM + idx;
    float pv[8];
    #pragma unroll
    for (int s = 0; s < 8; ++s) pv[s] = pp[(size_t)s * S];
    float v = pb[idx & 255];
    #pragma unroll
    for (int s = 0; s < 8; ++s) v += pv[s];
    sx[idx] = v;
    if (mat == 0) encPo[(size_t)row0 * DM + idx] = v;
  }
  __syncthreads();
  const float* WT = (mat == 0) ? WqT : (mat == 1) ? WkT : WvT;
  float* out = (mat == 0) ? qo : (mat == 1) ? ko : vo;
  float acc[4][4];
  #pragma unroll
  for (int r = 0; r < 4; ++r) { acc[r][0]=0.f; acc[r][1]=0.f; acc[r][2]=0.f; acc[r][3]=0.f; }
  const float* xb = sx + kq * 64;
  const float4* wp = reinterpret_cast<const float4*>(WT + (size_t)(kq * 64) * DM) + colg;
  #pragma unroll 1
  for (int k0 = 0; k0 < 64; k0 += 4) {
    float4 w[4];
    #pragma unroll
    for (int q = 0; q < 4; ++q) w[q] = wp[(size_t)(k0 + q) * 64];
    #pragma unroll
    for (int q = 0; q < 4; ++q)
      #pragma unroll
      for (int r = 0; r < 4; ++r) {
        float xv = xb[r * DM + k0 + q];
        acc[r][0] += xv * w[q].x; acc[r][1] += xv * w[q].y;
        acc[r][2] += xv * w[q].z; acc[r][3] += xv * w[q].w;
      }
  }
  if (kq) {
    #pragma unroll
    for (int r = 0; r < 4; ++r)
      reinterpret_cast<float4*>(sp)[((kq - 1) * 4 + r) * 64 + colg] =
          make_float4(acc[r][0], acc[r][1], acc[r][2], acc[r][3]);
  }
  __syncthreads();
  if (kq == 0) {
    const float4* sp4 = reinterpret_cast<const float4*>(sp);
    #pragma unroll
    for (int r = 0; r < 4; ++r) {
      float4 p0 = sp4[(0 * 4 + r) * 64 + colg];
      float4 p1 = sp4[(1 * 4 + r) * 64 + colg];
      float4 p2 = sp4[(2 * 4 + r) * 64 + colg];
      float4 o;
      o.x = acc[r][0] + p0.x + p1.x + p2.x;
      o.y = acc[r][1] + p0.y + p1.y + p2.y;
      o.z = acc[r][2] + p0.z + p1.z + p2.z;
      o.w = acc[r][3] + p0.w + p1.w + p2.w;
      reinterpret_cast<float4*>(out + (size_t)(row0 + r) * DM)[colg] = o;
    }
  }
}

// ---- QKV (TKA layer 1): WT [256][256], reg-tile, K-split 4 ---------------
template<int R>
__global__ void __launch_bounds__(256) k_qkv2(
    const float* __restrict__ WqT, const float* __restrict__ WkT,
    const float* __restrict__ WvT,
    const float* __restrict__ bq, const float* __restrict__ bk,
    const float* __restrict__ bv,
    const float* __restrict__ xin,
    float* __restrict__ qo, float* __restrict__ ko, float* __restrict__ vo,
    int ktm) {
  int bi = blockIdx.x;
  int rg = bi / 3, mat = bi % 3;
  int row0 = rg * R;
  __shared__ __align__(16) float sx[R * DM];
  __shared__ __align__(16) float sp[3 * R * DM];
  int t = threadIdx.x;
  int colg = t & 63, kq = t >> 6;
  #pragma unroll
  for (int i = 0; i < R / 4; ++i)
    reinterpret_cast<float4*>(sx)[t + i * 256] =
        reinterpret_cast<const float4*>(xin + (size_t)row0 * DM)[t + i * 256];
  __syncthreads();
  const float* WT = (mat == 0) ? WqT : (mat == 1) ? WkT : WvT;
  const float* bias = (mat == 0) ? bq : (mat == 1) ? bk : bv;
  float* out = (mat == 0) ? qo : (mat == 1) ? ko : vo;
  float acc[R][4];
  #pragma unroll
  for (int r = 0; r < R; ++r) { acc[r][0]=0.f; acc[r][1]=0.f; acc[r][2]=0.f; acc[r][3]=0.f; }
  const float* xb = sx + kq * 64;
  const float4* wp = reinterpret_cast<const float4*>(WT + (size_t)(kq * 64) * DM) + colg;
  #pragma unroll 1
  for (int k0 = 0; k0 < 64; k0 += 4) {
    float4 w[4];
    #pragma unroll
    for (int q = 0; q < 4; ++q) w[q] = wp[(size_t)(k0 + q) * 64];
    #pragma unroll
    for (int q = 0; q < 4; ++q)
      #pragma unroll
      for (int r = 0; r < R; ++r) {
        float xv = xb[r * DM + k0 + q];
        acc[r][0] += xv * w[q].x; acc[r][1] += xv * w[q].y;
        acc[r][2] += xv * w[q].z; acc[r][3] += xv * w[q].w;
      }
  }
  if (kq) {
    #pragma unroll
    for (int r = 0; r < R; ++r)
      reinterpret_cast<float4*>(sp)[((kq - 1) * R + r) * 64 + colg] =
          make_float4(acc[r][0], acc[r][1], acc[r][2], acc[r][3]);
  }
  __syncthreads();
  if (kq == 0) {
    float4 b4 = bias ? reinterpret_cast<const float4*>(bias)[colg]
                     : make_float4(0.f, 0.f, 0.f, 0.f);
    const float4* sp4 = reinterpret_cast<const float4*>(sp);
    #pragma unroll
    for (int r = 0; r < R; ++r) {
      float4 p0 = sp4[(0 * R + r) * 64 + colg];
      float4 p1 = sp4[(1 * R + r) * 64 + colg];
      float4 p2 = sp4[(2 * R + r) * 64 + colg];
      float4 o;
      o.x = acc[r][0] + p0.x + p1.x + p2.x + b4.x;
      o.y = acc[r][1] + p0.y + p1.y + p2.y + b4.y;
      o.z = acc[r][2] + p0.z + p1.z + p2.z + b4.z;
      o.w = acc[r][3] + p0.w + p1.w + p2.w + b4.w;
      if (ktm && mat == 1) {
        int gr = row0 + r, bb2 = gr / NT, jj2 = gr % NT;
        float* kd = out + (size_t)bb2 * (DM * NT) + jj2;
        kd[(size_t)(colg * 4 + 0) * NT] = o.x;
        kd[(size_t)(colg * 4 + 1) * NT] = o.y;
        kd[(size_t)(colg * 4 + 2) * NT] = o.z;
        kd[(size_t)(colg * 4 + 3) * NT] = o.w;
      } else {
        reinterpret_cast<float4*>(out + (size_t)(row0 + r) * DM)[colg] = o;
      }
    }
  }
}

// ---- encoder-L0 QKV: fused inverted-embedding + QKV (K written ^T) -------
__global__ void __launch_bounds__(256) k_qkv_enc0(
    const float* __restrict__ WqT, const float* __restrict__ WkT,
    const float* __restrict__ WvT,
    const float* __restrict__ bq, const float* __restrict__ bk,
    const float* __restrict__ bv,
    const float* __restrict__ invWT, const float* __restrict__ invb,
    const float* __restrict__ encP, const float* __restrict__ tws,
    float* __restrict__ qo, float* __restrict__ ko, float* __restrict__ vo,
    float* __restrict__ enc2) {
  int bi = blockIdx.x;
  int rg = bi / 3, mat = bi % 3;
  int row0 = rg * 8;
  __shared__ __align__(16) float sx[8 * DM];
  __shared__ float sxe[EL * 8 + 8];            // [l][r]
  __shared__ __align__(16) float sp[3 * 8 * DM];
  int t = threadIdx.x;
  int colg = t & 63, kq = t >> 6;
  // gather encP columns / tws for the block's 8 output rows
  #pragma unroll
  for (int it = 0; it < 2; ++it) {
    int idx = t + it * 256;
    if (idx < EL * 8) {
      int l = idx >> 3, r = idx & 7;
      int gr = row0 + r, bb2 = gr / NT, n = gr % NT;
      float v;
      if (n < DM) v = encP[(size_t)(bb2 * EL + l) * DM + n];
      else        v = tws[bb2 * EL * TDIM + l * TDIM + (n - DM)];
      sxe[l * 8 + r] = v;
    }
  }
  __syncthreads();
  // inverted embedding: thread t = output col, 8 rows
  {
    float bv2 = invb[t];
    float acc2[8];
    #pragma unroll
    for (int r = 0; r < 8; ++r) acc2[r] = bv2;
    #pragma unroll 1
    for (int l0 = 0; l0 < EL; l0 += 9) {
      float w[9];
      #pragma unroll
      for (int q = 0; q < 9; ++q) w[q] = invWT[(size_t)(l0 + q) * DM + t];
      #pragma unroll
      for (int q = 0; q < 9; ++q)
        #pragma unroll
        for (int r = 0; r < 8; ++r)
          acc2[r] += sxe[(l0 + q) * 8 + r] * w[q];
    }
    #pragma unroll
    for (int r = 0; r < 8; ++r) {
      sx[r * DM + t] = acc2[r];
      if (mat == 0) enc2[(size_t)(row0 + r) * DM + t] = acc2[r];
    }
  }
  __syncthreads();
  // QKV GEMM (K transposed out)
  const float* WT = (mat == 0) ? WqT : (mat == 1) ? WkT : WvT;
  const float* bias = (mat == 0) ? bq : (mat == 1) ? bk : bv;
  float* out = (mat == 0) ? qo : (mat == 1) ? ko : vo;
  float acc[8][4];
  #pragma unroll
  for (int r = 0; r < 8; ++r) { acc[r][0]=0.f; acc[r][1]=0.f; acc[r][2]=0.f; acc[r][3]=0.f; }
  const float* xb = sx + kq * 64;
  const float4* wp = reinterpret_cast<const float4*>(WT + (size_t)(kq * 64) * DM) + colg;
  #pragma unroll 1
  for (int k0 = 0; k0 < 64; k0 += 4) {
    float4 w[4];
    #pragma unroll
    for (int q = 0; q < 4; ++q) w[q] = wp[(size_t)(k0 + q) * 64];
    #pragma unroll
    for (int q = 0; q < 4; ++q)
      #pragma unroll
      for (int r = 0; r < 8; ++r) {
        float xv = xb[r * DM + k0 + q];
        acc[r][0] += xv * w[q].x; acc[r][1] += xv * w[q].y;
        acc[r][2] += xv * w[q].z; acc[r][3] += xv * w[q].w;
      }
  }
  if (kq) {
    #pragma unroll
    for (int r = 0; r < 8; ++r)
      reinterpret_cast<float4*>(sp)[((kq - 1) * 8 + r) * 64 + colg] =
          make_float4(acc[r][0], acc[r][1], acc[r][2], acc[r][3]);
  }
  __syncthreads();
  if (kq == 0) {
    float4 b4 = reinterpret_cast<const float4*>(bias)[colg];
    const float4* sp4 = reinterpret_cast<const float4*>(sp);
    #pragma unroll
    for (int r = 0; r < 8; ++r) {
      float4 p0 = sp4[(0 * 8 + r) * 64 + colg];
      float4 p1 = sp4[(1 * 8 + r) * 64 + colg];
      float4 p2 = sp4[(2 * 8 + r) * 64 + colg];
      float4 o;
      o.x = acc[r][0] + p0.x + p1.x + p2.x + b4.x;
      o.y = acc[r][1] + p0.y + p1.y + p2.y + b4.y;
      o.z = acc[r][2] + p0.z + p1.z + p2.z + b4.z;
      o.w = acc[r][3] + p0.w + p1.w + p2.w + b4.w;
      if (mat == 1) {
        int gr = row0 + r, bb2 = gr / NT, jj2 = gr % NT;
        float* kd = out + (size_t)bb2 * (DM * NT) + jj2;
        kd[(size_t)(colg * 4 + 0) * NT] = o.x;
        kd[(size_t)(colg * 4 + 1) * NT] = o.y;
        kd[(size_t)(colg * 4 + 2) * NT] = o.z;
        kd[(size_t)(colg * 4 + 3) * NT] = o.w;
      } else {
        reinterpret_cast<float4*>(out + (size_t)(row0 + r) * DM)[colg] = o;
      }
    }
  }
}

// ---- QKV layer-1: K^T full (1040 rows) + V full + Q first 24 rows per b --
__global__ void __launch_bounds__(256) k_qkv_l1(
    const float* __restrict__ WqT, const float* __restrict__ WkT,
    const float* __restrict__ WvT,
    const float* __restrict__ bq, const float* __restrict__ bk,
    const float* __restrict__ bv,
    const float* __restrict__ xin,
    float* __restrict__ qo, float* __restrict__ ko, float* __restrict__ vo) {
  int bi = blockIdx.x;
  const float* WT; const float* bias; float* out; int row0; int ktm = 0;
  if (bi < 130)      { WT = WkT; bias = bk; out = ko; row0 = bi * 8; ktm = 1; }
  else if (bi < 260) { WT = WvT; bias = bv; out = vo; row0 = (bi - 130) * 8; }
  else {             // 12 blocks: Q for rows b*NT + [0,24)
    int gq = bi - 260;
    WT = WqT; bias = bq; out = qo;
    row0 = (gq / 3) * NT + (gq % 3) * 8;
  }
  __shared__ __align__(16) float sx[8 * DM];
  __shared__ __align__(16) float sp[3 * 8 * DM];
  int t = threadIdx.x;
  int colg = t & 63, kq = t >> 6;
  #pragma unroll
  for (int i = 0; i < 2; ++i)
    reinterpret_cast<float4*>(sx)[t + i * 256] =
        reinterpret_cast<const float4*>(xin + (size_t)row0 * DM)[t + i * 256];
  __syncthreads();
  float acc[8][4];
  #pragma unroll
  for (int r = 0; r < 8; ++r) { acc[r][0]=0.f; acc[r][1]=0.f; acc[r][2]=0.f; acc[r][3]=0.f; }
  const float* xb = sx + kq * 64;
  const float4* wp = reinterpret_cast<const float4*>(WT + (size_t)(kq * 64) * DM) + colg;
  #pragma unroll 1
  for (int k0 = 0; k0 < 64; k0 += 4) {
    float4 w[4];
    #pragma unroll
    for (int q = 0; q < 4; ++q) w[q] = wp[(size_t)(k0 + q) * 64];
    #pragma unroll
    for (int q = 0; q < 4; ++q)
      #pragma unroll
      for (int r = 0; r < 8; ++r) {
        float xv = xb[r * DM + k0 + q];
        acc[r][0] += xv * w[q].x; acc[r][1] += xv * w[q].y;
        acc[r][2] += xv * w[q].z; acc[r][3] += xv * w[q].w;
      }
  }
  if (kq) {
    #pragma unroll
    for (int r = 0; r < 8; ++r)
      reinterpret_cast<float4*>(sp)[((kq - 1) * 8 + r) * 64 + colg] =
          make_float4(acc[r][0], acc[r][1], acc[r][2], acc[r][3]);
  }
  __syncthreads();
  if (kq == 0) {
    float4 b4 = reinterpret_cast<const float4*>(bias)[colg];
    const float4* sp4 = reinterpret_cast<const float4*>(sp);
    #pragma unroll
    for (int r = 0; r < 8; ++r) {
      float4 p0 = sp4[(0 * 8 + r) * 64 + colg];
      float4 p1 = sp4[(1 * 8 + r) * 64 + colg];
      float4 p2 = sp4[(2 * 8 + r) * 64 + colg];
      float4 o;
      o.x = acc[r][0] + p0.x + p1.x + p2.x + b4.x;
      o.y = acc[r][1] + p0.y + p1.y + p2.y + b4.y;
      o.z = acc[r][2] + p0.z + p1.z + p2.z + b4.z;
      o.w = acc[r][3] + p0.w + p1.w + p2.w + b4.w;
      if (ktm) {
        int gr = row0 + r, bb2 = gr / NT, jj2 = gr % NT;
        float* kd = out + (size_t)bb2 * (DM * NT) + jj2;
        kd[(size_t)(colg * 4 + 0) * NT] = o.x;
        kd[(size_t)(colg * 4 + 1) * NT] = o.y;
        kd[(size_t)(colg * 4 + 2) * NT] = o.z;
        kd[(size_t)(colg * 4 + 3) * NT] = o.w;
      } else {
        reinterpret_cast<float4*>(out + (size_t)(row0 + r) * DM)[colg] = o;
      }
    }
  }
}

// ---- TKA attention + fused Wo^T, 512 threads, split PV / split-K Wo ------
__global__ void __launch_bounds__(512) k_tka_attn_f(
    const float* __restrict__ xin, const float* __restrict__ qw,
    const float* __restrict__ kw, const float* __restrict__ vw,
    const float* __restrict__ grel, const float* __restrict__ gib,
    const float* __restrict__ alpha, const float* __restrict__ beta,
    const float* __restrict__ gamma,
    const float* __restrict__ WOT, const float* __restrict__ bO,
    float* __restrict__ xout) {
  int bi = blockIdx.x;                       // b*63+i
  int b = bi / EL, i = bi % EL;
  int t = threadIdx.x;
  __shared__ __align__(16) float sQX[2 * DM];
  __shared__ float sP[NH * 64];
  __shared__ __align__(16) float sO[DM];
  __shared__ float sPV[DM];
  if (t < 2 * DM)
    sQX[t] = (t < DM) ? qw[(size_t)bi * DM + t] : xin[(size_t)bi * DM + (t - DM)];
  __syncthreads();
  {
    int tile = t >> 8, h = (t >> 5) & 7, jj = t & 31;
    int j = tile * 32 + jj;
    bool valid = (j < EL);
    int jc = valid ? j : (EL - 1);
    float gi = gib[((size_t)b * NH + h) * EL + i];
    float al = alpha[h], be = beta[h], ga = gamma[h];
    const float* grow = grel + (((size_t)b * NH + h) * EL + i) * EL;
    const float4* kp = reinterpret_cast<const float4*>(
        kw + (size_t)(b * EL + jc) * DM + h * 32);
    const float4* xp = reinterpret_cast<const float4*>(
        xin + (size_t)(b * EL + jc) * DM + h * 32);
    float4 kf[8], xf[8];
    #pragma unroll
    for (int q = 0; q < 8; ++q) { kf[q] = kp[q]; xf[q] = xp[q]; }
    float qk  = dot32(reinterpret_cast<const float4*>(sQX + h * 32), kf);
    float pij = dot32(reinterpret_cast<const float4*>(sQX + DM + h * 32), xf);
    float A = al * pij * (2.f * gi) + be * pij * grow[jc] + ga;
    const float scale = 0.17677669529663687f;
    sP[h * 64 + tile * 32 + jj] = valid ? (qk * scale * A) : -1e30f;
  }
  __syncthreads();
  {
    int h = t >> 6, dh = t & 63;               // one wave per head
    float v = sP[h * 64 + dh];
    float m = v;
    #pragma unroll
    for (int s = 1; s < 64; s <<= 1) m = fmaxf(m, __shfl_xor(m, s, 64));
    float e = __expf(v - m);
    float ssum = e;
    #pragma unroll
    for (int s = 1; s < 64; s <<= 1) ssum += __shfl_xor(ssum, s, 64);
    sP[h * 64 + dh] = e / ssum;                // dh=63 -> 0
  }
  __syncthreads();
  {
    int ch = t & 255, jh = t >> 8, hh = ch >> 5;
    float acc = 0.f;
    const float* pp = sP + hh * 64 + jh * 32;
    int jbase = jh * 32;
    #pragma unroll 1
    for (int j0 = 0; j0 < 32; j0 += 8) {
      float v[8];
      #pragma unroll
      for (int q = 0; q < 8; ++q) {
        int jx = jbase + j0 + q;
        if (jx > 62) jx = 62;                  // j=63 weight is 0; avoid stale row
        v[q] = vw[(size_t)(b * EL + jx) * DM + ch];
      }
      #pragma unroll
      for (int q = 0; q < 8; ++q) acc += pp[j0 + q] * v[q];
    }
    if (jh) sPV[ch] = acc;
    __syncthreads();
    if (!jh) sO[ch] = acc + sPV[ch];
  }
  __syncthreads();
  {
    int col = t & 255, kh = t >> 8;
    float acc = 0.f;
    const float* wc = WOT + (size_t)(kh * 128) * DM + col;
    const float* sx = sO + kh * 128;
    #pragma unroll 1
    for (int k0 = 0; k0 < 128; k0 += 8) {
      float w[8];
      #pragma unroll
      for (int q = 0; q < 8; ++q) w[q] = wc[(size_t)(k0 + q) * DM];
      #pragma unroll
      for (int q = 0; q < 8; ++q) acc += sx[k0 + q] * w[q];
    }
    if (kh) sPV[col] = acc;
    __syncthreads();
    if (!kh) xout[(size_t)bi * DM + col] = acc + sPV[col] + bO[col];
  }
}

// ---- encoder attention, 512 thr, 2 rows/block, K^T coalesced scores ------
// kw is K^T [b][256][260]. tpb: i-tiles (2 rows) per batch (130 / 12).
__global__ void __launch_bounds__(512) k_enc_attn_f(
    const float* __restrict__ qw, const float* __restrict__ kw,
    const float* __restrict__ vw,
    const float* __restrict__ WoT, const float* __restrict__ bo,
    const float* __restrict__ g, const float* __restrict__ bb,
    const float* __restrict__ resin, float* __restrict__ out, int tpb) {
  int blk = blockIdx.x;                      // b*tpb + tile
  int b = blk / tpb, it = blk % tpb;
  int i0 = it * 2;
  int t = threadIdx.x;

  __shared__ __align__(16) float sQ[2 * DM]; // Q rows; later normalized PV out
  __shared__ float sS[2 * NH * NT];          // 16.6 KB
  __shared__ float sL[2 * NH];
  __shared__ __align__(16) float sPV[2 * DM];
  __shared__ float sb[8];

  for (int idx = t; idx < 2 * DM; idx += 512)
    sQ[idx] = qw[((size_t)(b * NT + i0)) * DM + idx];
  __syncthreads();

  const float scale = 0.17677669529663687f;
  {
    // scores: thread t owns column j=t (<260); coalesced K^T reads
    if (t < NT) {
      const float* kT = kw + (size_t)b * (DM * NT) + t;
      #pragma unroll
      for (int h = 0; h < NH; ++h) {
        float a0 = 0.f, a1 = 0.f;
        float kv[8];
        #pragma unroll
        for (int d0 = 0; d0 < 32; d0 += 8) {
          #pragma unroll
          for (int q = 0; q < 8; ++q)
            kv[q] = kT[(size_t)(h * 32 + d0 + q) * NT];
          #pragma unroll
          for (int q = 0; q < 8; ++q) {
            a0 += sQ[0 * DM + h * 32 + d0 + q] * kv[q];
            a1 += sQ[1 * DM + h * 32 + d0 + q] * kv[q];
          }
        }
        sS[(0 * NH + h) * NT + t] = a0 * scale;
        sS[(1 * NH + h) * NT + t] = a1 * scale;
      }
    }
  }
  __syncthreads();
  {
    int combo = t >> 5, lane32 = t & 31;     // 16 combos x 32 lanes
    float* row = sS + (size_t)combo * NT;
    float m = -1e30f;
    for (int jx = lane32; jx < NT; jx += 32) m = fmaxf(m, row[jx]);
    #pragma unroll
    for (int s = 1; s < 32; s <<= 1) m = fmaxf(m, __shfl_xor(m, s, 32));
    float ssum = 0.f;
    for (int jx = lane32; jx < NT; jx += 32) {
      float e = __expf(row[jx] - m);
      row[jx] = e;
      ssum += e;
    }
    #pragma unroll
    for (int s = 1; s < 32; s <<= 1) ssum += __shfl_xor(ssum, s, 32);
    if (lane32 == 0) sL[combo] = ssum;
  }
  __syncthreads();
  {
    int ch = t & 255, jh = t >> 8, hh = ch >> 5;
    float o0 = 0.f, o1 = 0.f;
    const float* vbase = vw + ((size_t)(b * NT + jh * 130)) * DM + ch;
    const float* p0 = sS + (0 * NH + hh) * NT + jh * 130;
    const float* p1 = sS + (1 * NH + hh) * NT + jh * 130;
    #pragma unroll 1
    for (int j0 = 0; j0 < 130; j0 += 10) {
      float v[10];
      #pragma unroll
      for (int q = 0; q < 10; ++q) v[q] = vbase[(size_t)(j0 + q) * DM];
      #pragma unroll
      for (int q = 0; q < 10; ++q) {
        o0 += p0[j0 + q] * v[q]; o1 += p1[j0 + q] * v[q];
      }
    }
    if (jh) {
      sPV[0 * DM + ch] = o0; sPV[1 * DM + ch] = o1;
    }
    __syncthreads();
    if (!jh) {
      sQ[0 * DM + ch] = (o0 + sPV[0 * DM + ch]) / sL[0 * NH + hh];
      sQ[1 * DM + ch] = (o1 + sPV[1 * DM + ch]) / sL[1 * NH + hh];
    }
  }
  __syncthreads();
  {
    int col = t & 255, kh = t >> 8;
    float acc[2] = {0.f, 0.f};
    const float* wcol = WoT + (size_t)(kh * 128) * DM + col;
    const float* s0 = sQ + kh * 128;
    #pragma unroll 1
    for (int k0 = 0; k0 < 128; k0 += 8) {
      float w[8];
      #pragma unroll
      for (int q = 0; q < 8; ++q) w[q] = wcol[(size_t)(k0 + q) * DM];
      #pragma unroll
      for (int q = 0; q < 8; ++q) {
        acc[0] += s0[0 * DM + k0 + q] * w[q];
        acc[1] += s0[1 * DM + k0 + q] * w[q];
      }
    }
    if (kh) {
      sPV[0 * DM + col] = acc[0]; sPV[1 * DM + col] = acc[1];
    }
    __syncthreads();
    float ov[2] = {0.f, 0.f};
    float gg = g[col], bb2 = bb[col];
    if (!kh) {
      float bias = bo[col];
      #pragma unroll
      for (int r = 0; r < 2; ++r)
        ov[r] = acc[r] + sPV[r * DM + col] + bias
              + resin[((size_t)(b * NT + i0 + r)) * DM + col];
    }
    int wid = t >> 6, lane = t & 63;
    #pragma unroll 1
    for (int r = 0; r < 2; ++r) {
      float o = (!kh) ? ov[r] : 0.f;
      __syncthreads();
      float s1 = o, s2 = o * o;
      #pragma unroll
      for (int off = 32; off > 0; off >>= 1) {
        s1 += __shfl_down(s1, off, 64);
        s2 += __shfl_down(s2, off, 64);
      }
      if (lane == 0 && wid < 4) { sb[wid * 2] = s1; sb[wid * 2 + 1] = s2; }
      __syncthreads();
      float m = (sb[0] + sb[2] + sb[4] + sb[6]) * (1.f / 256.f);
      float q2 = (sb[1] + sb[3] + sb[5] + sb[7]) * (1.f / 256.f);
      float var = q2 - m * m;
      if (!kh)
        out[((size_t)(b * NT + i0 + r)) * DM + col] =
            (ov[r] - m) * rsqrtf(var + EPSV) * gg + bb2;
    }
  }
}

// ---- FFN1: gelu(x@W1.T+b1), W1T bf16, y1 written bf16 --------------------
// gpb: row-groups per batch (0 = dense 130 groups; 3 = pruned 24 rows/b)
__global__ void __launch_bounds__(256) k_ffn1(
    const unsigned short* __restrict__ W1T, const float* __restrict__ b1,
    const float* __restrict__ xn, unsigned short* __restrict__ y1, int gpb) {
  int bi = blockIdx.x;                       // rg*4 + fg
  int rg = bi >> 2, fg = bi & 3;
  int row0 = gpb ? ((rg / gpb) * NT + (rg % gpb) * 8) : rg * 8;
  __shared__ __align__(16) float sx[8 * DM];
  __shared__ __align__(16) float sp[3 * 8 * DM];
  int t = threadIdx.x;
  int colg = t & 63, kq = t >> 6;
  #pragma unroll
  for (int i = 0; i < 2; ++i)
    reinterpret_cast<float4*>(sx)[t + i * 256] =
        reinterpret_cast<const float4*>(xn + (size_t)row0 * DM)[t + i * 256];
  __syncthreads();
  int f = fg * 256 + colg * 4;
  float acc[8][4];
  #pragma unroll
  for (int r = 0; r < 8; ++r) { acc[r][0]=0.f; acc[r][1]=0.f; acc[r][2]=0.f; acc[r][3]=0.f; }
  const float* xb = sx + kq * 64;
  const unsigned short* wb = W1T + (size_t)(kq * 64) * DFF + f;
  #pragma unroll 1
  for (int k0 = 0; k0 < 64; k0 += 4) {
    float4 w[4];
    #pragma unroll
    for (int q = 0; q < 4; ++q) {
      ushort4 u = *reinterpret_cast<const ushort4*>(wb + (size_t)(k0 + q) * DFF);
      w[q] = make_float4(bf2f(u.x), bf2f(u.y), bf2f(u.z), bf2f(u.w));
    }
    #pragma unroll
    for (int q = 0; q < 4; ++q)
      #pragma unroll
      for (int r = 0; r < 8; ++r) {
        float xv = xb[r * DM + k0 + q];
        acc[r][0] += xv * w[q].x; acc[r][1] += xv * w[q].y;
        acc[r][2] += xv * w[q].z; acc[r][3] += xv * w[q].w;
      }
  }
  if (kq) {
    #pragma unroll
    for (int r = 0; r < 8; ++r)
      reinterpret_cast<float4*>(sp)[((kq - 1) * 8 + r) * 64 + colg] =
          make_float4(acc[r][0], acc[r][1], acc[r][2], acc[r][3]);
  }
  __syncthreads();
  if (kq == 0) {
    float4 b4 = *reinterpret_cast<const float4*>(b1 + f);
    const float4* sp4 = reinterpret_cast<const float4*>(sp);
    #pragma unroll 1
    for (int r = 0; r < 8; ++r) {
      float4 p0 = sp4[(0 * 8 + r) * 64 + colg];
      float4 p1 = sp4[(1 * 8 + r) * 64 + colg];
      float4 p2 = sp4[(2 * 8 + r) * 64 + colg];
      float a0 = acc[r][0] + p0.x + p1.x + p2.x + b4.x;
      float a1 = acc[r][1] + p0.y + p1.y + p2.y + b4.y;
      float a2 = acc[r][2] + p0.z + p1.z + p2.z + b4.z;
      float a3 = acc[r][3] + p0.w + p1.w + p2.w + b4.w;
      ushort4 o;
      o.x = f2bf(0.5f * a0 * (1.f + erff(a0 * 0.70710678118654752f)));
      o.y = f2bf(0.5f * a1 * (1.f + erff(a1 * 0.70710678118654752f)));
      o.z = f2bf(0.5f * a2 * (1.f + erff(a2 * 0.70710678118654752f)));
      o.w = f2bf(0.5f * a3 * (1.f + erff(a3 * 0.70710678118654752f)));
      *reinterpret_cast<ushort4*>(y1 + (size_t)(row0 + r) * DFF + f) = o;
    }
  }
}

// ---- FFN2 fused: W2T bf16, y1 bf16 in, +bias+residual+LN -----------------
// gpb: groups-of-4 per batch (0 = dense 260 blocks; 6 = pruned 24 rows/b)
__global__ void __launch_bounds__(512) k_ffn2f(
    const unsigned short* __restrict__ W2T, const float* __restrict__ b2,
    const float* __restrict__ g, const float* __restrict__ bb,
    const unsigned short* __restrict__ y1, const float* __restrict__ xn,
    float* __restrict__ out, int gpb) {
  int blk = blockIdx.x;
  int row0 = gpb ? ((blk / gpb) * NT + (blk % gpb) * 4) : blk * 4;
  __shared__ __align__(16) float sy[4 * DFF];    // 16 KB
  __shared__ __align__(16) float sp[7 * 4 * DM]; // 28 KB
  int t = threadIdx.x;
  int colg = t & 63, kq = t >> 6;                // kq 0..7
  #pragma unroll
  for (int i = 0; i < 2; ++i) {
    ushort4 u = reinterpret_cast<const ushort4*>(y1 + (size_t)row0 * DFF)[t + i * 512];
    reinterpret_cast<float4*>(sy)[t + i * 512] =
        make_float4(bf2f(u.x), bf2f(u.y), bf2f(u.z), bf2f(u.w));
  }
  __syncthreads();
  float acc[4][4];
  #pragma unroll
  for (int r = 0; r < 4; ++r) { acc[r][0]=0.f; acc[r][1]=0.f; acc[r][2]=0.f; acc[r][3]=0.f; }
  const float* yb = sy + kq * 128;
  const unsigned short* wb2 = W2T + (size_t)(kq * 128) * DM + colg * 4;
  #pragma unroll 1
  for (int k0 = 0; k0 < 128; k0 += 8) {
    float4 w[8];
    #pragma unroll
    for (int q = 0; q < 8; ++q) {
      ushort4 u = *reinterpret_cast<const ushort4*>(wb2 + (size_t)(k0 + q) * DM);
      w[q] = make_float4(bf2f(u.x), bf2f(u.y), bf2f(u.z), bf2f(u.w));
    }
    #pragma unroll
    for (int q = 0; q < 8; ++q)
      #pragma unroll
      for (int r = 0; r < 4; ++r) {
        float yv = yb[r * DFF + k0 + q];
        acc[r][0] += yv * w[q].x; acc[r][1] += yv * w[q].y;
        acc[r][2] += yv * w[q].z; acc[r][3] += yv * w[q].w;
      }
  }
  if (kq) {
    #pragma unroll
    for (int r = 0; r < 4; ++r)
      reinterpret_cast<float4*>(sp)[((kq - 1) * 4 + r) * 64 + colg] =
          make_float4(acc[r][0], acc[r][1], acc[r][2], acc[r][3]);
  }
  __syncthreads();
  if (kq == 0) {
    float4 b4 = reinterpret_cast<const float4*>(b2)[colg];
    float4 g4 = reinterpret_cast<const float4*>(g)[colg];
    float4 bb4 = reinterpret_cast<const float4*>(bb)[colg];
    const float4* sp4 = reinterpret_cast<const float4*>(sp);
    #pragma unroll 1
    for (int r = 0; r < 4; ++r) {
      float o0 = acc[r][0], o1 = acc[r][1], o2 = acc[r][2], o3 = acc[r][3];
      #pragma unroll
      for (int s = 0; s < 7; ++s) {
        float4 ps = sp4[(s * 4 + r) * 64 + colg];
        o0 += ps.x; o1 += ps.y; o2 += ps.z; o3 += ps.w;
      }
      float4 xr = reinterpret_cast<const float4*>(xn + (size_t)(row0 + r) * DM)[colg];
      o0 += b4.x + xr.x; o1 += b4.y + xr.y; o2 += b4.z + xr.z; o3 += b4.w + xr.w;
      float s1 = o0 + o1 + o2 + o3;
      float s2 = o0*o0 + o1*o1 + o2*o2 + o3*o3;
      #pragma unroll
      for (int m = 1; m < 64; m <<= 1) {
        s1 += __shfl_xor(s1, m, 64);
        s2 += __shfl_xor(s2, m, 64);
      }
      float mean = s1 * (1.f / 256.f);
      float var = s2 * (1.f / 256.f) - mean * mean;
      float rs = rsqrtf(var + EPSV);
      float4 o;
      o.x = (o0 - mean) * rs * g4.x + bb4.x;
      o.y = (o1 - mean) * rs * g4.y + bb4.y;
      o.z = (o2 - mean) * rs * g4.z + bb4.z;
      o.w = (o3 - mean) * rs * g4.w + bb4.w;
      reinterpret_cast<float4*>(out + (size_t)(row0 + r) * DM)[colg] = o;
    }
  }
}

// ---- final LN + projection (pWT [256][96], batched) + denorm -------------
__global__ void k_final(const float* __restrict__ g, const float* __restrict__ bb,
                        const float* __restrict__ pWT, const float* __restrict__ pb,
                        const float* __restrict__ enc2,
                        const float* __restrict__ stdev, const float* __restrict__ means,
                        float* __restrict__ out) {
  int bi = blockIdx.x;                       // b*21+c
  int b = bi / CIN, c = bi % CIN;
  __shared__ __align__(16) float sx[DM];
  __shared__ float sb[8];
  int t = threadIdx.x;
  float v = enc2[(size_t)(b * NT + c) * DM + t];
  float2 mv = meanvar256(v, sb);
  sx[t] = (v - mv.x) * rsqrtf(mv.y + EPSV) * g[t] + bb[t];
  __syncthreads();
  if (t < PRED) {
    float acc = 0.f;
    #pragma unroll 1
    for (int k0 = 0; k0 < DM; k0 += 8) {
      float w[8];
      #pragma unroll
      for (int q = 0; q < 8; ++q) w[q] = pWT[(size_t)(k0 + q) * PRED + t];
      #pragma unroll
      for (int q = 0; q < 8; ++q) acc += sx[k0 + q] * w[q];
    }
    float y = (acc + pb[t]) * stdev[bi] + means[bi];
    out[(size_t)b * PRED * CIN + t * CIN + c] = y;
  }
}

extern "C" void kernel_launch(void* const* d_in, const int* in_sizes, int n_in,
                              void* d_out, int out_size, void* d_ws, size_t ws_size,
                              hipStream_t stream) {
  const float* x_enc   = (const float*)d_in[0];
  const float* x_mark  = (const float*)d_in[1];
  const float* tok_W   = (const float*)d_in[4];
  const float* patch_W = (const float*)d_in[5];
  const float* patch_b = (const float*)d_in[6];
  const float* nl_WQ   = (const float*)d_in[7];
  const float* nl_WK   = (const float*)d_in[8];
  const float* nl_WV   = (const float*)d_in[9];
  const float* nl_WO   = (const float*)d_in[10];
  const float* nl_bO   = (const float*)d_in[11];
  const float* nl_mu_a = (const float*)d_in[12];
  const float* nl_sg_a = (const float*)d_in[13];
  const float* nl_w_a  = (const float*)d_in[14];
  const float* nl_mu_r = (const float*)d_in[15];
  const float* nl_sg_r = (const float*)d_in[16];
  const float* nl_w_r  = (const float*)d_in[17];
  const float* nl_al   = (const float*)d_in[18];
  const float* nl_be   = (const float*)d_in[19];
  const float* nl_ga   = (const float*)d_in[20];
  const float* inv_W   = (const float*)d_in[21];
  const float* inv_b   = (const float*)d_in[22];
  const float* el_Wq   = (const float*)d_in[23];
  const float* el_bq   = (const float*)d_in[24];
  const float* el_Wk   = (const float*)d_in[25];
  const float* el_bk   = (const float*)d_in[26];
  const float* el_Wv   = (const float*)d_in[27];
  const float* el_bv   = (const float*)d_in[28];
  const float* el_Wo   = (const float*)d_in[29];
  const float* el_bo   = (const float*)d_in[30];
  const float* el_W1   = (const float*)d_in[31];
  const float* el_b1   = (const float*)d_in[32];
  const float* el_W2   = (const float*)d_in[33];
  const float* el_b2   = (const float*)d_in[34];
  const float* n1g     = (const float*)d_in[35];
  const float* n1b     = (const float*)d_in[36];
  const float* n2g     = (const float*)d_in[37];
  const float* n2b     = (const float*)d_in[38];
  const float* norm_g  = (const float*)d_in[39];
  const float* norm_b  = (const float*)d_in[40];
  const float* proj_W  = (const float*)d_in[41];
  const float* proj_b  = (const float*)d_in[42];

  // workspace layout (floats)
  float* ws = (float*)d_ws;
  float* means = ws + 0;          //     96
  float* stdev = ws + 96;         //     96
  float* tws   = ws + 192;        //   1024
  float* enc1  = ws + 1216;       // 524288  (B,512,256)
  float* encP  = ws + 525504;     //  64512  (252,256)
  float* pbuf  = ws + 590016;     // 516096  (8,252,256)
  float* enc2  = ws + 1106112;    // 266240  (1040,256)
  float* qb    = ws + 1638592;    // 266240  (xn aliases qb)
  float* kb    = ws + 1904832;    // 266240  (K or K^T)
  float* vb    = ws + 2171072;    // 266240
  float* y1    = ws + 2437312;    // 1064960 (y1 now bf16: uses half)
  float* encPb = ws + 3502272;    //  64512  (TKA ping-pong)
  float* grel  = ws + 4567232;    // 254016  (2,B,8,63,63)
  float* gib   = ws + 4821248;    //   4032  (2,B,8,63)
  float* wsT   = ws + 4825344;    // 3202560 (transposed weights; W1/W2 bf16)
  float* xn    = qb;              // alias: qb rows only self-read before overwrite

  // prep: weight transpose (3128) + stats/tws (88) + grel/gib (2016)
  k_prep<<<5232, 256, 0, stream>>>(nl_WQ, nl_WK, nl_WV, nl_WO,
                                   el_Wq, el_Wk, el_Wv, el_Wo,
                                   el_W1, el_W2, inv_W, proj_W,
                                   tok_W, patch_W, wsT,
                                   x_enc, x_mark, means, stdev, tws,
                                   nl_mu_r, nl_sg_r, nl_w_r,
                                   nl_mu_a, nl_sg_a, nl_w_a, grel, gib);
  k_tokconv<<<NB * 64, 256, 0, stream>>>(x_enc, wsT + T_tok, means, stdev, enc1);
  k_patch_part<<<42 * 8, 256, 0, stream>>>(enc1, wsT + T_pat, pbuf);

  // ---- TKA layer 0: fused patch-reduce + QKV, then attention -------------
  k_qkv_tka0<<<63 * 3, 256, 0, stream>>>(wsT + T_nlWQ, wsT + T_nlWK, wsT + T_nlWV,
                                         pbuf, patch_b, qb, kb, vb, encP);
  k_tka_attn_f<<<NB * EL, 512, 0, stream>>>(encP, qb, kb, vb,
      grel, gib, nl_al, nl_be, nl_ga,
      wsT + T_nlWO, nl_bO, encPb);
  // ---- TKA layer 1 -------------------------------------------------------
  {
    size_t wo = (size_t)DM * DM;
    k_qkv2<4><<<63 * 3, 256, 0, stream>>>(wsT + T_nlWQ + wo, wsT + T_nlWK + wo,
                                          wsT + T_nlWV + wo,
                                          nullptr, nullptr, nullptr,
                                          encPb, qb, kb, vb, 0);
    k_tka_attn_f<<<NB * EL, 512, 0, stream>>>(encPb, qb, kb, vb,
        grel + (size_t)(NB * NH * EL * EL), gib + (size_t)(NB * NH * EL),
        nl_al + 8, nl_be + 8, nl_ga + 8,
        wsT + T_nlWO + wo, nl_bO + DM, encP);
  }

  // ---- encoder layer 0: fused inv-embedding + QKV (K^T) ------------------
  k_qkv_enc0<<<130 * 3, 256, 0, stream>>>(wsT + T_elWq, wsT + T_elWk, wsT + T_elWv,
                                          el_bq, el_bk, el_bv,
                                          wsT + T_inv, inv_b, encP, tws,
                                          qb, kb, vb, enc2);
  k_enc_attn_f<<<NB * 130, 512, 0, stream>>>(qb, kb, vb, wsT + T_elWo, el_bo,
                                             n1g, n1b, enc2, xn, 130);
  k_ffn1<<<130 * 4, 256, 0, stream>>>((const unsigned short*)(wsT + T_elW1),
                                      el_b1, xn, (unsigned short*)y1, 0);
  k_ffn2f<<<260, 512, 0, stream>>>((const unsigned short*)(wsT + T_elW2),
                                   el_b2, n2g, n2b,
                                   (const unsigned short*)y1, xn, enc2, 0);

  // ---- encoder layer 1: pruned — only rows [b*NT, b*NT+24) reach k_final --
  {
    size_t wo = (size_t)DM * DM;
    size_t bo = (size_t)DM;
    size_t fe = (size_t)DFF * DM;   // bf16 element offset per layer
    k_qkv_l1<<<272, 256, 0, stream>>>(wsT + T_elWq + wo, wsT + T_elWk + wo,
                                      wsT + T_elWv + wo,
                                      el_bq + bo, el_bk + bo, el_bv + bo,
                                      enc2, qb, kb, vb);
    k_enc_attn_f<<<NB * 12, 512, 0, stream>>>(qb, kb, vb, wsT + T_elWo + wo,
                                              el_bo + bo, n1g + bo, n1b + bo,
                                              enc2, xn, 12);
    k_ffn1<<<12 * 4, 256, 0, stream>>>((const unsigned short*)(wsT + T_elW1) + fe,
                                       el_b1 + DFF, xn, (unsigned short*)y1, 3);
    k_ffn2f<<<NB * 6, 512, 0, stream>>>((const unsigned short*)(wsT + T_elW2) + fe,
                                        el_b2 + bo, n2g + bo, n2b + bo,
                                        (const unsigned short*)y1, xn, enc2, 6);
  }

  k_final<<<NB * CIN, 256, 0, stream>>>(norm_g, norm_b, wsT + T_proj, proj_b,
                                        enc2, stdev, means, (float*)d_out);
}